// Round 6
// baseline (906.001 us; speedup 1.0000x reference)
//
#include <hip/hip_runtime.h>
#include <math.h>

#define NFEAT 512
#define NHEADS 8
#define HDIM 64
#define NB 4
#define NG 1024
#define NC 1024
#define NQ 256
#define NEGV -9e15f
#define FF ((size_t)NFEAT*NFEAT)
#define LSTR 36   // LDS row stride (ushorts) for reg-written P tiles only
#define SEG 2304  // segmented attn rows per batch

typedef _Float16 v8h __attribute__((ext_vector_type(8)));
typedef float v4f __attribute__((ext_vector_type(4)));
#define MFMA16(a,b,c) __builtin_amdgcn_mfma_f32_16x16x32_f16((a),(b),(c),0,0,0)

// async global->LDS, 16B/lane, lane-linear LDS dest (wave-uniform base + lane*16)
#define GLDS(g, l) __builtin_amdgcn_global_load_lds( \
    (__attribute__((address_space(1))) void*)(g), \
    (__attribute__((address_space(3))) void*)(l), 16, 0, 0)

// XOR swizzle for 64B-row linear LDS tiles: physical 16B slot = quad ^ ((row>>1)&3).
__device__ __forceinline__ int ldsw(int row, int quad){
    return row*32 + (((quad) ^ ((row>>1)&3)) << 3);
}

__device__ __forceinline__ float lrelu(float x){ return fmaxf(x, 0.2f*x); }
__device__ __forceinline__ unsigned short f2h(float x){ union{_Float16 h; unsigned short u;} v; v.h = (_Float16)x; return v.u; }
__device__ __forceinline__ float h2f(unsigned short u){ union{_Float16 h; unsigned short u;} v; v.u = u; return (float)v.h; }

// ============ prep: fp32 -> fp16 flat ============
__global__ __launch_bounds__(256) void cvt_h_k(const float* __restrict__ src, unsigned short* __restrict__ dst){
    int idx = blockIdx.x*256 + threadIdx.x;
    const float4* s = (const float4*)(src + (size_t)idx*8);
    float4 a = s[0], b = s[1];
    ushort4 p0{f2h(a.x),f2h(a.y),f2h(a.z),f2h(a.w)};
    ushort4 p1{f2h(b.x),f2h(b.y),f2h(b.z),f2h(b.w)};
    *(ushort4*)(dst + (size_t)idx*8) = p0;
    *(ushort4*)(dst + (size_t)idx*8 + 4) = p1;
}

// ============ prep: fp32 -> fp16 hi/lo flat ============
__global__ __launch_bounds__(256) void cvt_hl_k(const float* __restrict__ src,
    unsigned short* __restrict__ dstHi, unsigned short* __restrict__ dstLo){
    int idx = blockIdx.x*256 + threadIdx.x;
    const float4* s = (const float4*)(src + (size_t)idx*8);
    float4 a = s[0], b = s[1];
    float x[8] = {a.x,a.y,a.z,a.w,b.x,b.y,b.z,b.w};
    unsigned short hi[8], lo[8];
    #pragma unroll
    for (int j = 0; j < 8; ++j){ hi[j] = f2h(x[j]); lo[j] = f2h(x[j] - h2f(hi[j])); }
    *(ushort4*)(dstHi + (size_t)idx*8)     = ushort4{hi[0],hi[1],hi[2],hi[3]};
    *(ushort4*)(dstHi + (size_t)idx*8 + 4) = ushort4{hi[4],hi[5],hi[6],hi[7]};
    *(ushort4*)(dstLo + (size_t)idx*8)     = ushort4{lo[0],lo[1],lo[2],lo[3]};
    *(ushort4*)(dstLo + (size_t)idx*8 + 4) = ushort4{lo[4],lo[5],lo[6],lo[7]};
}

// ============ prep: fusion weights -> PACKED transposed fp16 hi/lo ============
// packed layout per group li: [c0i(8)][ktI(16)][mat(4)][row64][k32]
__global__ __launch_bounds__(256) void wtT_k(const float* __restrict__ w0, const float* __restrict__ w1,
    const float* __restrict__ w2, const float* __restrict__ w3,
    unsigned short* __restrict__ dstHi, unsigned short* __restrict__ dstLo){
    int bx = blockIdx.x;
    int mat = bx >> 6, t = bx & 63;
    int a = mat & 3, li = mat >> 2;
    const float* src = (a==0?w0:a==1?w1:a==2?w2:w3) + (size_t)li*FF;
    int fo0 = (t>>3)*64, fi0 = (t&7)*64;
    __shared__ float sT[64][65];
    int tid = threadIdx.x;
    #pragma unroll
    for (int it = 0; it < 4; ++it){
        int idx = it*256 + tid;
        int r = idx >> 4, c4 = idx & 15;
        float4 v = *(const float4*)(src + (size_t)(fi0+r)*512 + fo0 + c4*4);
        sT[r][c4*4+0]=v.x; sT[r][c4*4+1]=v.y; sT[r][c4*4+2]=v.z; sT[r][c4*4+3]=v.w;
    }
    __syncthreads();
    #pragma unroll
    for (int it = 0; it < 2; ++it){
        int idx = it*256 + tid;
        int dd = idx >> 3, c8 = idx & 7;
        unsigned short hi[8], lo[8];
        #pragma unroll
        for (int j = 0; j < 8; ++j){
            float x = sT[c8*8+j][dd];
            hi[j] = f2h(x);
            lo[j] = f2h(x - h2f(hi[j]));
        }
        int ktI = (fi0 >> 5) + (c8 >> 2);
        int k31 = (c8 & 3)*8;
        size_t oo = (size_t)li*4*FF + ((((size_t)(fo0>>6)*16 + ktI)*4 + a)*64 + dd)*32 + k31;
        *(ushort4*)(dstHi+oo)   = ushort4{hi[0],hi[1],hi[2],hi[3]};
        *(ushort4*)(dstHi+oo+4) = ushort4{hi[4],hi[5],hi[6],hi[7]};
        *(ushort4*)(dstLo+oo)   = ushort4{lo[0],lo[1],lo[2],lo[3]};
        *(ushort4*)(dstLo+oo+4) = ushort4{lo[4],lo[5],lo[6],lo[7]};
    }
}

// ============ prep: 3 attn W repacks (blocks 0..191) + wa vectors (blocks 192..239) ============
__global__ __launch_bounds__(256) void prep_attnW3_k(
    const float* __restrict__ W0, const float* __restrict__ a10, const float* __restrict__ a20,
    const float* __restrict__ W1, const float* __restrict__ a11, const float* __restrict__ a21,
    const float* __restrict__ W2, const float* __restrict__ a12, const float* __restrict__ a22,
    unsigned short* __restrict__ WT3, float* __restrict__ wa13, float* __restrict__ wa23){
    int bx = blockIdx.x;
    int tid = threadIdx.x;
    if (bx >= 192){
        int r = bx - 192;
        int a = r >> 4;
        const float* W  = (a==0?W0:a==1?W1:W2);
        const float* a1 = (a==0?a10:a==1?a11:a12);
        const float* a2 = (a==0?a20:a==1?a21:a22);
        int idx = (r & 15)*256 + tid;
        int h = idx >> 9;
        const float* Wp = W + (size_t)idx*64;
        float s1 = 0.f, s2 = 0.f;
        #pragma unroll
        for (int d = 0; d < 64; ++d){ float w = Wp[d]; s1 += w*a1[(h<<6)+d]; s2 += w*a2[(h<<6)+d]; }
        wa13[a*4096 + idx] = s1; wa23[a*4096 + idx] = s2;
        return;
    }
    int a = bx >> 6, bxl = bx & 63;
    const float* W = (a==0?W0:a==1?W1:W2);
    unsigned short* WT = WT3 + (size_t)a*FF;
    int h = bxl >> 3, f0 = (bxl & 7)*64;
    __shared__ float sT[64][65];
    #pragma unroll
    for (int it = 0; it < 4; ++it){
        int idx = it*256 + tid;
        int r = idx >> 4, c4 = idx & 15;
        float4 v = *(const float4*)(W + ((size_t)h*512 + f0 + r)*64 + c4*4);
        sT[r][c4*4+0]=v.x; sT[r][c4*4+1]=v.y; sT[r][c4*4+2]=v.z; sT[r][c4*4+3]=v.w;
    }
    __syncthreads();
    #pragma unroll
    for (int it = 0; it < 2; ++it){
        int idx = it*256 + tid;
        int dd = idx >> 3, c8 = idx & 7;
        ushort4 p0{f2h(sT[c8*8+0][dd]),f2h(sT[c8*8+1][dd]),f2h(sT[c8*8+2][dd]),f2h(sT[c8*8+3][dd])};
        ushort4 p1{f2h(sT[c8*8+4][dd]),f2h(sT[c8*8+5][dd]),f2h(sT[c8*8+6][dd]),f2h(sT[c8*8+7][dd])};
        unsigned short* o = WT + ((size_t)h*64 + dd)*512 + f0 + c8*8;
        *(ushort4*)o = p0; *(ushort4*)(o+4) = p1;
    }
}

// ============ prep: adj_gc int -> adjT fp16 [b][c][g] + bitmasks both orientations ============
__global__ __launch_bounds__(256) void adjT_h_k(const int* __restrict__ adj, unsigned short* __restrict__ dst,
    unsigned long long* __restrict__ bm_gc, unsigned long long* __restrict__ bm_cg){
    int b = blockIdx.z;
    int c0 = blockIdx.x*64, g0 = blockIdx.y*64;
    __shared__ int sI[64][65];
    int tid = threadIdx.x;
    #pragma unroll
    for (int it = 0; it < 4; ++it){
        int idx = it*256 + tid;
        int r = idx >> 4, c4 = idx & 15;
        int4 v = *(const int4*)(adj + ((size_t)b*NG + g0 + r)*NC + c0 + c4*4);
        sI[r][c4*4+0]=v.x; sI[r][c4*4+1]=v.y; sI[r][c4*4+2]=v.z; sI[r][c4*4+3]=v.w;
    }
    __syncthreads();
    int wv = tid >> 6, lane = tid & 63;
    #pragma unroll
    for (int it = 0; it < 2; ++it){
        int idx = it*256 + tid;
        int dd = idx >> 3, c8 = idx & 7;
        ushort4 p0, p1;
        #pragma unroll
        for (int j = 0; j < 4; ++j) (&p0.x)[j] = sI[c8*8+j][dd] > 0 ? (unsigned short)0x3C00 : (unsigned short)0;
        #pragma unroll
        for (int j = 0; j < 4; ++j) (&p1.x)[j] = sI[c8*8+4+j][dd] > 0 ? (unsigned short)0x3C00 : (unsigned short)0;
        unsigned short* o = dst + ((size_t)b*NC + c0 + dd)*NG + g0 + c8*8;
        *(ushort4*)o = p0; *(ushort4*)(o+4) = p1;
    }
    // bitmasks from the tile: bm_gc rows over g (bits = c), bm_cg rows over c (bits = g)
    #pragma unroll
    for (int rr = wv; rr < 64; rr += 4){
        unsigned long long m = __ballot(sI[rr][lane] > 0);
        if (lane == 0) bm_gc[((size_t)b*NG + g0 + rr)*(NC/64) + (c0>>6)] = m;
    }
    #pragma unroll
    for (int cc = wv; cc < 64; cc += 4){
        unsigned long long m = __ballot(sI[lane][cc] > 0);
        if (lane == 0) bm_cg[((size_t)b*NC + c0 + cc)*(NG/64) + (g0>>6)] = m;
    }
}

// ============ prep: adj_gq int -> adjT int [b][q][g] + bitmasks both orientations ============
__global__ __launch_bounds__(256) void adjT_int_k(const int* __restrict__ adj, int* __restrict__ dst,
    unsigned long long* __restrict__ bm_gq, unsigned long long* __restrict__ bm_qg){
    int b = blockIdx.z;
    int q0 = blockIdx.x*64, g0 = blockIdx.y*64;
    __shared__ int sI[64][65];
    int tid = threadIdx.x;
    #pragma unroll
    for (int it = 0; it < 4; ++it){
        int idx = it*256 + tid;
        int r = idx >> 4, c4 = idx & 15;
        int4 v = *(const int4*)(adj + ((size_t)b*NG + g0 + r)*NQ + q0 + c4*4);
        sI[r][c4*4+0]=v.x; sI[r][c4*4+1]=v.y; sI[r][c4*4+2]=v.z; sI[r][c4*4+3]=v.w;
    }
    __syncthreads();
    int wv = tid >> 6, lane = tid & 63;
    #pragma unroll
    for (int it = 0; it < 4; ++it){
        int idx = it*256 + tid;
        int dd = idx >> 4, c4 = idx & 15;
        int4 v{sI[c4*4+0][dd], sI[c4*4+1][dd], sI[c4*4+2][dd], sI[c4*4+3][dd]};
        *(int4*)(dst + ((size_t)b*NQ + q0 + dd)*NG + g0 + c4*4) = v;
    }
    #pragma unroll
    for (int rr = wv; rr < 64; rr += 4){
        unsigned long long m = __ballot(sI[rr][lane] > 0);
        if (lane == 0) bm_gq[((size_t)b*NG + g0 + rr)*(NQ/64) + (q0>>6)] = m;
    }
    #pragma unroll
    for (int cc = wv; cc < 64; cc += 4){
        unsigned long long m = __ballot(sI[lane][cc] > 0);
        if (lane == 0) bm_qg[((size_t)b*NQ + q0 + cc)*(NG/64) + (g0>>6)] = m;
    }
}

// ============ prep: gloss fp32 -> transposed hi/lo [b][512][N] AND row-major hi/lo ============
__global__ __launch_bounds__(256) void actT_hl_k(const float* __restrict__ src,
    unsigned short* __restrict__ dstHi, unsigned short* __restrict__ dstLo,
    unsigned short* __restrict__ rmHi, unsigned short* __restrict__ rmLo, int Nrows){
    int b = blockIdx.z;
    int f0 = blockIdx.x*64, g0 = blockIdx.y*64;
    __shared__ float sF[64][65];
    int tid = threadIdx.x;
    #pragma unroll
    for (int it = 0; it < 4; ++it){
        int idx = it*256 + tid;
        int r = idx >> 4, c4 = idx & 15;
        float4 v = *(const float4*)(src + ((size_t)b*Nrows + g0 + r)*512 + f0 + c4*4);
        sF[r][c4*4+0]=v.x; sF[r][c4*4+1]=v.y; sF[r][c4*4+2]=v.z; sF[r][c4*4+3]=v.w;
    }
    __syncthreads();
    #pragma unroll
    for (int it = 0; it < 2; ++it){
        int idx = it*256 + tid;
        int dd = idx >> 3, c8 = idx & 7;
        unsigned short hi[8], lo[8];
        #pragma unroll
        for (int j = 0; j < 8; ++j){
            float x = sF[c8*8+j][dd];
            hi[j] = f2h(x);
            lo[j] = f2h(x - h2f(hi[j]));
        }
        size_t oo = ((size_t)b*512 + f0 + dd)*Nrows + g0 + c8*8;
        *(ushort4*)(dstHi+oo)   = ushort4{hi[0],hi[1],hi[2],hi[3]};
        *(ushort4*)(dstHi+oo+4) = ushort4{hi[4],hi[5],hi[6],hi[7]};
        *(ushort4*)(dstLo+oo)   = ushort4{lo[0],lo[1],lo[2],lo[3]};
        *(ushort4*)(dstLo+oo+4) = ushort4{lo[4],lo[5],lo[6],lo[7]};
    }
    // row-major hi/lo from the same tile
    #pragma unroll
    for (int it = 0; it < 2; ++it){
        int idx = it*256 + tid;
        int r = idx >> 3, c8 = idx & 7;
        unsigned short hi[8], lo[8];
        #pragma unroll
        for (int j = 0; j < 8; ++j){
            float x = sF[r][c8*8+j];
            hi[j] = f2h(x);
            lo[j] = f2h(x - h2f(hi[j]));
        }
        size_t oo = ((size_t)b*Nrows + g0 + r)*512 + f0 + c8*8;
        *(ushort4*)(rmHi+oo)   = ushort4{hi[0],hi[1],hi[2],hi[3]};
        *(ushort4*)(rmHi+oo+4) = ushort4{hi[4],hi[5],hi[6],hi[7]};
        *(ushort4*)(rmLo+oo)   = ushort4{lo[0],lo[1],lo[2],lo[3]};
        *(ushort4*)(rmLo+oo+4) = ushort4{lo[4],lo[5],lo[6],lo[7]};
    }
}

// ============ batched scores: all 3 attns' q and k scores in one launch ============
__global__ __launch_bounds__(256) void scores3_k(
    const unsigned short* __restrict__ g, const unsigned short* __restrict__ c,
    const unsigned short* __restrict__ q,
    const float* __restrict__ wa13, const float* __restrict__ wa23,
    float* __restrict__ qs3, float* __restrict__ ks3){
    int lane = threadIdx.x & 63;
    int grow = blockIdx.x*4 + (threadIdx.x >> 6);
    int b = grow / 4608; int r = grow - b*4608;
    const unsigned short* X; const float* wa; float* out; int n, oOff, rowsX;
    if (r < SEG){
        out = qs3;
        if (r < 1024)      { X=g; wa=wa13;        n=r;        oOff=0;    rowsX=NG; }
        else if (r < 1280) { X=q; wa=wa13+4096;   n=r-1024;   oOff=1024; rowsX=NQ; }
        else               { X=g; wa=wa13+8192;   n=r-1280;   oOff=1280; rowsX=NG; }
    } else {
        out = ks3; r -= SEG;
        if (r < 1024)      { X=c; wa=wa23;        n=r;        oOff=0;    rowsX=NC; }
        else if (r < 2048) { X=g; wa=wa23+4096;   n=r-1024;   oOff=1024; rowsX=NG; }
        else               { X=q; wa=wa23+8192;   n=r-2048;   oOff=2048; rowsX=NQ; }
    }
    const unsigned short* Xr = X + ((size_t)b*rowsX + n)*NFEAT;
    float p[NHEADS];
    #pragma unroll
    for (int h = 0; h < NHEADS; ++h) p[h] = 0.f;
    #pragma unroll
    for (int cc = 0; cc < 8; ++cc){
        float x = h2f(Xr[(cc<<6) + lane]);
        #pragma unroll
        for (int h = 0; h < NHEADS; ++h) p[h] += x * wa[(h<<9) + (cc<<6) + lane];
    }
    #pragma unroll
    for (int h = 0; h < NHEADS; ++h){
        float v = p[h];
        #pragma unroll
        for (int off = 32; off > 0; off >>= 1) v += __shfl_xor(v, off);
        if (lane == 0) out[((size_t)b*SEG + oOff + n)*8 + h] = v;
    }
}

// ============ batched WkT gemm: WkT3[b][512][2304] = {clip,gloss,question} @ WT3[a]^T ============
__global__ __launch_bounds__(256) void wkt3_mfma_k(
    const unsigned short* __restrict__ c, const unsigned short* __restrict__ g,
    const unsigned short* __restrict__ q, const unsigned short* __restrict__ WT3,
    unsigned short* __restrict__ WkT3){
    int b = blockIdx.z;
    int y = blockIdx.y;
    const unsigned short* kv; int rowsX, mOff, a;
    if (y < 16)      { a=0; kv=c; rowsX=NC; mOff=0; }
    else if (y < 32) { a=1; y-=16; kv=g; rowsX=NG; mOff=1024; }
    else             { a=2; y-=32; kv=q; rowsX=NQ; mOff=2048; }
    int r0 = y*64, c0 = blockIdx.x*64;
    int tid = threadIdx.x;
    __shared__ alignas(16) unsigned short aS[2][2048], bS[2][2048];
    const unsigned short* aG = kv + (size_t)b*rowsX*512;
    const unsigned short* bG = WT3 + (size_t)a*FF;
    int w = tid >> 6, lane = tid & 63;
    int lrow = lane & 15, quad = lane >> 4;
    int sr = tid >> 2;
    int sq = (tid & 3) ^ ((sr >> 1) & 3);
    size_t aRow = (size_t)(r0 + sr)*512 + sq*8;
    size_t bRow = (size_t)(c0 + sr)*512 + sq*8;
    v4f acc[4];
    #pragma unroll
    for (int cf = 0; cf < 4; ++cf) acc[cf] = (v4f)0.f;
    GLDS(aG + aRow, &aS[0][w << 9]);
    GLDS(bG + bRow, &bS[0][w << 9]);
    __syncthreads();
    int buf = 0;
    for (int s = 0; s < 16; ++s){
        if (s < 15){
            int ktn = (s + 1) << 5;
            GLDS(aG + aRow + ktn, &aS[buf^1][w << 9]);
            GLDS(bG + bRow + ktn, &bS[buf^1][w << 9]);
        }
        v8h af = *(const v8h*)&aS[buf][ldsw(w*16 + lrow, quad)];
        #pragma unroll
        for (int cf = 0; cf < 4; ++cf){
            v8h bf = *(const v8h*)&bS[buf][ldsw(cf*16 + lrow, quad)];
            acc[cf] = MFMA16(af, bf, acc[cf]);
        }
        __syncthreads();
        buf ^= 1;
    }
    #pragma unroll
    for (int cf = 0; cf < 4; ++cf){
        int colg = c0 + cf*16 + lrow;
        int rbase = r0 + w*16 + quad*4;
        ushort4 pk{f2h(acc[cf][0]), f2h(acc[cf][1]), f2h(acc[cf][2]), f2h(acc[cf][3])};
        *(ushort4*)&WkT3[((size_t)b*512 + colg)*SEG + mOff + rbase] = pk;
    }
}

// ============ merged colstat+finalize: all 3 attns, direct ksh/cmh/ish ============
// grid (36, 1, NB): x<16 a0 (m over clip, n over gloss), x<32 a1 (m gloss, n question),
// else a2 (m question, n gloss). Each block: 64 m-columns, full N loop.
__global__ __launch_bounds__(256) void colstat3b_k(
    const unsigned* __restrict__ bm_cg, const unsigned* __restrict__ bm_gq,
    const unsigned* __restrict__ bm_qg,
    const float* __restrict__ qs3, const float* __restrict__ ks3,
    float* __restrict__ ksh, float* __restrict__ cmh, float* __restrict__ ish){
    int x = blockIdx.x, b = blockIdx.z;
    const unsigned* bm; int Mrows, N, N32, mOff, qOff;
    if (x < 16)      { bm=bm_cg; Mrows=NC; N=NG; N32=NG/32; mOff=0;    qOff=0; }
    else if (x < 32) { x-=16; bm=bm_gq; Mrows=NG; N=NQ; N32=NQ/32; mOff=1024; qOff=1024; }
    else             { x-=32; bm=bm_qg; Mrows=NQ; N=NG; N32=NG/32; mOff=2048; qOff=1280; }
    int ml = threadIdx.x & 63; int m = x*64 + ml;
    int g = threadIdx.x >> 6;
    int len = N >> 2;
    int n0 = g*len;
    __shared__ float sQ[1024*8];
    {
        const float* qb = qs3 + ((size_t)b*SEG + qOff)*8;
        for (int t4 = threadIdx.x; t4 < N*2; t4 += 256)
            *(float4*)&sQ[t4*4] = *(const float4*)(qb + t4*4);
    }
    float ksv[8];
    size_t mo = ((size_t)b*SEG + mOff + m)*8;
    #pragma unroll
    for (int h = 0; h < 8; ++h) ksv[h] = ks3[mo+h];
    const unsigned* bmr = bm + ((size_t)b*Mrows + m)*N32 + (n0>>5);
    int nw = len >> 5;
    // pass 1: masked max of q over this thread's n-range
    float mx[8];
    #pragma unroll
    for (int h = 0; h < 8; ++h) mx[h] = -INFINITY;
    unsigned anyw = 0;
    __syncthreads();
    for (int wI = 0; wI < nw; ++wI){
        unsigned wd = bmr[wI];
        anyw |= wd;
        if (!wd) continue;
        int base = n0 + wI*32;
        for (int i2 = 0; i2 < 32; ++i2){
            if ((wd >> i2) & 1){
                const float* qr = &sQ[(base+i2)*8];
                #pragma unroll
                for (int h = 0; h < 8; ++h) mx[h] = fmaxf(mx[h], qr[h]);
            }
        }
    }
    __shared__ float scm[4][64][8], ssm[4][64][8];
    #pragma unroll
    for (int h = 0; h < 8; ++h) scm[g][ml][h] = anyw ? mx[h] : -INFINITY;
    __syncthreads();
    __shared__ float sCM[64][8];
    if (g == 0){
        #pragma unroll
        for (int h = 0; h < 8; ++h){
            float am = fmaxf(fmaxf(scm[0][ml][h], scm[1][ml][h]), fmaxf(scm[2][ml][h], scm[3][ml][h]));
            sCM[ml][h] = (am == -INFINITY) ? NEGV : lrelu(am + ksv[h]);
        }
    }
    __syncthreads();
    float CM[8];
    #pragma unroll
    for (int h = 0; h < 8; ++h) CM[h] = sCM[ml][h];
    // pass 2: denominator (off entries contribute exp(NEGV - CM): 0 if CM finite, 1 if all-masked)
    float s[8];
    #pragma unroll
    for (int h = 0; h < 8; ++h) s[h] = 0.f;
    for (int wI = 0; wI < nw; ++wI){
        unsigned wd = bmr[wI];
        int base = n0 + wI*32;
        for (int i2 = 0; i2 < 32; ++i2){
            bool on = (wd >> i2) & 1;
            const float* qr = &sQ[(base+i2)*8];
            #pragma unroll
            for (int h = 0; h < 8; ++h){
                float e = on ? lrelu(qr[h] + ksv[h]) : NEGV;
                s[h] += __expf(e - CM[h]);
            }
        }
    }
    #pragma unroll
    for (int h = 0; h < 8; ++h) ssm[g][ml][h] = s[h];
    __syncthreads();
    if (g == 0){
        #pragma unroll
        for (int h = 0; h < 8; ++h){
            float S = ssm[0][ml][h] + ssm[1][ml][h] + ssm[2][ml][h] + ssm[3][ml][h];
            size_t o = ((size_t)b*8 + h)*SEG + mOff + m;
            ksh[o] = ksv[h]; cmh[o] = CM[h]; ish[o] = 1.f/S;
        }
    }
}

// ============ 3-pass fusion MFMA: 64x64 tile, packed weights, GLDS staging ============
__global__ __launch_bounds__(256) void fusion3_k(
    const unsigned short* __restrict__ aHi, const unsigned short* __restrict__ aLo,
    const unsigned short* __restrict__ bHi, const unsigned short* __restrict__ bLo,
    const unsigned short* __restrict__ Whi, const unsigned short* __restrict__ Wlo,
    unsigned short* __restrict__ dst, unsigned short* __restrict__ dstLo,
    unsigned short* __restrict__ dstT, unsigned short* __restrict__ dstTLo,
    float* __restrict__ dstF, int rows){
    int nY = rows >> 6;
    int ppg = (nY * NB) >> 3;
    int F = blockIdx.x;
    int xcd = F & 7, t = F >> 3;
    int c0i = t / ppg;
    int p = xcd + ((t - c0i*ppg) << 3);
    int r0 = (p % nY) << 6, c0 = c0i << 6;
    int b = p / nY;
    int tid = threadIdx.x;
    __shared__ alignas(16) unsigned short aHs[2048], bHs[2048], aLs[2048], bLs[2048];
    __shared__ alignas(16) unsigned short wHs[8192], wLs[8192];
    size_t actOff = (size_t)b*rows*512;
    const unsigned short* aHG = aHi + actOff;
    const unsigned short* bHG = bHi + actOff;
    const unsigned short* aLG = aLo ? aLo + actOff : nullptr;
    const unsigned short* bLG = bLo ? bLo + actOff : nullptr;
    bool hasALo = (aLG != nullptr);
    bool hasBLo = (bLG != nullptr);
    int w = tid >> 6, lane = tid & 63;
    int wr = w >> 1, wc = w & 1;
    int lrow = lane & 15, quad = lane >> 4;
    int sr = tid >> 2;
    int sq = (tid & 3) ^ ((sr >> 1) & 3);
    size_t aRow = (size_t)(r0 + sr)*512 + sq*8;
    size_t wPk = (size_t)c0i*16*8192 + (size_t)sr*32 + sq*8;
    unsigned short* ldsA  = &aHs[w << 9];
    unsigned short* ldsB  = &bHs[w << 9];
    unsigned short* ldsAL = &aLs[w << 9];
    unsigned short* ldsBL = &bLs[w << 9];
    v4f accN[2][2], accF[2][2];
    #pragma unroll
    for (int r = 0; r < 2; ++r)
        #pragma unroll
        for (int cf = 0; cf < 2; ++cf){ accN[r][cf] = (v4f)0.f; accF[r][cf] = (v4f)0.f; }
    for (int kt = 0; kt < 512; kt += 32){
        __syncthreads();
        GLDS(aHG + aRow + kt, ldsA);
        GLDS(bHG + aRow + kt, ldsB);
        if (hasALo) GLDS(aLG + aRow + kt, ldsAL);
        if (hasBLo) GLDS(bLG + aRow + kt, ldsBL);
        size_t wk = wPk + (size_t)(kt >> 5)*8192;
        #pragma unroll
        for (int m = 0; m < 4; ++m){
            GLDS(Whi + wk + (m<<11), &wHs[(m<<11) + (w<<9)]);
            GLDS(Wlo + wk + (m<<11), &wLs[(m<<11) + (w<<9)]);
        }
        __syncthreads();
        v8h ah[2], bh[2], al[2], bl[2];
        #pragma unroll
        for (int r = 0; r < 2; ++r){
            int ao = ldsw(wr*32 + r*16 + lrow, quad);
            ah[r] = *(const v8h*)&aHs[ao];
            bh[r] = *(const v8h*)&bHs[ao];
            if (hasALo) al[r] = *(const v8h*)&aLs[ao];
            if (hasBLo) bl[r] = *(const v8h*)&bLs[ao];
        }
        #pragma unroll
        for (int cf = 0; cf < 2; ++cf){
            int wo = ldsw(wc*32 + cf*16 + lrow, quad);
            v8h w0 = *(const v8h*)&wHs[wo];
            v8h w1 = *(const v8h*)&wHs[2048 + wo];
            v8h w2 = *(const v8h*)&wHs[4096 + wo];
            v8h w3 = *(const v8h*)&wHs[6144 + wo];
            v8h l0 = *(const v8h*)&wLs[wo];
            v8h l1 = *(const v8h*)&wLs[2048 + wo];
            v8h l2 = *(const v8h*)&wLs[4096 + wo];
            v8h l3 = *(const v8h*)&wLs[6144 + wo];
            #pragma unroll
            for (int r = 0; r < 2; ++r){
                accN[r][cf] = MFMA16(ah[r], w0, accN[r][cf]);
                accN[r][cf] = MFMA16(bh[r], w1, accN[r][cf]);
                accF[r][cf] = MFMA16(ah[r], w2, accF[r][cf]);
                accF[r][cf] = MFMA16(bh[r], w3, accF[r][cf]);
                if (hasALo){ accN[r][cf] = MFMA16(al[r], w0, accN[r][cf]); accF[r][cf] = MFMA16(al[r], w2, accF[r][cf]); }
                if (hasBLo){ accN[r][cf] = MFMA16(bl[r], w1, accN[r][cf]); accF[r][cf] = MFMA16(bl[r], w3, accF[r][cf]); }
                accN[r][cf] = MFMA16(ah[r], l0, accN[r][cf]);
                accN[r][cf] = MFMA16(bh[r], l1, accN[r][cf]);
                accF[r][cf] = MFMA16(ah[r], l2, accF[r][cf]);
                accF[r][cf] = MFMA16(bh[r], l3, accF[r][cf]);
            }
        }
    }
    #pragma unroll
    for (int r = 0; r < 2; ++r)
        #pragma unroll
        for (int cf = 0; cf < 2; ++cf){
            int colg = c0 + wc*32 + cf*16 + lrow;
            int rbase = r0 + wr*32 + r*16 + quad*4;
            float o4[4];
            #pragma unroll
            for (int reg = 0; reg < 4; ++reg){
                float f = 1.f/(1.f + __expf(-accF[r][cf][reg]));
                size_t ai = (size_t)(rbase+reg)*512 + colg;
                float ao = h2f(aHG[ai]);
                if (aLG) ao += h2f(aLG[ai]);
                o4[reg] = f*accN[r][cf][reg] + (1.f - f)*ao;
                size_t oo = ((size_t)b*rows + rbase + reg)*512 + colg;
                unsigned short hv = f2h(o4[reg]);
                dst[oo] = hv;
                if (dstLo) dstLo[oo] = f2h(o4[reg] - h2f(hv));
                if (dstF) dstF[oo] = o4[reg];
            }
            if (dstT){
                unsigned short h0 = f2h(o4[0]), h1 = f2h(o4[1]), h2 = f2h(o4[2]), h3 = f2h(o4[3]);
                size_t to = ((size_t)b*512 + colg)*rows + rbase;
                *(ushort4*)&dstT[to] = ushort4{h0,h1,h2,h3};
                if (dstTLo)
                    *(ushort4*)&dstTLo[to] = ushort4{f2h(o4[0]-h2f(h0)), f2h(o4[1]-h2f(h1)),
                                                     f2h(o4[2]-h2f(h2)), f2h(o4[3]-h2f(h3))};
            }
        }
}

// ============ 1-pass fusion MFMA: double-buffered, single barrier per K-step ============
__global__ __launch_bounds__(256) void fusion1_k(
    const unsigned short* __restrict__ aHi, const unsigned short* __restrict__ aLo,
    const unsigned short* __restrict__ bHi,
    const unsigned short* __restrict__ Whi,
    unsigned short* __restrict__ dst, unsigned short* __restrict__ dstLo,
    float* __restrict__ dstF, int rows){
    int nY = rows >> 6;
    int ppg = (nY * NB) >> 3;
    int F = blockIdx.x;
    int xcd = F & 7, t = F >> 3;
    int c0i = t / ppg;
    int p = xcd + ((t - c0i*ppg) << 3);
    int r0 = (p % nY) << 6, c0 = c0i << 6;
    int b = p / nY;
    int tid = threadIdx.x;
    __shared__ alignas(16) unsigned short aHs[2][2048], bHs[2][2048];
    __shared__ alignas(16) unsigned short wHs[2][8192];
    size_t actOff = (size_t)b*rows*512;
    const unsigned short* aHG = aHi + actOff;
    const unsigned short* bHG = bHi + actOff;
    const unsigned short* aLG = aLo ? aLo + actOff : nullptr;
    int w = tid >> 6, lane = tid & 63;
    int wr = w >> 1, wc = w & 1;
    int lrow = lane & 15, quad = lane >> 4;
    int sr = tid >> 2;
    int sq = (tid & 3) ^ ((sr >> 1) & 3);
    size_t aRow = (size_t)(r0 + sr)*512 + sq*8;
    size_t wPk = (size_t)c0i*16*8192 + (size_t)sr*32 + sq*8;
    v4f accN[2][2], accF[2][2];
    #pragma unroll
    for (int r = 0; r < 2; ++r)
        #pragma unroll
        for (int cf = 0; cf < 2; ++cf){ accN[r][cf] = (v4f)0.f; accF[r][cf] = (v4f)0.f; }

    #define F1STAGE(bb, kk) do{ \
        GLDS(aHG + aRow + (kk), &aHs[bb][w << 9]); \
        GLDS(bHG + aRow + (kk), &bHs[bb][w << 9]); \
        size_t wk_ = wPk + (size_t)((kk) >> 5)*8192; \
        GLDS(Whi + wk_,          &wHs[bb][(0<<11) + (w<<9)]); \
        GLDS(Whi + wk_ + (1<<11), &wHs[bb][(1<<11) + (w<<9)]); \
        GLDS(Whi + wk_ + (2<<11), &wHs[bb][(2<<11) + (w<<9)]); \
        GLDS(Whi + wk_ + (3<<11), &wHs[bb][(3<<11) + (w<<9)]); \
    } while(0)

    F1STAGE(0, 0);
    __syncthreads();
    int buf = 0;
    for (int kt = 0; kt < 512; kt += 32){
        if (kt + 32 < 512) F1STAGE(buf^1, kt + 32);
        v8h ah[2], bh[2];
        #pragma unroll
        for (int r = 0; r < 2; ++r){
            int ao = ldsw(wr*32 + r*16 + lrow, quad);
            ah[r] = *(const v8h*)&aHs[buf][ao];
            bh[r] = *(const v8h*)&bHs[buf][ao];
        }
        #pragma unroll
        for (int cf = 0; cf < 2; ++cf){
            int wo = ldsw(wc*32 + cf*16 + lrow, quad);
            v8h w0 = *(const v8h*)&wHs[buf][wo];
            v8h w1 = *(const v8h*)&wHs[buf][2048 + wo];
            v8h w2 = *(const v8h*)&wHs[buf][4096 + wo];
            v8h w3 = *(const v8h*)&wHs[buf][6144 + wo];
            #pragma unroll
            for (int r = 0; r < 2; ++r){
                accN[r][cf] = MFMA16(ah[r], w0, accN[r][cf]);
                accN[r][cf] = MFMA16(bh[r], w1, accN[r][cf]);
                accF[r][cf] = MFMA16(ah[r], w2, accF[r][cf]);
                accF[r][cf] = MFMA16(bh[r], w3, accF[r][cf]);
            }
        }
        __syncthreads();
        buf ^= 1;
    }
    #undef F1STAGE
    #pragma unroll
    for (int r = 0; r < 2; ++r)
        #pragma unroll
        for (int cf = 0; cf < 2; ++cf){
            int colg = c0 + wc*32 + cf*16 + lrow;
            int rbase = r0 + wr*32 + r*16 + quad*4;
            #pragma unroll
            for (int reg = 0; reg < 4; ++reg){
                float f = 1.f/(1.f + __expf(-accF[r][cf][reg]));
                size_t ai = (size_t)(rbase+reg)*512 + colg;
                float ao = h2f(aHG[ai]);
                if (aLG) ao += h2f(aLG[ai]);
                float o = f*accN[r][cf][reg] + (1.f - f)*ao;
                size_t oo = ((size_t)b*rows + rbase + reg)*512 + colg;
                unsigned short hv = f2h(o);
                dst[oo] = hv;
                if (dstLo) dstLo[oo] = f2h(o - h2f(hv));
                if (dstF) dstF[oo] = o;
            }
        }
}

// ============ generic MFMA GEMM (64-row tiles, double-buffered) — gloss_same only ============
__global__ __launch_bounds__(256) void gemmT_mfma_k(
    const unsigned short* __restrict__ A, size_t aStride,
    const unsigned short* __restrict__ BT, const unsigned short* __restrict__ BT2, size_t bStride,
    int K, int rowsPB,
    unsigned short* __restrict__ outRM, unsigned short* __restrict__ outLo,
    unsigned short* __restrict__ outT){
    int b = blockIdx.z;
    int r0 = blockIdx.y*64, c0 = blockIdx.x*64;
    int tid = threadIdx.x;
    __shared__ alignas(16) unsigned short aS[2][2048], bS[2][2048];
    const unsigned short* aG = A + (size_t)b*aStride;
    const unsigned short* bG0 = BT + (size_t)b*bStride;
    const unsigned short* bG1 = BT2 ? BT2 + (size_t)b*bStride : nullptr;
    int w = tid >> 6, lane = tid & 63;
    int lrow = lane & 15, quad = lane >> 4;
    int sr = tid >> 2;
    int sq = (tid & 3) ^ ((sr >> 1) & 3);
    size_t aRow = (size_t)(r0 + sr)*K + sq*8;
    size_t bRow = (size_t)(c0 + sr)*K + sq*8;
    int spp = K >> 5;
    int nsteps = (BT2 ? 2 : 1)*spp;
    v4f acc[4];
    #pragma unroll
    for (int cf = 0; cf < 4; ++cf) acc[cf] = (v4f)0.f;
    GLDS(aG + aRow, &aS[0][w << 9]);
    GLDS(bG0 + bRow, &bS[0][w << 9]);
    __syncthreads();
    int buf = 0;
    for (int s = 0; s < nsteps; ++s){
        int sn = s + 1;
        if (sn < nsteps){
            int ktn = ((sn >= spp) ? (sn - spp) : sn) << 5;
            const unsigned short* bgn = (sn >= spp) ? bG1 : bG0;
            GLDS(aG + aRow + ktn, &aS[buf^1][w << 9]);
            GLDS(bgn + bRow + ktn, &bS[buf^1][w << 9]);
        }
        v8h af = *(const v8h*)&aS[buf][ldsw(w*16 + lrow, quad)];
        #pragma unroll
        for (int cf = 0; cf < 4; ++cf){
            v8h bf = *(const v8h*)&bS[buf][ldsw(cf*16 + lrow, quad)];
            acc[cf] = MFMA16(af, bf, acc[cf]);
        }
        __syncthreads();
        buf ^= 1;
    }
    #pragma unroll
    for (int cf = 0; cf < 4; ++cf){
        int colg = c0 + cf*16 + lrow;
        int rbase = r0 + w*16 + quad*4;
        if (outRM){
            #pragma unroll
            for (int reg = 0; reg < 4; ++reg){
                float v = acc[cf][reg];
                unsigned short hv = f2h(v);
                size_t oo = ((size_t)b*rowsPB + rbase + reg)*512 + colg;
                outRM[oo] = hv;
                if (outLo) outLo[oo] = f2h(v - h2f(hv));
            }
        }
        if (outT){
            ushort4 pk{f2h(acc[cf][0]), f2h(acc[cf][1]), f2h(acc[cf][2]), f2h(acc[cf][3])};
            *(ushort4*)&outT[((size_t)b*512 + colg)*rowsPB + rbase] = pk;
        }
    }
}

// ============ attention output MFMA: T1-swizzled grid, LDS stats, bitmask adj ============
__global__ __launch_bounds__(256) void attn_mfma_k(const unsigned* __restrict__ bmN, int M32,
    const float* __restrict__ qs3, int qOff,
    const float* __restrict__ ksh, const float* __restrict__ cmh, const float* __restrict__ ish,
    int mOff, const unsigned short* __restrict__ WkT3,
    unsigned short* __restrict__ outp, int N, int M){
    int nN0 = N >> 6;
    int F = blockIdx.x;
    int xcd = F & 7, t = F >> 3;
    int bh = xcd*4 + t/nN0;
    int n0 = (t % nN0) << 6;
    int b = bh >> 3, h = bh & 7;
    int tid = threadIdx.x;
    __shared__ unsigned short pS[2*64*LSTR];
    __shared__ alignas(16) unsigned short wS[2*2048];
    __shared__ float qsS[64];
    __shared__ alignas(16) float sKs[1024], sCm[1024], sIs[1024];
    const float* ksb = ksh + ((size_t)b*8 + h)*SEG + mOff;
    const float* cmb = cmh + ((size_t)b*8 + h)*SEG + mOff;
    const float* isb = ish + ((size_t)b*8 + h)*SEG + mOff;
    const unsigned short* wkb = WkT3 + ((size_t)b*512 + h*64)*SEG + mOff;
    int w = tid >> 6, lane = tid & 63;
    int lrow = lane & 15, quad = lane >> 4;
    int pn = tid >> 2, pm = (tid & 3)*8;
    int sr = tid >> 2;
    int sq = (tid & 3) ^ ((sr >> 1) & 3);
    for (int o = w*256; o < M; o += 1024){
        GLDS(ksb + o + lane*4, &sKs[o]);
        GLDS(cmb + o + lane*4, &sCm[o]);
        GLDS(isb + o + lane*4, &sIs[o]);
    }
    if (tid < 64) qsS[tid] = qs3[((size_t)b*SEG + qOff + n0 + tid)*8 + h];
    const unsigned* bmrow = bmN + ((size_t)b*N + n0 + pn)*M32;
    v4f acc[4];
    #pragma unroll
    for (int cf = 0; cf < 4; ++cf) acc[cf] = (v4f)0.f;
    uint2 CW = *(const uint2*)(bmrow);
    uint2 NW;
    __syncthreads();
    float qv = qsS[pn];
    for (int mt = 0; mt < M; mt += 64){
        int mtB = mt + 32;
        int mtN = (mt + 64 < M) ? (mt + 64) : 0;
        GLDS(wkb + (size_t)sr*SEG + mt + sq*8, &wS[w << 9]);
        {
            unsigned bb = (CW.x >> pm) & 0xffu;
            float4 k0 = *(const float4*)&sKs[mt+pm], k1 = *(const float4*)&sKs[mt+pm+4];
            float4 c0 = *(const float4*)&sCm[mt+pm], c1 = *(const float4*)&sCm[mt+pm+4];
            float4 i0 = *(const float4*)&sIs[mt+pm], i1 = *(const float4*)&sIs[mt+pm+4];
            float p[8];
            const float* kk0 = &k0.x; const float* kk1 = &k1.x;
            const float* cc0 = &c0.x; const float* cc1 = &c1.x;
            const float* ii0 = &i0.x; const float* ii1 = &i1.x;
            #pragma unroll
            for (int j = 0; j < 4; ++j){
                float e = ((bb >> j) & 1) ? lrelu(qv + kk0[j]) : NEGV;
                p[j] = __expf(e - cc0[j]) * ii0[j];
            }
            #pragma unroll
            for (int j = 0; j < 4; ++j){
                float e = ((bb >> (4+j)) & 1) ? lrelu(qv + kk1[j]) : NEGV;
                p[4+j] = __expf(e - cc1[j]) * ii1[j];
            }
            *(ushort4*)&pS[pn*LSTR + pm]     = ushort4{f2h(p[0]), f2h(p[1]), f2h(p[2]), f2h(p[3])};
            *(ushort4*)&pS[pn*LSTR + pm + 4] = ushort4{f2h(p[4]), f2h(p[5]), f2h(p[6]), f2h(p[7])};
        }
        __syncthreads();
        {
            v8h af = *(const v8h*)&pS[(w*16 + lrow)*LSTR + quad*8];
            #pragma unroll
            for (int cf = 0; cf < 4; ++cf){
                v8h bf = *(const v8h*)&wS[ldsw(cf*16 + lrow, quad)];
                acc[cf] = MFMA16(af, bf, acc[cf]);
            }
        }
        GLDS(wkb + (size_t)sr*SEG + mtB + sq*8, &wS[2048 + (w << 9)]);
        NW = *(const uint2*)(bmrow + (mtN >> 5));
        {
            unsigned bb = (CW.y >> pm) & 0xffu;
            float4 k0 = *(const float4*)&sKs[mtB+pm], k1 = *(const float4*)&sKs[mtB+pm+4];
            float4 c0 = *(const float4*)&sCm[mtB+pm], c1 = *(const float4*)&sCm[mtB+pm+4];
            float4 i0 = *(const float4*)&sIs[mtB+pm], i1 = *(const float4*)&sIs[mtB+pm+4];
            float p[8];
            const float* kk0 = &k0.x; const float* kk1 = &k1.x;
            const float* cc0 = &c0.x; const float* cc1 = &c1.x;
            const float* ii0 = &i0.x; const float* ii1 = &i1.x;
            #pragma unroll
            for (int j = 0; j < 4; ++j){
                float e = ((bb >> j) & 1) ? lrelu(qv + kk0[j]) : NEGV;
                p[j] = __expf(e - cc0[j]) * ii0[j];
            }
            #pragma unroll
            for (int j = 0; j < 4; ++j){
                float e = ((bb >> (4+j)) & 1) ? lrelu(qv + kk1[j]) : NEGV;
                p[4+j] = __expf(e - cc1[j]) * ii1[j];
            }
            *(ushort4*)&pS[2304 + pn*LSTR + pm]     = ushort4{f2h(p[0]), f2h(p[1]), f2h(p[2]), f2h(p[3])};
            *(ushort4*)&pS[2304 + pn*LSTR + pm + 4] = ushort4{f2h(p[4]), f2h(p[5]), f2h(p[6]), f2h(p[7])};
        }
        __syncthreads();
        {
            v8h af = *(const v8h*)&pS[2304 + (w*16 + lrow)*LSTR + quad*8];
            #pragma unroll
            for (int cf = 0; cf < 4; ++cf){
                v8h bf = *(const v8h*)&wS[2048 + ldsw(cf*16 + lrow, quad)];
                acc[cf] = MFMA16(af, bf, acc[cf]);
            }
        }
        CW = NW;
    }
    #pragma unroll
    for (int cf = 0; cf < 4; ++cf){
        int colg = h*64 + cf*16 + lrow;
        int rbase = n0 + w*16 + quad*4;
        #pragma unroll
        for (int reg = 0; reg < 4; ++reg){
            float v = acc[cf][reg];
            v = (v > 0.f) ? v : (__expf(v) - 1.f);
            outp[((size_t)b*N + rbase + reg)*512 + colg] = f2h(v);
        }
    }
}

extern "C" void kernel_launch(void* const* d_in, const int* in_sizes, int n_in,
                              void* d_out, int out_size, void* d_ws, size_t ws_size,
                              hipStream_t stream){
    const float* in_gloss = (const float*)d_in[0];
    const float* in_clip  = (const float*)d_in[1];
    const float* in_q     = (const float*)d_in[2];
    const int*   adj_gc   = (const int*)d_in[3];
    const int*   adj_gq   = (const int*)d_in[4];
    const float* c2gW  = (const float*)d_in[5];
    const float* c2ga1 = (const float*)d_in[6];
    const float* c2ga2 = (const float*)d_in[7];
    const float* g2qW  = (const float*)d_in[8];
    const float* g2qa1 = (const float*)d_in[9];
    const float* g2qa2 = (const float*)d_in[10];
    const float* q2gW  = (const float*)d_in[11];
    const float* q2ga1 = (const float*)d_in[12];
    const float* q2ga2 = (const float*)d_in[13];
    const float* fusW  = (const float*)d_in[14];
    const float* fusU  = (const float*)d_in[15];
    const float* fusWf = (const float*)d_in[16];
    const float* fusUf = (const float*)d_in[17];
    float* out = (float*)d_out;
    float* out_gloss = out;
    float* out_clip  = out + (size_t)NB*NG*NFEAT;
    float* out_q     = out + (size_t)NB*NG*NFEAT*2;

    char* wsB = (char*)d_ws;
    size_t off = 0;
    auto alloc = [&](size_t bytes){ void* p = wsB + off; off += (bytes + 255) & ~(size_t)255; return p; };
    float* wa13  = (float*)alloc(3*4096*4);
    float* wa23  = (float*)alloc(3*4096*4);
    float* qs3   = (float*)alloc((size_t)NB*SEG*8*4);
    float* ks3   = (float*)alloc((size_t)NB*SEG*8*4);
    float* ksh3  = (float*)alloc((size_t)NB*8*SEG*4);
    float* cmh3  = (float*)alloc((size_t)NB*8*SEG*4);
    float* ish3  = (float*)alloc((size_t)NB*8*SEG*4);
    unsigned short* WflatT3 = (unsigned short*)alloc((size_t)3*FF*2);
    unsigned short* WkT3    = (unsigned short*)alloc((size_t)NB*512*SEG*2);
    unsigned short* wtAll   = (unsigned short*)alloc((size_t)32*FF*2);
    unsigned short* wtAllLo = (unsigned short*)alloc((size_t)32*FF*2);
    unsigned short* adjTgc  = (unsigned short*)alloc((size_t)NB*NC*NG*2);
    unsigned short* g_bf0   = (unsigned short*)alloc((size_t)NB*NG*NFEAT*2);
    unsigned short* gLo0    = (unsigned short*)alloc((size_t)NB*NG*NFEAT*2);
    unsigned short* g_bf1   = (unsigned short*)alloc((size_t)NB*NG*NFEAT*2);
    unsigned short* gLo1    = (unsigned short*)alloc((size_t)NB*NG*NFEAT*2);
    unsigned short* gT      = (unsigned short*)alloc((size_t)NB*NFEAT*NG*2);
    unsigned short* gTlo    = (unsigned short*)alloc((size_t)NB*NFEAT*NG*2);
    unsigned short* gA_bf   = (unsigned short*)alloc((size_t)NB*NG*NFEAT*2);
    unsigned short* gALo    = (unsigned short*)alloc((size_t)NB*NG*NFEAT*2);
    unsigned short* c_bf0   = (unsigned short*)alloc((size_t)NB*NC*NFEAT*2);
    unsigned short* cLo0    = (unsigned short*)alloc((size_t)NB*NC*NFEAT*2);
    unsigned short* c_bf1   = (unsigned short*)alloc((size_t)NB*NC*NFEAT*2);
    unsigned short* cLo1    = (unsigned short*)alloc((size_t)NB*NC*NFEAT*2);
    unsigned short* q_bf0   = (unsigned short*)alloc((size_t)NB*NQ*NFEAT*2);
    unsigned short* q_bf1   = (unsigned short*)alloc((size_t)NB*NQ*NFEAT*2);
    unsigned short* agg_bf  = (unsigned short*)alloc((size_t)NB*NG*NFEAT*2);
    unsigned short* aggLo   = (unsigned short*)alloc((size_t)NB*NG*NFEAT*2);
    int* adjTgq = (int*)alloc((size_t)NB*NQ*NG*4);
    unsigned* bm_gc = (unsigned*)alloc((size_t)NB*NG*(NC/32)*4);
    unsigned* bm_cg = (unsigned*)alloc((size_t)NB*NC*(NG/32)*4);
    unsigned* bm_gq = (unsigned*)alloc((size_t)NB*NG*(NQ/32)*4);
    unsigned* bm_qg = (unsigned*)alloc((size_t)NB*NQ*(NG/32)*4);
    (void)ws_size; (void)in_sizes; (void)n_in; (void)out_size;

    const size_t HFD = (size_t)NHEADS*NFEAT*HDIM;
    const size_t HD  = (size_t)NHEADS*HDIM;

    // ---- prep ----
    wtT_k<<<2048, 256, 0, stream>>>(fusW, fusU, fusWf, fusUf, wtAll, wtAllLo);
    adjT_h_k<<<dim3(NC/64, NG/64, NB), 256, 0, stream>>>(adj_gc, adjTgc,
        (unsigned long long*)bm_gc, (unsigned long long*)bm_cg);
    adjT_int_k<<<dim3(NQ/64, NG/64, NB), 256, 0, stream>>>(adj_gq, adjTgq,
        (unsigned long long*)bm_gq, (unsigned long long*)bm_qg);
    cvt_hl_k<<<(NB*NC*NFEAT)/2048, 256, 0, stream>>>(in_clip,  c_bf0, cLo0);
    cvt_h_k<<<(NB*NQ*NFEAT)/2048, 256, 0, stream>>>(in_q,     q_bf0);
    actT_hl_k<<<dim3(8, NG/64, NB), 256, 0, stream>>>(in_gloss, gT, gTlo, g_bf0, gLo0, NG);

    auto run_fusion = [&](const unsigned short* a, const unsigned short* aLo,
                          const unsigned short* bb, const unsigned short* bLo, int rows,
                          int l, int i, int npass,
                          unsigned short* dst, unsigned short* dstLo,
                          unsigned short* dstT, unsigned short* dstTLo, float* dstF){
        const unsigned short* Whi = wtAll   + (size_t)((l*4 + i)*4)*FF;
        const unsigned short* Wlo = wtAllLo + (size_t)((l*4 + i)*4)*FF;
        if (npass == 3)
            fusion3_k<<<dim3(8*(rows/64)*NB), 256, 0, stream>>>(
                a, aLo, bb, bLo, Whi, Wlo, dst, dstLo, dstT, dstTLo, dstF, rows);
        else
            fusion1_k<<<dim3(8*(rows/64)*NB), 256, 0, stream>>>(
                a, aLo, bb, Whi, dst, dstLo, dstF, rows);
    };

    for (int l = 0; l < 2; ++l){
        const unsigned short* g_cur = (l == 0) ? g_bf0 : g_bf1;
        const unsigned short* gLoC  = (l == 0) ? gLo0  : gLo1;
        const unsigned short* c_cur = (l == 0) ? c_bf0 : c_bf1;
        const unsigned short* cLoC  = (l == 0) ? cLo0  : cLo1;
        const unsigned short* q_cur = (l == 0) ? q_bf0 : q_bf1;
        unsigned short* g_nxt = (l == 0) ? g_bf1 : g_bf0;
        unsigned short* gLoN  = (l == 0) ? gLo1  : nullptr;
        unsigned short* c_nxt = (l == 0) ? c_bf1 : c_bf0;
        unsigned short* cLoN  = (l == 0) ? cLo1  : nullptr;
        unsigned short* q_nxt = (l == 0) ? q_bf1 : q_bf0;
        float* gF = (l == 1) ? out_gloss : nullptr;
        float* cF = (l == 1) ? out_clip  : nullptr;
        float* qF = (l == 1) ? out_q     : nullptr;

        // ---- batched attention prep (depends only on layer inputs) ----
        prep_attnW3_k<<<240, 256, 0, stream>>>(
            c2gW + l*HFD, c2ga1 + l*HD, c2ga2 + l*HD,
            g2qW + l*HFD, g2qa1 + l*HD, g2qa2 + l*HD,
            q2gW + l*HFD, q2ga1 + l*HD, q2ga2 + l*HD,
            WflatT3, wa13, wa23);
        scores3_k<<<(NB*4608)/4, 256, 0, stream>>>(g_cur, c_cur, q_cur, wa13, wa23, qs3, ks3);
        wkt3_mfma_k<<<dim3(8, 36, NB), 256, 0, stream>>>(c_cur, g_cur, q_cur, WflatT3, WkT3);
        colstat3b_k<<<dim3(36, 1, NB), 256, 0, stream>>>(bm_cg, bm_gq, bm_qg, qs3, ks3,
                                                         ksh3, cmh3, ish3);

        // gloss_same = adj_gc^T @ gloss  (hi/lo B, hi/lo out)
        gemmT_mfma_k<<<dim3(8, NC/64, NB), 256, 0, stream>>>(adjTgc, (size_t)NC*NG, gT, gTlo,
                                                             (size_t)512*NG, NG, NC,
                                                             agg_bf, aggLo, nullptr);
        // clip_1 (3-pass hi/lo)
        run_fusion(c_cur, cLoC, agg_bf, aggLo, NC, l, 0, 3,
                   c_nxt, cLoN, nullptr, nullptr, cF);
        // clip_agg = attn0(q=gloss, kv=clip)
        attn_mfma_k<<<(NG/64)*32, 256, 0, stream>>>(bm_gc, NC/32, qs3, 0, ksh3, cmh3, ish3, 0,
                                                    WkT3, agg_bf, NG, NC);
        // gloss_1 (single pass; aLo used for exact gate residual)
        run_fusion(g_cur, gLoC, agg_bf, nullptr, NG, l, 1, 1,
                   gA_bf, gALo, nullptr, nullptr, nullptr);
        // gloss_agg = attn1(q=question, kv=gloss)
        attn_mfma_k<<<(NQ/64)*32, 256, 0, stream>>>(bm_qg, NG/32, qs3, 1024, ksh3, cmh3, ish3, 1024,
                                                    WkT3, agg_bf, NQ, NG);
        // question_1 (single pass)
        run_fusion(q_cur, nullptr, agg_bf, nullptr, NQ, l, 2, 1,
                   q_nxt, nullptr, nullptr, nullptr, qF);
        // question_agg = attn2(q=gloss, kv=question)
        attn_mfma_k<<<(NG/64)*32, 256, 0, stream>>>(bm_gq, NQ/32, qs3, 1280, ksh3, cmh3, ish3, 2048,
                                                    WkT3, agg_bf, NG, NQ);
        // gloss_2 (3-pass; emit hi/lo + transposed hi/lo for next layer's gloss_same)
        run_fusion(gA_bf, gALo, agg_bf, nullptr, NG, l, 3, 3,
                   g_nxt, gLoN, (l == 0) ? gT : nullptr, (l == 0) ? gTlo : nullptr, gF);
    }
}

// Round 7
// 688.134 us; speedup vs baseline: 1.3166x; 1.3166x over previous
//
#include <hip/hip_runtime.h>
#include <math.h>

#define NFEAT 512
#define NHEADS 8
#define HDIM 64
#define NB 4
#define NG 1024
#define NC 1024
#define NQ 256
#define NEGV -9e15f
#define CHUNKS 16
#define FF ((size_t)NFEAT*NFEAT)
#define LSTR 36   // LDS row stride (ushorts) for reg-written P tiles only
#define SEG 2304  // segmented attn rows per batch

typedef _Float16 v8h __attribute__((ext_vector_type(8)));
typedef float v4f __attribute__((ext_vector_type(4)));
#define MFMA16(a,b,c) __builtin_amdgcn_mfma_f32_16x16x32_f16((a),(b),(c),0,0,0)

// async global->LDS, 16B/lane, lane-linear LDS dest (wave-uniform base + lane*16)
#define GLDS(g, l) __builtin_amdgcn_global_load_lds( \
    (__attribute__((address_space(1))) void*)(g), \
    (__attribute__((address_space(3))) void*)(l), 16, 0, 0)

// XOR swizzle for 64B-row linear LDS tiles: physical 16B slot = quad ^ ((row>>1)&3).
__device__ __forceinline__ int ldsw(int row, int quad){
    return row*32 + (((quad) ^ ((row>>1)&3)) << 3);
}

__device__ __forceinline__ float lrelu(float x){ return fmaxf(x, 0.2f*x); }
__device__ __forceinline__ unsigned short f2h(float x){ union{_Float16 h; unsigned short u;} v; v.h = (_Float16)x; return v.u; }
__device__ __forceinline__ float h2f(unsigned short u){ union{_Float16 h; unsigned short u;} v; v.u = u; return (float)v.h; }

// ============ prep: fp32 -> fp16 flat ============
__global__ __launch_bounds__(256) void cvt_h_k(const float* __restrict__ src, unsigned short* __restrict__ dst){
    int idx = blockIdx.x*256 + threadIdx.x;
    const float4* s = (const float4*)(src + (size_t)idx*8);
    float4 a = s[0], b = s[1];
    ushort4 p0{f2h(a.x),f2h(a.y),f2h(a.z),f2h(a.w)};
    ushort4 p1{f2h(b.x),f2h(b.y),f2h(b.z),f2h(b.w)};
    *(ushort4*)(dst + (size_t)idx*8) = p0;
    *(ushort4*)(dst + (size_t)idx*8 + 4) = p1;
}

// ============ prep: fp32 -> fp16 hi/lo flat ============
__global__ __launch_bounds__(256) void cvt_hl_k(const float* __restrict__ src,
    unsigned short* __restrict__ dstHi, unsigned short* __restrict__ dstLo){
    int idx = blockIdx.x*256 + threadIdx.x;
    const float4* s = (const float4*)(src + (size_t)idx*8);
    float4 a = s[0], b = s[1];
    float x[8] = {a.x,a.y,a.z,a.w,b.x,b.y,b.z,b.w};
    unsigned short hi[8], lo[8];
    #pragma unroll
    for (int j = 0; j < 8; ++j){ hi[j] = f2h(x[j]); lo[j] = f2h(x[j] - h2f(hi[j])); }
    *(ushort4*)(dstHi + (size_t)idx*8)     = ushort4{hi[0],hi[1],hi[2],hi[3]};
    *(ushort4*)(dstHi + (size_t)idx*8 + 4) = ushort4{hi[4],hi[5],hi[6],hi[7]};
    *(ushort4*)(dstLo + (size_t)idx*8)     = ushort4{lo[0],lo[1],lo[2],lo[3]};
    *(ushort4*)(dstLo + (size_t)idx*8 + 4) = ushort4{lo[4],lo[5],lo[6],lo[7]};
}

// ============ prep: fusion weights -> PACKED transposed fp16 hi/lo ============
// packed layout per group li: [c0i(8)][ktI(16)][mat(4)][row64][k32]
__global__ __launch_bounds__(256) void wtT_k(const float* __restrict__ w0, const float* __restrict__ w1,
    const float* __restrict__ w2, const float* __restrict__ w3,
    unsigned short* __restrict__ dstHi, unsigned short* __restrict__ dstLo){
    int bx = blockIdx.x;
    int mat = bx >> 6, t = bx & 63;
    int a = mat & 3, li = mat >> 2;
    const float* src = (a==0?w0:a==1?w1:a==2?w2:w3) + (size_t)li*FF;
    int fo0 = (t>>3)*64, fi0 = (t&7)*64;
    __shared__ float sT[64][65];
    int tid = threadIdx.x;
    #pragma unroll
    for (int it = 0; it < 4; ++it){
        int idx = it*256 + tid;
        int r = idx >> 4, c4 = idx & 15;
        float4 v = *(const float4*)(src + (size_t)(fi0+r)*512 + fo0 + c4*4);
        sT[r][c4*4+0]=v.x; sT[r][c4*4+1]=v.y; sT[r][c4*4+2]=v.z; sT[r][c4*4+3]=v.w;
    }
    __syncthreads();
    #pragma unroll
    for (int it = 0; it < 2; ++it){
        int idx = it*256 + tid;
        int dd = idx >> 3, c8 = idx & 7;
        unsigned short hi[8], lo[8];
        #pragma unroll
        for (int j = 0; j < 8; ++j){
            float x = sT[c8*8+j][dd];
            hi[j] = f2h(x);
            lo[j] = f2h(x - h2f(hi[j]));
        }
        int ktI = (fi0 >> 5) + (c8 >> 2);
        int k31 = (c8 & 3)*8;
        size_t oo = (size_t)li*4*FF + ((((size_t)(fo0>>6)*16 + ktI)*4 + a)*64 + dd)*32 + k31;
        *(ushort4*)(dstHi+oo)   = ushort4{hi[0],hi[1],hi[2],hi[3]};
        *(ushort4*)(dstHi+oo+4) = ushort4{hi[4],hi[5],hi[6],hi[7]};
        *(ushort4*)(dstLo+oo)   = ushort4{lo[0],lo[1],lo[2],lo[3]};
        *(ushort4*)(dstLo+oo+4) = ushort4{lo[4],lo[5],lo[6],lo[7]};
    }
}

// ============ prep: 3 attn W repacks (blocks 0..191) + wa vectors (blocks 192..239) ============
__global__ __launch_bounds__(256) void prep_attnW3_k(
    const float* __restrict__ W0, const float* __restrict__ a10, const float* __restrict__ a20,
    const float* __restrict__ W1, const float* __restrict__ a11, const float* __restrict__ a21,
    const float* __restrict__ W2, const float* __restrict__ a12, const float* __restrict__ a22,
    unsigned short* __restrict__ WT3, float* __restrict__ wa13, float* __restrict__ wa23){
    int bx = blockIdx.x;
    int tid = threadIdx.x;
    if (bx >= 192){
        int r = bx - 192;
        int a = r >> 4;
        const float* W  = (a==0?W0:a==1?W1:W2);
        const float* a1 = (a==0?a10:a==1?a11:a12);
        const float* a2 = (a==0?a20:a==1?a21:a22);
        int idx = (r & 15)*256 + tid;
        int h = idx >> 9;
        const float* Wp = W + (size_t)idx*64;
        float s1 = 0.f, s2 = 0.f;
        #pragma unroll
        for (int d = 0; d < 64; ++d){ float w = Wp[d]; s1 += w*a1[(h<<6)+d]; s2 += w*a2[(h<<6)+d]; }
        wa13[a*4096 + idx] = s1; wa23[a*4096 + idx] = s2;
        return;
    }
    int a = bx >> 6, bxl = bx & 63;
    const float* W = (a==0?W0:a==1?W1:W2);
    unsigned short* WT = WT3 + (size_t)a*FF;
    int h = bxl >> 3, f0 = (bxl & 7)*64;
    __shared__ float sT[64][65];
    #pragma unroll
    for (int it = 0; it < 4; ++it){
        int idx = it*256 + tid;
        int r = idx >> 4, c4 = idx & 15;
        float4 v = *(const float4*)(W + ((size_t)h*512 + f0 + r)*64 + c4*4);
        sT[r][c4*4+0]=v.x; sT[r][c4*4+1]=v.y; sT[r][c4*4+2]=v.z; sT[r][c4*4+3]=v.w;
    }
    __syncthreads();
    #pragma unroll
    for (int it = 0; it < 2; ++it){
        int idx = it*256 + tid;
        int dd = idx >> 3, c8 = idx & 7;
        ushort4 p0{f2h(sT[c8*8+0][dd]),f2h(sT[c8*8+1][dd]),f2h(sT[c8*8+2][dd]),f2h(sT[c8*8+3][dd])};
        ushort4 p1{f2h(sT[c8*8+4][dd]),f2h(sT[c8*8+5][dd]),f2h(sT[c8*8+6][dd]),f2h(sT[c8*8+7][dd])};
        unsigned short* o = WT + ((size_t)h*64 + dd)*512 + f0 + c8*8;
        *(ushort4*)o = p0; *(ushort4*)(o+4) = p1;
    }
}

// ============ prep: adj_gc int -> adjT fp16 [b][c][g] + bitmasks both orientations ============
__global__ __launch_bounds__(256) void adjT_h_k(const int* __restrict__ adj, unsigned short* __restrict__ dst,
    unsigned long long* __restrict__ bm_gc, unsigned long long* __restrict__ bm_cg){
    int b = blockIdx.z;
    int c0 = blockIdx.x*64, g0 = blockIdx.y*64;
    __shared__ int sI[64][65];
    int tid = threadIdx.x;
    #pragma unroll
    for (int it = 0; it < 4; ++it){
        int idx = it*256 + tid;
        int r = idx >> 4, c4 = idx & 15;
        int4 v = *(const int4*)(adj + ((size_t)b*NG + g0 + r)*NC + c0 + c4*4);
        sI[r][c4*4+0]=v.x; sI[r][c4*4+1]=v.y; sI[r][c4*4+2]=v.z; sI[r][c4*4+3]=v.w;
    }
    __syncthreads();
    int wv = tid >> 6, lane = tid & 63;
    #pragma unroll
    for (int it = 0; it < 2; ++it){
        int idx = it*256 + tid;
        int dd = idx >> 3, c8 = idx & 7;
        ushort4 p0, p1;
        #pragma unroll
        for (int j = 0; j < 4; ++j) (&p0.x)[j] = sI[c8*8+j][dd] > 0 ? (unsigned short)0x3C00 : (unsigned short)0;
        #pragma unroll
        for (int j = 0; j < 4; ++j) (&p1.x)[j] = sI[c8*8+4+j][dd] > 0 ? (unsigned short)0x3C00 : (unsigned short)0;
        unsigned short* o = dst + ((size_t)b*NC + c0 + dd)*NG + g0 + c8*8;
        *(ushort4*)o = p0; *(ushort4*)(o+4) = p1;
    }
    // bitmasks from the tile: bm_gc rows over g (bits = c), bm_cg rows over c (bits = g)
    #pragma unroll
    for (int rr = wv; rr < 64; rr += 4){
        unsigned long long m = __ballot(sI[rr][lane] > 0);
        if (lane == 0) bm_gc[((size_t)b*NG + g0 + rr)*(NC/64) + (c0>>6)] = m;
    }
    #pragma unroll
    for (int cc = wv; cc < 64; cc += 4){
        unsigned long long m = __ballot(sI[lane][cc] > 0);
        if (lane == 0) bm_cg[((size_t)b*NC + c0 + cc)*(NG/64) + (g0>>6)] = m;
    }
}

// ============ prep: adj_gq int -> adjT int [b][q][g] + bitmasks both orientations ============
__global__ __launch_bounds__(256) void adjT_int_k(const int* __restrict__ adj, int* __restrict__ dst,
    unsigned long long* __restrict__ bm_gq, unsigned long long* __restrict__ bm_qg){
    int b = blockIdx.z;
    int q0 = blockIdx.x*64, g0 = blockIdx.y*64;
    __shared__ int sI[64][65];
    int tid = threadIdx.x;
    #pragma unroll
    for (int it = 0; it < 4; ++it){
        int idx = it*256 + tid;
        int r = idx >> 4, c4 = idx & 15;
        int4 v = *(const int4*)(adj + ((size_t)b*NG + g0 + r)*NQ + q0 + c4*4);
        sI[r][c4*4+0]=v.x; sI[r][c4*4+1]=v.y; sI[r][c4*4+2]=v.z; sI[r][c4*4+3]=v.w;
    }
    __syncthreads();
    int wv = tid >> 6, lane = tid & 63;
    #pragma unroll
    for (int it = 0; it < 4; ++it){
        int idx = it*256 + tid;
        int dd = idx >> 4, c4 = idx & 15;
        int4 v{sI[c4*4+0][dd], sI[c4*4+1][dd], sI[c4*4+2][dd], sI[c4*4+3][dd]};
        *(int4*)(dst + ((size_t)b*NQ + q0 + dd)*NG + g0 + c4*4) = v;
    }
    #pragma unroll
    for (int rr = wv; rr < 64; rr += 4){
        unsigned long long m = __ballot(sI[rr][lane] > 0);
        if (lane == 0) bm_gq[((size_t)b*NG + g0 + rr)*(NQ/64) + (q0>>6)] = m;
    }
    #pragma unroll
    for (int cc = wv; cc < 64; cc += 4){
        unsigned long long m = __ballot(sI[lane][cc] > 0);
        if (lane == 0) bm_qg[((size_t)b*NQ + q0 + cc)*(NG/64) + (g0>>6)] = m;
    }
}

// ============ prep: gloss fp32 -> transposed hi/lo [b][512][N] AND row-major hi/lo ============
__global__ __launch_bounds__(256) void actT_hl_k(const float* __restrict__ src,
    unsigned short* __restrict__ dstHi, unsigned short* __restrict__ dstLo,
    unsigned short* __restrict__ rmHi, unsigned short* __restrict__ rmLo, int Nrows){
    int b = blockIdx.z;
    int f0 = blockIdx.x*64, g0 = blockIdx.y*64;
    __shared__ float sF[64][65];
    int tid = threadIdx.x;
    #pragma unroll
    for (int it = 0; it < 4; ++it){
        int idx = it*256 + tid;
        int r = idx >> 4, c4 = idx & 15;
        float4 v = *(const float4*)(src + ((size_t)b*Nrows + g0 + r)*512 + f0 + c4*4);
        sF[r][c4*4+0]=v.x; sF[r][c4*4+1]=v.y; sF[r][c4*4+2]=v.z; sF[r][c4*4+3]=v.w;
    }
    __syncthreads();
    #pragma unroll
    for (int it = 0; it < 2; ++it){
        int idx = it*256 + tid;
        int dd = idx >> 3, c8 = idx & 7;
        unsigned short hi[8], lo[8];
        #pragma unroll
        for (int j = 0; j < 8; ++j){
            float x = sF[c8*8+j][dd];
            hi[j] = f2h(x);
            lo[j] = f2h(x - h2f(hi[j]));
        }
        size_t oo = ((size_t)b*512 + f0 + dd)*Nrows + g0 + c8*8;
        *(ushort4*)(dstHi+oo)   = ushort4{hi[0],hi[1],hi[2],hi[3]};
        *(ushort4*)(dstHi+oo+4) = ushort4{hi[4],hi[5],hi[6],hi[7]};
        *(ushort4*)(dstLo+oo)   = ushort4{lo[0],lo[1],lo[2],lo[3]};
        *(ushort4*)(dstLo+oo+4) = ushort4{lo[4],lo[5],lo[6],lo[7]};
    }
    // row-major hi/lo from the same tile
    #pragma unroll
    for (int it = 0; it < 2; ++it){
        int idx = it*256 + tid;
        int r = idx >> 3, c8 = idx & 7;
        unsigned short hi[8], lo[8];
        #pragma unroll
        for (int j = 0; j < 8; ++j){
            float x = sF[r][c8*8+j];
            hi[j] = f2h(x);
            lo[j] = f2h(x - h2f(hi[j]));
        }
        size_t oo = ((size_t)b*Nrows + g0 + r)*512 + f0 + c8*8;
        *(ushort4*)(rmHi+oo)   = ushort4{hi[0],hi[1],hi[2],hi[3]};
        *(ushort4*)(rmHi+oo+4) = ushort4{hi[4],hi[5],hi[6],hi[7]};
        *(ushort4*)(rmLo+oo)   = ushort4{lo[0],lo[1],lo[2],lo[3]};
        *(ushort4*)(rmLo+oo+4) = ushort4{lo[4],lo[5],lo[6],lo[7]};
    }
}

// ============ batched scores: all 3 attns' q and k scores in one launch ============
__global__ __launch_bounds__(256) void scores3_k(
    const unsigned short* __restrict__ g, const unsigned short* __restrict__ c,
    const unsigned short* __restrict__ q,
    const float* __restrict__ wa13, const float* __restrict__ wa23,
    float* __restrict__ qs3, float* __restrict__ ks3){
    int lane = threadIdx.x & 63;
    int grow = blockIdx.x*4 + (threadIdx.x >> 6);
    int b = grow / 4608; int r = grow - b*4608;
    const unsigned short* X; const float* wa; float* out; int n, oOff, rowsX;
    if (r < SEG){
        out = qs3;
        if (r < 1024)      { X=g; wa=wa13;        n=r;        oOff=0;    rowsX=NG; }
        else if (r < 1280) { X=q; wa=wa13+4096;   n=r-1024;   oOff=1024; rowsX=NQ; }
        else               { X=g; wa=wa13+8192;   n=r-1280;   oOff=1280; rowsX=NG; }
    } else {
        out = ks3; r -= SEG;
        if (r < 1024)      { X=c; wa=wa23;        n=r;        oOff=0;    rowsX=NC; }
        else if (r < 2048) { X=g; wa=wa23+4096;   n=r-1024;   oOff=1024; rowsX=NG; }
        else               { X=q; wa=wa23+8192;   n=r-2048;   oOff=2048; rowsX=NQ; }
    }
    const unsigned short* Xr = X + ((size_t)b*rowsX + n)*NFEAT;
    float p[NHEADS];
    #pragma unroll
    for (int h = 0; h < NHEADS; ++h) p[h] = 0.f;
    #pragma unroll
    for (int cc = 0; cc < 8; ++cc){
        float x = h2f(Xr[(cc<<6) + lane]);
        #pragma unroll
        for (int h = 0; h < NHEADS; ++h) p[h] += x * wa[(h<<9) + (cc<<6) + lane];
    }
    #pragma unroll
    for (int h = 0; h < NHEADS; ++h){
        float v = p[h];
        #pragma unroll
        for (int off = 32; off > 0; off >>= 1) v += __shfl_xor(v, off);
        if (lane == 0) out[((size_t)b*SEG + oOff + n)*8 + h] = v;
    }
}

// ============ batched WkT gemm: WkT3[b][512][2304] = {clip,gloss,question} @ WT3[a]^T ============
__global__ __launch_bounds__(256) void wkt3_mfma_k(
    const unsigned short* __restrict__ c, const unsigned short* __restrict__ g,
    const unsigned short* __restrict__ q, const unsigned short* __restrict__ WT3,
    unsigned short* __restrict__ WkT3){
    int b = blockIdx.z;
    int y = blockIdx.y;
    const unsigned short* kv; int rowsX, mOff, a;
    if (y < 16)      { a=0; kv=c; rowsX=NC; mOff=0; }
    else if (y < 32) { a=1; y-=16; kv=g; rowsX=NG; mOff=1024; }
    else             { a=2; y-=32; kv=q; rowsX=NQ; mOff=2048; }
    int r0 = y*64, c0 = blockIdx.x*64;
    int tid = threadIdx.x;
    __shared__ alignas(16) unsigned short aS[2][2048], bS[2][2048];
    const unsigned short* aG = kv + (size_t)b*rowsX*512;
    const unsigned short* bG = WT3 + (size_t)a*FF;
    int w = tid >> 6, lane = tid & 63;
    int lrow = lane & 15, quad = lane >> 4;
    int sr = tid >> 2;
    int sq = (tid & 3) ^ ((sr >> 1) & 3);
    size_t aRow = (size_t)(r0 + sr)*512 + sq*8;
    size_t bRow = (size_t)(c0 + sr)*512 + sq*8;
    v4f acc[4];
    #pragma unroll
    for (int cf = 0; cf < 4; ++cf) acc[cf] = (v4f)0.f;
    GLDS(aG + aRow, &aS[0][w << 9]);
    GLDS(bG + bRow, &bS[0][w << 9]);
    __syncthreads();
    int buf = 0;
    for (int s = 0; s < 16; ++s){
        if (s < 15){
            int ktn = (s + 1) << 5;
            GLDS(aG + aRow + ktn, &aS[buf^1][w << 9]);
            GLDS(bG + bRow + ktn, &bS[buf^1][w << 9]);
        }
        v8h af = *(const v8h*)&aS[buf][ldsw(w*16 + lrow, quad)];
        #pragma unroll
        for (int cf = 0; cf < 4; ++cf){
            v8h bf = *(const v8h*)&bS[buf][ldsw(cf*16 + lrow, quad)];
            acc[cf] = MFMA16(af, bf, acc[cf]);
        }
        __syncthreads();
        buf ^= 1;
    }
    #pragma unroll
    for (int cf = 0; cf < 4; ++cf){
        int colg = c0 + cf*16 + lrow;
        int rbase = r0 + w*16 + quad*4;
        ushort4 pk{f2h(acc[cf][0]), f2h(acc[cf][1]), f2h(acc[cf][2]), f2h(acc[cf][3])};
        *(ushort4*)&WkT3[((size_t)b*512 + colg)*SEG + mOff + rbase] = pk;
    }
}

// ============ batched colstat: all 3 attns, per-chunk (cm, sum) via bitmasks ============
__global__ __launch_bounds__(256) void colstat3_k(
    const unsigned* __restrict__ bm_cg, const unsigned* __restrict__ bm_gq,
    const unsigned* __restrict__ bm_qg,
    const float* __restrict__ qs3, const float* __restrict__ ks3,
    float* __restrict__ pcm, float* __restrict__ psum){
    int x = blockIdx.x, b = blockIdx.z;
    const unsigned* bm; int Mrows, N, N32, mOff, qOff;
    if (x < 256)      { bm=bm_cg; Mrows=NC; N=NG; N32=NG/32; mOff=0;    qOff=0; }
    else if (x < 512) { x-=256; bm=bm_gq; Mrows=NG; N=NQ; N32=NQ/32; mOff=1024; qOff=1024; }
    else              { x-=512; bm=bm_qg; Mrows=NQ; N=NG; N32=NG/32; mOff=2048; qOff=1280; }
    int mt = x >> 4, ch = x & 15;
    int chunk = N / CHUNKS, subl = chunk >> 2;
    int ml = threadIdx.x & 63; int m = mt*64 + ml;
    int g = threadIdx.x >> 6;
    int n0 = ch*chunk + g*subl;
    __shared__ float sQ[64][8];
    for (int t2 = threadIdx.x; t2 < chunk*8; t2 += 256)
        sQ[t2>>3][t2&7] = qs3[((size_t)b*SEG + qOff + ch*chunk)*8 + t2];
    float ksv[8];
    size_t mo = ((size_t)b*SEG + mOff + m)*8;
    #pragma unroll
    for (int h = 0; h < 8; ++h) ksv[h] = ks3[mo+h];
    unsigned word = bm[((size_t)b*Mrows + m)*N32 + (n0>>5)];
    unsigned bits = (word >> (n0 & 31)) & ((1u << subl) - 1u);
    __syncthreads();
    int nb = g*subl;
    float mx[8];
    #pragma unroll
    for (int h = 0; h < 8; ++h) mx[h] = -INFINITY;
    for (int i = 0; i < subl; ++i){
        if ((bits >> i) & 1){
            #pragma unroll
            for (int h = 0; h < 8; ++h) mx[h] = fmaxf(mx[h], sQ[nb+i][h]);
        }
    }
    float cm[8], s[8];
    #pragma unroll
    for (int h = 0; h < 8; ++h){
        cm[h] = bits ? lrelu(mx[h] + ksv[h]) : NEGV;
        s[h] = 0.f;
    }
    for (int i = 0; i < subl; ++i){
        bool on = (bits >> i) & 1;
        #pragma unroll
        for (int h = 0; h < 8; ++h){
            float e = on ? lrelu(sQ[nb+i][h] + ksv[h]) : NEGV;
            s[h] += __expf(e - cm[h]);
        }
    }
    __shared__ float scm[4][64][8], ssm[4][64][8];
    #pragma unroll
    for (int h = 0; h < 8; ++h){ scm[g][ml][h] = cm[h]; ssm[g][ml][h] = s[h]; }
    __syncthreads();
    if (g == 0){
        #pragma unroll
        for (int h = 0; h < 8; ++h){
            float c0 = scm[0][ml][h], c1 = scm[1][ml][h], c2 = scm[2][ml][h], c3 = scm[3][ml][h];
            float CM = fmaxf(fmaxf(c0, c1), fmaxf(c2, c3));
            float S = ssm[0][ml][h]*__expf(c0-CM) + ssm[1][ml][h]*__expf(c1-CM)
                    + ssm[2][ml][h]*__expf(c2-CM) + ssm[3][ml][h]*__expf(c3-CM);
            size_t o = (((size_t)b*CHUNKS + ch)*SEG + mOff + m)*8 + h;
            pcm[o] = CM; psum[o] = S;
        }
    }
}

// ============ batched finalize: chunk-combine + repack -> ksh/cmh/ish [b][8][SEG] ============
__global__ __launch_bounds__(256) void colfin3_k(const float* __restrict__ pcm, const float* __restrict__ psum,
    const float* __restrict__ ks3, float* __restrict__ ksh, float* __restrict__ cmh,
    float* __restrict__ ish){
    int idx = blockIdx.x*256 + threadIdx.x;    // NB*SEG*8
    const int m8 = SEG*8;
    int b = idx / m8, rem = idx - b*m8;
    int m = rem >> 3, h = rem & 7;
    size_t base = (size_t)b*CHUNKS*m8 + rem;
    float c[CHUNKS], s[CHUNKS];
    #pragma unroll
    for (int ch = 0; ch < CHUNKS; ++ch){
        c[ch] = pcm[base + (size_t)ch*m8];
        s[ch] = psum[base + (size_t)ch*m8];
    }
    float CM = c[0];
    #pragma unroll
    for (int ch = 1; ch < CHUNKS; ++ch) CM = fmaxf(CM, c[ch]);
    float S = 0.f;
    #pragma unroll
    for (int ch = 0; ch < CHUNKS; ++ch) S += s[ch]*__expf(c[ch] - CM);
    size_t o = ((size_t)b*8 + h)*SEG + m;
    ksh[o] = ks3[idx]; cmh[o] = CM; ish[o] = 1.f/S;
}

// ============ 3-pass fusion MFMA: 64x64 tile, packed weights, GLDS staging ============
__global__ __launch_bounds__(256) void fusion3_k(
    const unsigned short* __restrict__ aHi, const unsigned short* __restrict__ aLo,
    const unsigned short* __restrict__ bHi, const unsigned short* __restrict__ bLo,
    const unsigned short* __restrict__ Whi, const unsigned short* __restrict__ Wlo,
    unsigned short* __restrict__ dst, unsigned short* __restrict__ dstLo,
    unsigned short* __restrict__ dstT, unsigned short* __restrict__ dstTLo,
    float* __restrict__ dstF, int rows){
    int nY = rows >> 6;
    int ppg = (nY * NB) >> 3;
    int F = blockIdx.x;
    int xcd = F & 7, t = F >> 3;
    int c0i = t / ppg;
    int p = xcd + ((t - c0i*ppg) << 3);
    int r0 = (p % nY) << 6, c0 = c0i << 6;
    int b = p / nY;
    int tid = threadIdx.x;
    __shared__ alignas(16) unsigned short aHs[2048], bHs[2048], aLs[2048], bLs[2048];
    __shared__ alignas(16) unsigned short wHs[8192], wLs[8192];
    size_t actOff = (size_t)b*rows*512;
    const unsigned short* aHG = aHi + actOff;
    const unsigned short* bHG = bHi + actOff;
    const unsigned short* aLG = aLo ? aLo + actOff : nullptr;
    const unsigned short* bLG = bLo ? bLo + actOff : nullptr;
    bool hasALo = (aLG != nullptr);
    bool hasBLo = (bLG != nullptr);
    int w = tid >> 6, lane = tid & 63;
    int wr = w >> 1, wc = w & 1;
    int lrow = lane & 15, quad = lane >> 4;
    int sr = tid >> 2;
    int sq = (tid & 3) ^ ((sr >> 1) & 3);
    size_t aRow = (size_t)(r0 + sr)*512 + sq*8;
    size_t wPk = (size_t)c0i*16*8192 + (size_t)sr*32 + sq*8;
    unsigned short* ldsA  = &aHs[w << 9];
    unsigned short* ldsB  = &bHs[w << 9];
    unsigned short* ldsAL = &aLs[w << 9];
    unsigned short* ldsBL = &bLs[w << 9];
    v4f accN[2][2], accF[2][2];
    #pragma unroll
    for (int r = 0; r < 2; ++r)
        #pragma unroll
        for (int cf = 0; cf < 2; ++cf){ accN[r][cf] = (v4f)0.f; accF[r][cf] = (v4f)0.f; }
    for (int kt = 0; kt < 512; kt += 32){
        __syncthreads();
        GLDS(aHG + aRow + kt, ldsA);
        GLDS(bHG + aRow + kt, ldsB);
        if (hasALo) GLDS(aLG + aRow + kt, ldsAL);
        if (hasBLo) GLDS(bLG + aRow + kt, ldsBL);
        size_t wk = wPk + (size_t)(kt >> 5)*8192;
        #pragma unroll
        for (int m = 0; m < 4; ++m){
            GLDS(Whi + wk + (m<<11), &wHs[(m<<11) + (w<<9)]);
            GLDS(Wlo + wk + (m<<11), &wLs[(m<<11) + (w<<9)]);
        }
        __syncthreads();
        v8h ah[2], bh[2], al[2], bl[2];
        #pragma unroll
        for (int r = 0; r < 2; ++r){
            int ao = ldsw(wr*32 + r*16 + lrow, quad);
            ah[r] = *(const v8h*)&aHs[ao];
            bh[r] = *(const v8h*)&bHs[ao];
            if (hasALo) al[r] = *(const v8h*)&aLs[ao];
            if (hasBLo) bl[r] = *(const v8h*)&bLs[ao];
        }
        #pragma unroll
        for (int cf = 0; cf < 2; ++cf){
            int wo = ldsw(wc*32 + cf*16 + lrow, quad);
            v8h w0 = *(const v8h*)&wHs[wo];
            v8h w1 = *(const v8h*)&wHs[2048 + wo];
            v8h w2 = *(const v8h*)&wHs[4096 + wo];
            v8h w3 = *(const v8h*)&wHs[6144 + wo];
            v8h l0 = *(const v8h*)&wLs[wo];
            v8h l1 = *(const v8h*)&wLs[2048 + wo];
            v8h l2 = *(const v8h*)&wLs[4096 + wo];
            v8h l3 = *(const v8h*)&wLs[6144 + wo];
            #pragma unroll
            for (int r = 0; r < 2; ++r){
                accN[r][cf] = MFMA16(ah[r], w0, accN[r][cf]);
                accN[r][cf] = MFMA16(bh[r], w1, accN[r][cf]);
                accF[r][cf] = MFMA16(ah[r], w2, accF[r][cf]);
                accF[r][cf] = MFMA16(bh[r], w3, accF[r][cf]);
                if (hasALo){ accN[r][cf] = MFMA16(al[r], w0, accN[r][cf]); accF[r][cf] = MFMA16(al[r], w2, accF[r][cf]); }
                if (hasBLo){ accN[r][cf] = MFMA16(bl[r], w1, accN[r][cf]); accF[r][cf] = MFMA16(bl[r], w3, accF[r][cf]); }
                accN[r][cf] = MFMA16(ah[r], l0, accN[r][cf]);
                accN[r][cf] = MFMA16(bh[r], l1, accN[r][cf]);
                accF[r][cf] = MFMA16(ah[r], l2, accF[r][cf]);
                accF[r][cf] = MFMA16(bh[r], l3, accF[r][cf]);
            }
        }
    }
    #pragma unroll
    for (int r = 0; r < 2; ++r)
        #pragma unroll
        for (int cf = 0; cf < 2; ++cf){
            int colg = c0 + wc*32 + cf*16 + lrow;
            int rbase = r0 + wr*32 + r*16 + quad*4;
            float o4[4];
            #pragma unroll
            for (int reg = 0; reg < 4; ++reg){
                float f = 1.f/(1.f + __expf(-accF[r][cf][reg]));
                size_t ai = (size_t)(rbase+reg)*512 + colg;
                float ao = h2f(aHG[ai]);
                if (aLG) ao += h2f(aLG[ai]);
                o4[reg] = f*accN[r][cf][reg] + (1.f - f)*ao;
                size_t oo = ((size_t)b*rows + rbase + reg)*512 + colg;
                unsigned short hv = f2h(o4[reg]);
                dst[oo] = hv;
                if (dstLo) dstLo[oo] = f2h(o4[reg] - h2f(hv));
                if (dstF) dstF[oo] = o4[reg];
            }
            if (dstT){
                unsigned short h0 = f2h(o4[0]), h1 = f2h(o4[1]), h2 = f2h(o4[2]), h3 = f2h(o4[3]);
                size_t to = ((size_t)b*512 + colg)*rows + rbase;
                *(ushort4*)&dstT[to] = ushort4{h0,h1,h2,h3};
                if (dstTLo)
                    *(ushort4*)&dstTLo[to] = ushort4{f2h(o4[0]-h2f(h0)), f2h(o4[1]-h2f(h1)),
                                                     f2h(o4[2]-h2f(h2)), f2h(o4[3]-h2f(h3))};
            }
        }
}

// ============ 1-pass fusion MFMA: double-buffered, single barrier per K-step ============
__global__ __launch_bounds__(256) void fusion1_k(
    const unsigned short* __restrict__ aHi, const unsigned short* __restrict__ aLo,
    const unsigned short* __restrict__ bHi,
    const unsigned short* __restrict__ Whi,
    unsigned short* __restrict__ dst, unsigned short* __restrict__ dstLo,
    float* __restrict__ dstF, int rows){
    int nY = rows >> 6;
    int ppg = (nY * NB) >> 3;
    int F = blockIdx.x;
    int xcd = F & 7, t = F >> 3;
    int c0i = t / ppg;
    int p = xcd + ((t - c0i*ppg) << 3);
    int r0 = (p % nY) << 6, c0 = c0i << 6;
    int b = p / nY;
    int tid = threadIdx.x;
    __shared__ alignas(16) unsigned short aHs[2][2048], bHs[2][2048];
    __shared__ alignas(16) unsigned short wHs[2][8192];
    size_t actOff = (size_t)b*rows*512;
    const unsigned short* aHG = aHi + actOff;
    const unsigned short* bHG = bHi + actOff;
    const unsigned short* aLG = aLo ? aLo + actOff : nullptr;
    int w = tid >> 6, lane = tid & 63;
    int wr = w >> 1, wc = w & 1;
    int lrow = lane & 15, quad = lane >> 4;
    int sr = tid >> 2;
    int sq = (tid & 3) ^ ((sr >> 1) & 3);
    size_t aRow = (size_t)(r0 + sr)*512 + sq*8;
    size_t wPk = (size_t)c0i*16*8192 + (size_t)sr*32 + sq*8;
    v4f accN[2][2], accF[2][2];
    #pragma unroll
    for (int r = 0; r < 2; ++r)
        #pragma unroll
        for (int cf = 0; cf < 2; ++cf){ accN[r][cf] = (v4f)0.f; accF[r][cf] = (v4f)0.f; }

    #define F1STAGE(bb, kk) do{ \
        GLDS(aHG + aRow + (kk), &aHs[bb][w << 9]); \
        GLDS(bHG + aRow + (kk), &bHs[bb][w << 9]); \
        size_t wk_ = wPk + (size_t)((kk) >> 5)*8192; \
        GLDS(Whi + wk_,          &wHs[bb][(0<<11) + (w<<9)]); \
        GLDS(Whi + wk_ + (1<<11), &wHs[bb][(1<<11) + (w<<9)]); \
        GLDS(Whi + wk_ + (2<<11), &wHs[bb][(2<<11) + (w<<9)]); \
        GLDS(Whi + wk_ + (3<<11), &wHs[bb][(3<<11) + (w<<9)]); \
    } while(0)

    F1STAGE(0, 0);
    __syncthreads();
    int buf = 0;
    for (int kt = 0; kt < 512; kt += 32){
        if (kt + 32 < 512) F1STAGE(buf^1, kt + 32);
        v8h ah[2], bh[2];
        #pragma unroll
        for (int r = 0; r < 2; ++r){
            int ao = ldsw(wr*32 + r*16 + lrow, quad);
            ah[r] = *(const v8h*)&aHs[buf][ao];
            bh[r] = *(const v8h*)&bHs[buf][ao];
        }
        #pragma unroll
        for (int cf = 0; cf < 2; ++cf){
            int wo = ldsw(wc*32 + cf*16 + lrow, quad);
            v8h w0 = *(const v8h*)&wHs[buf][wo];
            v8h w1 = *(const v8h*)&wHs[buf][2048 + wo];
            v8h w2 = *(const v8h*)&wHs[buf][4096 + wo];
            v8h w3 = *(const v8h*)&wHs[buf][6144 + wo];
            #pragma unroll
            for (int r = 0; r < 2; ++r){
                accN[r][cf] = MFMA16(ah[r], w0, accN[r][cf]);
                accN[r][cf] = MFMA16(bh[r], w1, accN[r][cf]);
                accF[r][cf] = MFMA16(ah[r], w2, accF[r][cf]);
                accF[r][cf] = MFMA16(bh[r], w3, accF[r][cf]);
            }
        }
        __syncthreads();
        buf ^= 1;
    }
    #undef F1STAGE
    #pragma unroll
    for (int r = 0; r < 2; ++r)
        #pragma unroll
        for (int cf = 0; cf < 2; ++cf){
            int colg = c0 + wc*32 + cf*16 + lrow;
            int rbase = r0 + wr*32 + r*16 + quad*4;
            #pragma unroll
            for (int reg = 0; reg < 4; ++reg){
                float f = 1.f/(1.f + __expf(-accF[r][cf][reg]));
                size_t ai = (size_t)(rbase+reg)*512 + colg;
                float ao = h2f(aHG[ai]);
                if (aLG) ao += h2f(aLG[ai]);
                float o = f*accN[r][cf][reg] + (1.f - f)*ao;
                size_t oo = ((size_t)b*rows + rbase + reg)*512 + colg;
                unsigned short hv = f2h(o);
                dst[oo] = hv;
                if (dstLo) dstLo[oo] = f2h(o - h2f(hv));
                if (dstF) dstF[oo] = o;
            }
        }
}

// ============ generic MFMA GEMM (64-row tiles, double-buffered) — gloss_same only ============
__global__ __launch_bounds__(256) void gemmT_mfma_k(
    const unsigned short* __restrict__ A, size_t aStride,
    const unsigned short* __restrict__ BT, const unsigned short* __restrict__ BT2, size_t bStride,
    int K, int rowsPB,
    unsigned short* __restrict__ outRM, unsigned short* __restrict__ outLo,
    unsigned short* __restrict__ outT){
    int b = blockIdx.z;
    int r0 = blockIdx.y*64, c0 = blockIdx.x*64;
    int tid = threadIdx.x;
    __shared__ alignas(16) unsigned short aS[2][2048], bS[2][2048];
    const unsigned short* aG = A + (size_t)b*aStride;
    const unsigned short* bG0 = BT + (size_t)b*bStride;
    const unsigned short* bG1 = BT2 ? BT2 + (size_t)b*bStride : nullptr;
    int w = tid >> 6, lane = tid & 63;
    int lrow = lane & 15, quad = lane >> 4;
    int sr = tid >> 2;
    int sq = (tid & 3) ^ ((sr >> 1) & 3);
    size_t aRow = (size_t)(r0 + sr)*K + sq*8;
    size_t bRow = (size_t)(c0 + sr)*K + sq*8;
    int spp = K >> 5;
    int nsteps = (BT2 ? 2 : 1)*spp;
    v4f acc[4];
    #pragma unroll
    for (int cf = 0; cf < 4; ++cf) acc[cf] = (v4f)0.f;
    GLDS(aG + aRow, &aS[0][w << 9]);
    GLDS(bG0 + bRow, &bS[0][w << 9]);
    __syncthreads();
    int buf = 0;
    for (int s = 0; s < nsteps; ++s){
        int sn = s + 1;
        if (sn < nsteps){
            int ktn = ((sn >= spp) ? (sn - spp) : sn) << 5;
            const unsigned short* bgn = (sn >= spp) ? bG1 : bG0;
            GLDS(aG + aRow + ktn, &aS[buf^1][w << 9]);
            GLDS(bgn + bRow + ktn, &bS[buf^1][w << 9]);
        }
        v8h af = *(const v8h*)&aS[buf][ldsw(w*16 + lrow, quad)];
        #pragma unroll
        for (int cf = 0; cf < 4; ++cf){
            v8h bf = *(const v8h*)&bS[buf][ldsw(cf*16 + lrow, quad)];
            acc[cf] = MFMA16(af, bf, acc[cf]);
        }
        __syncthreads();
        buf ^= 1;
    }
    #pragma unroll
    for (int cf = 0; cf < 4; ++cf){
        int colg = c0 + cf*16 + lrow;
        int rbase = r0 + w*16 + quad*4;
        if (outRM){
            #pragma unroll
            for (int reg = 0; reg < 4; ++reg){
                float v = acc[cf][reg];
                unsigned short hv = f2h(v);
                size_t oo = ((size_t)b*rowsPB + rbase + reg)*512 + colg;
                outRM[oo] = hv;
                if (outLo) outLo[oo] = f2h(v - h2f(hv));
            }
        }
        if (outT){
            ushort4 pk{f2h(acc[cf][0]), f2h(acc[cf][1]), f2h(acc[cf][2]), f2h(acc[cf][3])};
            *(ushort4*)&outT[((size_t)b*512 + colg)*rowsPB + rbase] = pk;
        }
    }
}

// ============ attention output MFMA: T1-swizzled grid, LDS stats, bitmask adj ============
__global__ __launch_bounds__(256) void attn_mfma_k(const unsigned* __restrict__ bmN, int M32,
    const float* __restrict__ qs3, int qOff,
    const float* __restrict__ ksh, const float* __restrict__ cmh, const float* __restrict__ ish,
    int mOff, const unsigned short* __restrict__ WkT3,
    unsigned short* __restrict__ outp, int N, int M){
    int nN0 = N >> 6;
    int F = blockIdx.x;
    int xcd = F & 7, t = F >> 3;
    int bh = xcd*4 + t/nN0;
    int n0 = (t % nN0) << 6;
    int b = bh >> 3, h = bh & 7;
    int tid = threadIdx.x;
    __shared__ unsigned short pS[2*64*LSTR];
    __shared__ alignas(16) unsigned short wS[2*2048];
    __shared__ float qsS[64];
    __shared__ alignas(16) float sKs[1024], sCm[1024], sIs[1024];
    const float* ksb = ksh + ((size_t)b*8 + h)*SEG + mOff;
    const float* cmb = cmh + ((size_t)b*8 + h)*SEG + mOff;
    const float* isb = ish + ((size_t)b*8 + h)*SEG + mOff;
    const unsigned short* wkb = WkT3 + ((size_t)b*512 + h*64)*SEG + mOff;
    int w = tid >> 6, lane = tid & 63;
    int lrow = lane & 15, quad = lane >> 4;
    int pn = tid >> 2, pm = (tid & 3)*8;
    int sr = tid >> 2;
    int sq = (tid & 3) ^ ((sr >> 1) & 3);
    for (int o = w*256; o < M; o += 1024){
        GLDS(ksb + o + lane*4, &sKs[o]);
        GLDS(cmb + o + lane*4, &sCm[o]);
        GLDS(isb + o + lane*4, &sIs[o]);
    }
    if (tid < 64) qsS[tid] = qs3[((size_t)b*SEG + qOff + n0 + tid)*8 + h];
    const unsigned* bmrow = bmN + ((size_t)b*N + n0 + pn)*M32;
    v4f acc[4];
    #pragma unroll
    for (int cf = 0; cf < 4; ++cf) acc[cf] = (v4f)0.f;
    uint2 CW = *(const uint2*)(bmrow);
    uint2 NW;
    __syncthreads();
    float qv = qsS[pn];
    for (int mt = 0; mt < M; mt += 64){
        int mtB = mt + 32;
        int mtN = (mt + 64 < M) ? (mt + 64) : 0;
        GLDS(wkb + (size_t)sr*SEG + mt + sq*8, &wS[w << 9]);
        {
            unsigned bb = (CW.x >> pm) & 0xffu;
            float4 k0 = *(const float4*)&sKs[mt+pm], k1 = *(const float4*)&sKs[mt+pm+4];
            float4 c0 = *(const float4*)&sCm[mt+pm], c1 = *(const float4*)&sCm[mt+pm+4];
            float4 i0 = *(const float4*)&sIs[mt+pm], i1 = *(const float4*)&sIs[mt+pm+4];
            float p[8];
            const float* kk0 = &k0.x; const float* kk1 = &k1.x;
            const float* cc0 = &c0.x; const float* cc1 = &c1.x;
            const float* ii0 = &i0.x; const float* ii1 = &i1.x;
            #pragma unroll
            for (int j = 0; j < 4; ++j){
                float e = ((bb >> j) & 1) ? lrelu(qv + kk0[j]) : NEGV;
                p[j] = __expf(e - cc0[j]) * ii0[j];
            }
            #pragma unroll
            for (int j = 0; j < 4; ++j){
                float e = ((bb >> (4+j)) & 1) ? lrelu(qv + kk1[j]) : NEGV;
                p[4+j] = __expf(e - cc1[j]) * ii1[j];
            }
            *(ushort4*)&pS[pn*LSTR + pm]     = ushort4{f2h(p[0]), f2h(p[1]), f2h(p[2]), f2h(p[3])};
            *(ushort4*)&pS[pn*LSTR + pm + 4] = ushort4{f2h(p[4]), f2h(p[5]), f2h(p[6]), f2h(p[7])};
        }
        __syncthreads();
        {
            v8h af = *(const v8h*)&pS[(w*16 + lrow)*LSTR + quad*8];
            #pragma unroll
            for (int cf = 0; cf < 4; ++cf){
                v8h bf = *(const v8h*)&wS[ldsw(cf*16 + lrow, quad)];
                acc[cf] = MFMA16(af, bf, acc[cf]);
            }
        }
        GLDS(wkb + (size_t)sr*SEG + mtB + sq*8, &wS[2048 + (w << 9)]);
        NW = *(const uint2*)(bmrow + (mtN >> 5));
        {
            unsigned bb = (CW.y >> pm) & 0xffu;
            float4 k0 = *(const float4*)&sKs[mtB+pm], k1 = *(const float4*)&sKs[mtB+pm+4];
            float4 c0 = *(const float4*)&sCm[mtB+pm], c1 = *(const float4*)&sCm[mtB+pm+4];
            float4 i0 = *(const float4*)&sIs[mtB+pm], i1 = *(const float4*)&sIs[mtB+pm+4];
            float p[8];
            const float* kk0 = &k0.x; const float* kk1 = &k1.x;
            const float* cc0 = &c0.x; const float* cc1 = &c1.x;
            const float* ii0 = &i0.x; const float* ii1 = &i1.x;
            #pragma unroll
            for (int j = 0; j < 4; ++j){
                float e = ((bb >> j) & 1) ? lrelu(qv + kk0[j]) : NEGV;
                p[j] = __expf(e - cc0[j]) * ii0[j];
            }
            #pragma unroll
            for (int j = 0; j < 4; ++j){
                float e = ((bb >> (4+j)) & 1) ? lrelu(qv + kk1[j]) : NEGV;
                p[4+j] = __expf(e - cc1[j]) * ii1[j];
            }
            *(ushort4*)&pS[2304 + pn*LSTR + pm]     = ushort4{f2h(p[0]), f2h(p[1]), f2h(p[2]), f2h(p[3])};
            *(ushort4*)&pS[2304 + pn*LSTR + pm + 4] = ushort4{f2h(p[4]), f2h(p[5]), f2h(p[6]), f2h(p[7])};
        }
        __syncthreads();
        {
            v8h af = *(const v8h*)&pS[2304 + (w*16 + lrow)*LSTR + quad*8];
            #pragma unroll
            for (int cf = 0; cf < 4; ++cf){
                v8h bf = *(const v8h*)&wS[2048 + ldsw(cf*16 + lrow, quad)];
                acc[cf] = MFMA16(af, bf, acc[cf]);
            }
        }
        CW = NW;
    }
    #pragma unroll
    for (int cf = 0; cf < 4; ++cf){
        int colg = h*64 + cf*16 + lrow;
        int rbase = n0 + w*16 + quad*4;
        #pragma unroll
        for (int reg = 0; reg < 4; ++reg){
            float v = acc[cf][reg];
            v = (v > 0.f) ? v : (__expf(v) - 1.f);
            outp[((size_t)b*N + rbase + reg)*512 + colg] = f2h(v);
        }
    }
}

extern "C" void kernel_launch(void* const* d_in, const int* in_sizes, int n_in,
                              void* d_out, int out_size, void* d_ws, size_t ws_size,
                              hipStream_t stream){
    const float* in_gloss = (const float*)d_in[0];
    const float* in_clip  = (const float*)d_in[1];
    const float* in_q     = (const float*)d_in[2];
    const int*   adj_gc   = (const int*)d_in[3];
    const int*   adj_gq   = (const int*)d_in[4];
    const float* c2gW  = (const float*)d_in[5];
    const float* c2ga1 = (const float*)d_in[6];
    const float* c2ga2 = (const float*)d_in[7];
    const float* g2qW  = (const float*)d_in[8];
    const float* g2qa1 = (const float*)d_in[9];
    const float* g2qa2 = (const float*)d_in[10];
    const float* q2gW  = (const float*)d_in[11];
    const float* q2ga1 = (const float*)d_in[12];
    const float* q2ga2 = (const float*)d_in[13];
    const float* fusW  = (const float*)d_in[14];
    const float* fusU  = (const float*)d_in[15];
    const float* fusWf = (const float*)d_in[16];
    const float* fusUf = (const float*)d_in[17];
    float* out = (float*)d_out;
    float* out_gloss = out;
    float* out_clip  = out + (size_t)NB*NG*NFEAT;
    float* out_q     = out + (size_t)NB*NG*NFEAT*2;

    char* wsB = (char*)d_ws;
    size_t off = 0;
    auto alloc = [&](size_t bytes){ void* p = wsB + off; off += (bytes + 255) & ~(size_t)255; return p; };
    float* wa13  = (float*)alloc(3*4096*4);
    float* wa23  = (float*)alloc(3*4096*4);
    float* qs3   = (float*)alloc((size_t)NB*SEG*8*4);
    float* ks3   = (float*)alloc((size_t)NB*SEG*8*4);
    float* ksh3  = (float*)alloc((size_t)NB*8*SEG*4);
    float* cmh3  = (float*)alloc((size_t)NB*8*SEG*4);
    float* ish3  = (float*)alloc((size_t)NB*8*SEG*4);
    float* pcm   = (float*)alloc((size_t)NB*CHUNKS*SEG*8*4);
    float* psum  = (float*)alloc((size_t)NB*CHUNKS*SEG*8*4);
    unsigned short* WflatT3 = (unsigned short*)alloc((size_t)3*FF*2);
    unsigned short* WkT3    = (unsigned short*)alloc((size_t)NB*512*SEG*2);
    unsigned short* wtAll   = (unsigned short*)alloc((size_t)32*FF*2);
    unsigned short* wtAllLo = (unsigned short*)alloc((size_t)32*FF*2);
    unsigned short* adjTgc  = (unsigned short*)alloc((size_t)NB*NC*NG*2);
    unsigned short* g_bf0   = (unsigned short*)alloc((size_t)NB*NG*NFEAT*2);
    unsigned short* gLo0    = (unsigned short*)alloc((size_t)NB*NG*NFEAT*2);
    unsigned short* g_bf1   = (unsigned short*)alloc((size_t)NB*NG*NFEAT*2);
    unsigned short* gLo1    = (unsigned short*)alloc((size_t)NB*NG*NFEAT*2);
    unsigned short* gT      = (unsigned short*)alloc((size_t)NB*NFEAT*NG*2);
    unsigned short* gTlo    = (unsigned short*)alloc((size_t)NB*NFEAT*NG*2);
    unsigned short* gA_bf   = (unsigned short*)alloc((size_t)NB*NG*NFEAT*2);
    unsigned short* gALo    = (unsigned short*)alloc((size_t)NB*NG*NFEAT*2);
    unsigned short* c_bf0   = (unsigned short*)alloc((size_t)NB*NC*NFEAT*2);
    unsigned short* cLo0    = (unsigned short*)alloc((size_t)NB*NC*NFEAT*2);
    unsigned short* c_bf1   = (unsigned short*)alloc((size_t)NB*NC*NFEAT*2);
    unsigned short* cLo1    = (unsigned short*)alloc((size_t)NB*NC*NFEAT*2);
    unsigned short* q_bf0   = (unsigned short*)alloc((size_t)NB*NQ*NFEAT*2);
    unsigned short* q_bf1   = (unsigned short*)alloc((size_t)NB*NQ*NFEAT*2);
    unsigned short* agg_bf  = (unsigned short*)alloc((size_t)NB*NG*NFEAT*2);
    unsigned short* aggLo   = (unsigned short*)alloc((size_t)NB*NG*NFEAT*2);
    int* adjTgq = (int*)alloc((size_t)NB*NQ*NG*4);
    unsigned* bm_gc = (unsigned*)alloc((size_t)NB*NG*(NC/32)*4);
    unsigned* bm_cg = (unsigned*)alloc((size_t)NB*NC*(NG/32)*4);
    unsigned* bm_gq = (unsigned*)alloc((size_t)NB*NG*(NQ/32)*4);
    unsigned* bm_qg = (unsigned*)alloc((size_t)NB*NQ*(NG/32)*4);
    (void)ws_size; (void)in_sizes; (void)n_in; (void)out_size;

    const size_t HFD = (size_t)NHEADS*NFEAT*HDIM;
    const size_t HD  = (size_t)NHEADS*HDIM;

    // ---- prep ----
    wtT_k<<<2048, 256, 0, stream>>>(fusW, fusU, fusWf, fusUf, wtAll, wtAllLo);
    adjT_h_k<<<dim3(NC/64, NG/64, NB), 256, 0, stream>>>(adj_gc, adjTgc,
        (unsigned long long*)bm_gc, (unsigned long long*)bm_cg);
    adjT_int_k<<<dim3(NQ/64, NG/64, NB), 256, 0, stream>>>(adj_gq, adjTgq,
        (unsigned long long*)bm_gq, (unsigned long long*)bm_qg);
    cvt_hl_k<<<(NB*NC*NFEAT)/2048, 256, 0, stream>>>(in_clip,  c_bf0, cLo0);
    cvt_h_k<<<(NB*NQ*NFEAT)/2048, 256, 0, stream>>>(in_q,     q_bf0);
    actT_hl_k<<<dim3(8, NG/64, NB), 256, 0, stream>>>(in_gloss, gT, gTlo, g_bf0, gLo0, NG);

    auto run_fusion = [&](const unsigned short* a, const unsigned short* aLo,
                          const unsigned short* bb, const unsigned short* bLo, int rows,
                          int l, int i, int npass,
                          unsigned short* dst, unsigned short* dstLo,
                          unsigned short* dstT, unsigned short* dstTLo, float* dstF){
        const unsigned short* Whi = wtAll   + (size_t)((l*4 + i)*4)*FF;
        const unsigned short* Wlo = wtAllLo + (size_t)((l*4 + i)*4)*FF;
        if (npass == 3)
            fusion3_k<<<dim3(8*(rows/64)*NB), 256, 0, stream>>>(
                a, aLo, bb, bLo, Whi, Wlo, dst, dstLo, dstT, dstTLo, dstF, rows);
        else
            fusion1_k<<<dim3(8*(rows/64)*NB), 256, 0, stream>>>(
                a, aLo, bb, Whi, dst, dstLo, dstF, rows);
    };

    for (int l = 0; l < 2; ++l){
        const unsigned short* g_cur = (l == 0) ? g_bf0 : g_bf1;
        const unsigned short* gLoC  = (l == 0) ? gLo0  : gLo1;
        const unsigned short* c_cur = (l == 0) ? c_bf0 : c_bf1;
        const unsigned short* cLoC  = (l == 0) ? cLo0  : cLo1;
        const unsigned short* q_cur = (l == 0) ? q_bf0 : q_bf1;
        unsigned short* g_nxt = (l == 0) ? g_bf1 : g_bf0;
        unsigned short* gLoN  = (l == 0) ? gLo1  : nullptr;
        unsigned short* c_nxt = (l == 0) ? c_bf1 : c_bf0;
        unsigned short* cLoN  = (l == 0) ? cLo1  : nullptr;
        unsigned short* q_nxt = (l == 0) ? q_bf1 : q_bf0;
        float* gF = (l == 1) ? out_gloss : nullptr;
        float* cF = (l == 1) ? out_clip  : nullptr;
        float* qF = (l == 1) ? out_q     : nullptr;

        // ---- batched attention prep (depends only on layer inputs) ----
        prep_attnW3_k<<<240, 256, 0, stream>>>(
            c2gW + l*HFD, c2ga1 + l*HD, c2ga2 + l*HD,
            g2qW + l*HFD, g2qa1 + l*HD, g2qa2 + l*HD,
            q2gW + l*HFD, q2ga1 + l*HD, q2ga2 + l*HD,
            WflatT3, wa13, wa23);
        scores3_k<<<(NB*4608)/4, 256, 0, stream>>>(g_cur, c_cur, q_cur, wa13, wa23, qs3, ks3);
        wkt3_mfma_k<<<dim3(8, 36, NB), 256, 0, stream>>>(c_cur, g_cur, q_cur, WflatT3, WkT3);
        colstat3_k<<<dim3(576, 1, NB), 256, 0, stream>>>(bm_cg, bm_gq, bm_qg, qs3, ks3, pcm, psum);
        colfin3_k<<<(NB*SEG*8)/256, 256, 0, stream>>>(pcm, psum, ks3, ksh3, cmh3, ish3);

        // gloss_same = adj_gc^T @ gloss  (hi/lo B, hi/lo out)
        gemmT_mfma_k<<<dim3(8, NC/64, NB), 256, 0, stream>>>(adjTgc, (size_t)NC*NG, gT, gTlo,
                                                             (size_t)512*NG, NG, NC,
                                                             agg_bf, aggLo, nullptr);
        // clip_1 (3-pass hi/lo)
        run_fusion(c_cur, cLoC, agg_bf, aggLo, NC, l, 0, 3,
                   c_nxt, cLoN, nullptr, nullptr, cF);
        // clip_agg = attn0(q=gloss, kv=clip)
        attn_mfma_k<<<(NG/64)*32, 256, 0, stream>>>(bm_gc, NC/32, qs3, 0, ksh3, cmh3, ish3, 0,
                                                    WkT3, agg_bf, NG, NC);
        // gloss_1 (single pass; aLo used for exact gate residual)
        run_fusion(g_cur, gLoC, agg_bf, nullptr, NG, l, 1, 1,
                   gA_bf, gALo, nullptr, nullptr, nullptr);
        // gloss_agg = attn1(q=question, kv=gloss)
        attn_mfma_k<<<(NQ/64)*32, 256, 0, stream>>>(bm_qg, NG/32, qs3, 1024, ksh3, cmh3, ish3, 1024,
                                                    WkT3, agg_bf, NQ, NG);
        // question_1 (single pass)
        run_fusion(q_cur, nullptr, agg_bf, nullptr, NQ, l, 2, 1,
                   q_nxt, nullptr, nullptr, nullptr, qF);
        // question_agg = attn2(q=gloss, kv=question)
        attn_mfma_k<<<(NG/64)*32, 256, 0, stream>>>(bm_gq, NQ/32, qs3, 1280, ksh3, cmh3, ish3, 2048,
                                                    WkT3, agg_bf, NG, NQ);
        // gloss_2 (3-pass; emit hi/lo + transposed hi/lo for next layer's gloss_same)
        run_fusion(gA_bf, gALo, agg_bf, nullptr, NG, l, 3, 3,
                   g_nxt, gLoN, (l == 0) ? gT : nullptr, (l == 0) ? gTlo : nullptr, gF);
    }
}

// Round 8
// 638.837 us; speedup vs baseline: 1.4182x; 1.0772x over previous
//
#include <hip/hip_runtime.h>
#include <math.h>

#define NFEAT 512
#define NHEADS 8
#define HDIM 64
#define NB 4
#define NG 1024
#define NC 1024
#define NQ 256
#define NEGV -9e15f
#define CHUNKS 16
#define FF ((size_t)NFEAT*NFEAT)
#define LSTR 36   // LDS row stride (ushorts) for reg-written P tiles only
#define SEG 2304  // segmented attn rows per batch

typedef _Float16 v8h __attribute__((ext_vector_type(8)));
typedef float v4f __attribute__((ext_vector_type(4)));
#define MFMA16(a,b,c) __builtin_amdgcn_mfma_f32_16x16x32_f16((a),(b),(c),0,0,0)

// async global->LDS, 16B/lane, lane-linear LDS dest (wave-uniform base + lane*16)
#define GLDS(g, l) __builtin_amdgcn_global_load_lds( \
    (__attribute__((address_space(1))) void*)(g), \
    (__attribute__((address_space(3))) void*)(l), 16, 0, 0)

// XOR swizzle for 64B-row linear LDS tiles: physical 16B slot = quad ^ ((row>>1)&3).
__device__ __forceinline__ int ldsw(int row, int quad){
    return row*32 + (((quad) ^ ((row>>1)&3)) << 3);
}

__device__ __forceinline__ float lrelu(float x){ return fmaxf(x, 0.2f*x); }
__device__ __forceinline__ unsigned short f2h(float x){ union{_Float16 h; unsigned short u;} v; v.h = (_Float16)x; return v.u; }
__device__ __forceinline__ float h2f(unsigned short u){ union{_Float16 h; unsigned short u;} v; v.u = u; return (float)v.h; }

// ============ prep: fp32 -> fp16 flat ============
__global__ __launch_bounds__(256) void cvt_h_k(const float* __restrict__ src, unsigned short* __restrict__ dst){
    int idx = blockIdx.x*256 + threadIdx.x;
    const float4* s = (const float4*)(src + (size_t)idx*8);
    float4 a = s[0], b = s[1];
    ushort4 p0{f2h(a.x),f2h(a.y),f2h(a.z),f2h(a.w)};
    ushort4 p1{f2h(b.x),f2h(b.y),f2h(b.z),f2h(b.w)};
    *(ushort4*)(dst + (size_t)idx*8) = p0;
    *(ushort4*)(dst + (size_t)idx*8 + 4) = p1;
}

// ============ prep: fp32 -> fp16 hi/lo flat ============
__global__ __launch_bounds__(256) void cvt_hl_k(const float* __restrict__ src,
    unsigned short* __restrict__ dstHi, unsigned short* __restrict__ dstLo){
    int idx = blockIdx.x*256 + threadIdx.x;
    const float4* s = (const float4*)(src + (size_t)idx*8);
    float4 a = s[0], b = s[1];
    float x[8] = {a.x,a.y,a.z,a.w,b.x,b.y,b.z,b.w};
    unsigned short hi[8], lo[8];
    #pragma unroll
    for (int j = 0; j < 8; ++j){ hi[j] = f2h(x[j]); lo[j] = f2h(x[j] - h2f(hi[j])); }
    *(ushort4*)(dstHi + (size_t)idx*8)     = ushort4{hi[0],hi[1],hi[2],hi[3]};
    *(ushort4*)(dstHi + (size_t)idx*8 + 4) = ushort4{hi[4],hi[5],hi[6],hi[7]};
    *(ushort4*)(dstLo + (size_t)idx*8)     = ushort4{lo[0],lo[1],lo[2],lo[3]};
    *(ushort4*)(dstLo + (size_t)idx*8 + 4) = ushort4{lo[4],lo[5],lo[6],lo[7]};
}

// ============ prep: fusion weights -> PACKED transposed fp16 hi/lo ============
// packed layout per group li: [c0i(8)][ktI(16)][mat(4)][row64][k32]
__global__ __launch_bounds__(256) void wtT_k(const float* __restrict__ w0, const float* __restrict__ w1,
    const float* __restrict__ w2, const float* __restrict__ w3,
    unsigned short* __restrict__ dstHi, unsigned short* __restrict__ dstLo){
    int bx = blockIdx.x;
    int mat = bx >> 6, t = bx & 63;
    int a = mat & 3, li = mat >> 2;
    const float* src = (a==0?w0:a==1?w1:a==2?w2:w3) + (size_t)li*FF;
    int fo0 = (t>>3)*64, fi0 = (t&7)*64;
    __shared__ float sT[64][65];
    int tid = threadIdx.x;
    #pragma unroll
    for (int it = 0; it < 4; ++it){
        int idx = it*256 + tid;
        int r = idx >> 4, c4 = idx & 15;
        float4 v = *(const float4*)(src + (size_t)(fi0+r)*512 + fo0 + c4*4);
        sT[r][c4*4+0]=v.x; sT[r][c4*4+1]=v.y; sT[r][c4*4+2]=v.z; sT[r][c4*4+3]=v.w;
    }
    __syncthreads();
    #pragma unroll
    for (int it = 0; it < 2; ++it){
        int idx = it*256 + tid;
        int dd = idx >> 3, c8 = idx & 7;
        unsigned short hi[8], lo[8];
        #pragma unroll
        for (int j = 0; j < 8; ++j){
            float x = sT[c8*8+j][dd];
            hi[j] = f2h(x);
            lo[j] = f2h(x - h2f(hi[j]));
        }
        int ktI = (fi0 >> 5) + (c8 >> 2);
        int k31 = (c8 & 3)*8;
        size_t oo = (size_t)li*4*FF + ((((size_t)(fo0>>6)*16 + ktI)*4 + a)*64 + dd)*32 + k31;
        *(ushort4*)(dstHi+oo)   = ushort4{hi[0],hi[1],hi[2],hi[3]};
        *(ushort4*)(dstHi+oo+4) = ushort4{hi[4],hi[5],hi[6],hi[7]};
        *(ushort4*)(dstLo+oo)   = ushort4{lo[0],lo[1],lo[2],lo[3]};
        *(ushort4*)(dstLo+oo+4) = ushort4{lo[4],lo[5],lo[6],lo[7]};
    }
}

// ============ prep: 3 attn W repacks (blocks 0..191) + wa vectors (blocks 192..239) ============
__global__ __launch_bounds__(256) void prep_attnW3_k(
    const float* __restrict__ W0, const float* __restrict__ a10, const float* __restrict__ a20,
    const float* __restrict__ W1, const float* __restrict__ a11, const float* __restrict__ a21,
    const float* __restrict__ W2, const float* __restrict__ a12, const float* __restrict__ a22,
    unsigned short* __restrict__ WT3, float* __restrict__ wa13, float* __restrict__ wa23){
    int bx = blockIdx.x;
    int tid = threadIdx.x;
    if (bx >= 192){
        int r = bx - 192;
        int a = r >> 4;
        const float* W  = (a==0?W0:a==1?W1:W2);
        const float* a1 = (a==0?a10:a==1?a11:a12);
        const float* a2 = (a==0?a20:a==1?a21:a22);
        int idx = (r & 15)*256 + tid;
        int h = idx >> 9;
        const float* Wp = W + (size_t)idx*64;
        float s1 = 0.f, s2 = 0.f;
        #pragma unroll
        for (int d = 0; d < 64; ++d){ float w = Wp[d]; s1 += w*a1[(h<<6)+d]; s2 += w*a2[(h<<6)+d]; }
        wa13[a*4096 + idx] = s1; wa23[a*4096 + idx] = s2;
        return;
    }
    int a = bx >> 6, bxl = bx & 63;
    const float* W = (a==0?W0:a==1?W1:W2);
    unsigned short* WT = WT3 + (size_t)a*FF;
    int h = bxl >> 3, f0 = (bxl & 7)*64;
    __shared__ float sT[64][65];
    #pragma unroll
    for (int it = 0; it < 4; ++it){
        int idx = it*256 + tid;
        int r = idx >> 4, c4 = idx & 15;
        float4 v = *(const float4*)(W + ((size_t)h*512 + f0 + r)*64 + c4*4);
        sT[r][c4*4+0]=v.x; sT[r][c4*4+1]=v.y; sT[r][c4*4+2]=v.z; sT[r][c4*4+3]=v.w;
    }
    __syncthreads();
    #pragma unroll
    for (int it = 0; it < 2; ++it){
        int idx = it*256 + tid;
        int dd = idx >> 3, c8 = idx & 7;
        ushort4 p0{f2h(sT[c8*8+0][dd]),f2h(sT[c8*8+1][dd]),f2h(sT[c8*8+2][dd]),f2h(sT[c8*8+3][dd])};
        ushort4 p1{f2h(sT[c8*8+4][dd]),f2h(sT[c8*8+5][dd]),f2h(sT[c8*8+6][dd]),f2h(sT[c8*8+7][dd])};
        unsigned short* o = WT + ((size_t)h*64 + dd)*512 + f0 + c8*8;
        *(ushort4*)o = p0; *(ushort4*)(o+4) = p1;
    }
}

// ============ prep: adj_gc int -> adjT fp16 [b][c][g] + bitmasks both orientations ============
__global__ __launch_bounds__(256) void adjT_h_k(const int* __restrict__ adj, unsigned short* __restrict__ dst,
    unsigned long long* __restrict__ bm_gc, unsigned long long* __restrict__ bm_cg){
    int b = blockIdx.z;
    int c0 = blockIdx.x*64, g0 = blockIdx.y*64;
    __shared__ int sI[64][65];
    int tid = threadIdx.x;
    #pragma unroll
    for (int it = 0; it < 4; ++it){
        int idx = it*256 + tid;
        int r = idx >> 4, c4 = idx & 15;
        int4 v = *(const int4*)(adj + ((size_t)b*NG + g0 + r)*NC + c0 + c4*4);
        sI[r][c4*4+0]=v.x; sI[r][c4*4+1]=v.y; sI[r][c4*4+2]=v.z; sI[r][c4*4+3]=v.w;
    }
    __syncthreads();
    int wv = tid >> 6, lane = tid & 63;
    #pragma unroll
    for (int it = 0; it < 2; ++it){
        int idx = it*256 + tid;
        int dd = idx >> 3, c8 = idx & 7;
        ushort4 p0, p1;
        #pragma unroll
        for (int j = 0; j < 4; ++j) (&p0.x)[j] = sI[c8*8+j][dd] > 0 ? (unsigned short)0x3C00 : (unsigned short)0;
        #pragma unroll
        for (int j = 0; j < 4; ++j) (&p1.x)[j] = sI[c8*8+4+j][dd] > 0 ? (unsigned short)0x3C00 : (unsigned short)0;
        unsigned short* o = dst + ((size_t)b*NC + c0 + dd)*NG + g0 + c8*8;
        *(ushort4*)o = p0; *(ushort4*)(o+4) = p1;
    }
    #pragma unroll
    for (int rr = wv; rr < 64; rr += 4){
        unsigned long long m = __ballot(sI[rr][lane] > 0);
        if (lane == 0) bm_gc[((size_t)b*NG + g0 + rr)*(NC/64) + (c0>>6)] = m;
    }
    #pragma unroll
    for (int cc = wv; cc < 64; cc += 4){
        unsigned long long m = __ballot(sI[lane][cc] > 0);
        if (lane == 0) bm_cg[((size_t)b*NC + c0 + cc)*(NG/64) + (g0>>6)] = m;
    }
}

// ============ prep: adj_gq int -> adjT int [b][q][g] + bitmasks both orientations ============
__global__ __launch_bounds__(256) void adjT_int_k(const int* __restrict__ adj, int* __restrict__ dst,
    unsigned long long* __restrict__ bm_gq, unsigned long long* __restrict__ bm_qg){
    int b = blockIdx.z;
    int q0 = blockIdx.x*64, g0 = blockIdx.y*64;
    __shared__ int sI[64][65];
    int tid = threadIdx.x;
    #pragma unroll
    for (int it = 0; it < 4; ++it){
        int idx = it*256 + tid;
        int r = idx >> 4, c4 = idx & 15;
        int4 v = *(const int4*)(adj + ((size_t)b*NG + g0 + r)*NQ + q0 + c4*4);
        sI[r][c4*4+0]=v.x; sI[r][c4*4+1]=v.y; sI[r][c4*4+2]=v.z; sI[r][c4*4+3]=v.w;
    }
    __syncthreads();
    int wv = tid >> 6, lane = tid & 63;
    #pragma unroll
    for (int it = 0; it < 4; ++it){
        int idx = it*256 + tid;
        int dd = idx >> 4, c4 = idx & 15;
        int4 v{sI[c4*4+0][dd], sI[c4*4+1][dd], sI[c4*4+2][dd], sI[c4*4+3][dd]};
        *(int4*)(dst + ((size_t)b*NQ + q0 + dd)*NG + g0 + c4*4) = v;
    }
    #pragma unroll
    for (int rr = wv; rr < 64; rr += 4){
        unsigned long long m = __ballot(sI[rr][lane] > 0);
        if (lane == 0) bm_gq[((size_t)b*NG + g0 + rr)*(NQ/64) + (q0>>6)] = m;
    }
    #pragma unroll
    for (int cc = wv; cc < 64; cc += 4){
        unsigned long long m = __ballot(sI[lane][cc] > 0);
        if (lane == 0) bm_qg[((size_t)b*NQ + q0 + cc)*(NG/64) + (g0>>6)] = m;
    }
}

// ============ prep: gloss fp32 -> transposed hi/lo [b][512][N] AND row-major hi/lo ============
__global__ __launch_bounds__(256) void actT_hl_k(const float* __restrict__ src,
    unsigned short* __restrict__ dstHi, unsigned short* __restrict__ dstLo,
    unsigned short* __restrict__ rmHi, unsigned short* __restrict__ rmLo, int Nrows){
    int b = blockIdx.z;
    int f0 = blockIdx.x*64, g0 = blockIdx.y*64;
    __shared__ float sF[64][65];
    int tid = threadIdx.x;
    #pragma unroll
    for (int it = 0; it < 4; ++it){
        int idx = it*256 + tid;
        int r = idx >> 4, c4 = idx & 15;
        float4 v = *(const float4*)(src + ((size_t)b*Nrows + g0 + r)*512 + f0 + c4*4);
        sF[r][c4*4+0]=v.x; sF[r][c4*4+1]=v.y; sF[r][c4*4+2]=v.z; sF[r][c4*4+3]=v.w;
    }
    __syncthreads();
    #pragma unroll
    for (int it = 0; it < 2; ++it){
        int idx = it*256 + tid;
        int dd = idx >> 3, c8 = idx & 7;
        unsigned short hi[8], lo[8];
        #pragma unroll
        for (int j = 0; j < 8; ++j){
            float x = sF[c8*8+j][dd];
            hi[j] = f2h(x);
            lo[j] = f2h(x - h2f(hi[j]));
        }
        size_t oo = ((size_t)b*512 + f0 + dd)*Nrows + g0 + c8*8;
        *(ushort4*)(dstHi+oo)   = ushort4{hi[0],hi[1],hi[2],hi[3]};
        *(ushort4*)(dstHi+oo+4) = ushort4{hi[4],hi[5],hi[6],hi[7]};
        *(ushort4*)(dstLo+oo)   = ushort4{lo[0],lo[1],lo[2],lo[3]};
        *(ushort4*)(dstLo+oo+4) = ushort4{lo[4],lo[5],lo[6],lo[7]};
    }
    #pragma unroll
    for (int it = 0; it < 2; ++it){
        int idx = it*256 + tid;
        int r = idx >> 3, c8 = idx & 7;
        unsigned short hi[8], lo[8];
        #pragma unroll
        for (int j = 0; j < 8; ++j){
            float x = sF[r][c8*8+j];
            hi[j] = f2h(x);
            lo[j] = f2h(x - h2f(hi[j]));
        }
        size_t oo = ((size_t)b*Nrows + g0 + r)*512 + f0 + c8*8;
        *(ushort4*)(rmHi+oo)   = ushort4{hi[0],hi[1],hi[2],hi[3]};
        *(ushort4*)(rmHi+oo+4) = ushort4{hi[4],hi[5],hi[6],hi[7]};
        *(ushort4*)(rmLo+oo)   = ushort4{lo[0],lo[1],lo[2],lo[3]};
        *(ushort4*)(rmLo+oo+4) = ushort4{lo[4],lo[5],lo[6],lo[7]};
    }
}

// ============ batched scores: all 3 attns' q and k scores in one launch ============
__global__ __launch_bounds__(256) void scores3_k(
    const unsigned short* __restrict__ g, const unsigned short* __restrict__ c,
    const unsigned short* __restrict__ q,
    const float* __restrict__ wa13, const float* __restrict__ wa23,
    float* __restrict__ qs3, float* __restrict__ ks3){
    int lane = threadIdx.x & 63;
    int grow = blockIdx.x*4 + (threadIdx.x >> 6);
    int b = grow / 4608; int r = grow - b*4608;
    const unsigned short* X; const float* wa; float* out; int n, oOff, rowsX;
    if (r < SEG){
        out = qs3;
        if (r < 1024)      { X=g; wa=wa13;        n=r;        oOff=0;    rowsX=NG; }
        else if (r < 1280) { X=q; wa=wa13+4096;   n=r-1024;   oOff=1024; rowsX=NQ; }
        else               { X=g; wa=wa13+8192;   n=r-1280;   oOff=1280; rowsX=NG; }
    } else {
        out = ks3; r -= SEG;
        if (r < 1024)      { X=c; wa=wa23;        n=r;        oOff=0;    rowsX=NC; }
        else if (r < 2048) { X=g; wa=wa23+4096;   n=r-1024;   oOff=1024; rowsX=NG; }
        else               { X=q; wa=wa23+8192;   n=r-2048;   oOff=2048; rowsX=NQ; }
    }
    const unsigned short* Xr = X + ((size_t)b*rowsX + n)*NFEAT;
    float p[NHEADS];
    #pragma unroll
    for (int h = 0; h < NHEADS; ++h) p[h] = 0.f;
    #pragma unroll
    for (int cc = 0; cc < 8; ++cc){
        float x = h2f(Xr[(cc<<6) + lane]);
        #pragma unroll
        for (int h = 0; h < NHEADS; ++h) p[h] += x * wa[(h<<9) + (cc<<6) + lane];
    }
    #pragma unroll
    for (int h = 0; h < NHEADS; ++h){
        float v = p[h];
        #pragma unroll
        for (int off = 32; off > 0; off >>= 1) v += __shfl_xor(v, off);
        if (lane == 0) out[((size_t)b*SEG + oOff + n)*8 + h] = v;
    }
}

// ============ batched WkT gemm: WkT3[b][512][2304] = {clip,gloss,question} @ WT3[a]^T ============
__global__ __launch_bounds__(256) void wkt3_mfma_k(
    const unsigned short* __restrict__ c, const unsigned short* __restrict__ g,
    const unsigned short* __restrict__ q, const unsigned short* __restrict__ WT3,
    unsigned short* __restrict__ WkT3){
    int b = blockIdx.z;
    int y = blockIdx.y;
    const unsigned short* kv; int rowsX, mOff, a;
    if (y < 16)      { a=0; kv=c; rowsX=NC; mOff=0; }
    else if (y < 32) { a=1; y-=16; kv=g; rowsX=NG; mOff=1024; }
    else             { a=2; y-=32; kv=q; rowsX=NQ; mOff=2048; }
    int r0 = y*64, c0 = blockIdx.x*64;
    int tid = threadIdx.x;
    __shared__ alignas(16) unsigned short aS[2][2048], bS[2][2048];
    const unsigned short* aG = kv + (size_t)b*rowsX*512;
    const unsigned short* bG = WT3 + (size_t)a*FF;
    int w = tid >> 6, lane = tid & 63;
    int lrow = lane & 15, quad = lane >> 4;
    int sr = tid >> 2;
    int sq = (tid & 3) ^ ((sr >> 1) & 3);
    size_t aRow = (size_t)(r0 + sr)*512 + sq*8;
    size_t bRow = (size_t)(c0 + sr)*512 + sq*8;
    v4f acc[4];
    #pragma unroll
    for (int cf = 0; cf < 4; ++cf) acc[cf] = (v4f)0.f;
    GLDS(aG + aRow, &aS[0][w << 9]);
    GLDS(bG + bRow, &bS[0][w << 9]);
    __syncthreads();
    int buf = 0;
    for (int s = 0; s < 16; ++s){
        if (s < 15){
            int ktn = (s + 1) << 5;
            GLDS(aG + aRow + ktn, &aS[buf^1][w << 9]);
            GLDS(bG + bRow + ktn, &bS[buf^1][w << 9]);
        }
        v8h af = *(const v8h*)&aS[buf][ldsw(w*16 + lrow, quad)];
        #pragma unroll
        for (int cf = 0; cf < 4; ++cf){
            v8h bf = *(const v8h*)&bS[buf][ldsw(cf*16 + lrow, quad)];
            acc[cf] = MFMA16(af, bf, acc[cf]);
        }
        __syncthreads();
        buf ^= 1;
    }
    #pragma unroll
    for (int cf = 0; cf < 4; ++cf){
        int colg = c0 + cf*16 + lrow;
        int rbase = r0 + w*16 + quad*4;
        ushort4 pk{f2h(acc[cf][0]), f2h(acc[cf][1]), f2h(acc[cf][2]), f2h(acc[cf][3])};
        *(ushort4*)&WkT3[((size_t)b*512 + colg)*SEG + mOff + rbase] = pk;
    }
}

// ============ batched colstat: all 3 attns, per-chunk (cm, sum) via bitmasks ============
__global__ __launch_bounds__(256) void colstat3_k(
    const unsigned* __restrict__ bm_cg, const unsigned* __restrict__ bm_gq,
    const unsigned* __restrict__ bm_qg,
    const float* __restrict__ qs3, const float* __restrict__ ks3,
    float* __restrict__ pcm, float* __restrict__ psum){
    int x = blockIdx.x, b = blockIdx.z;
    const unsigned* bm; int Mrows, N, N32, mOff, qOff;
    if (x < 256)      { bm=bm_cg; Mrows=NC; N=NG; N32=NG/32; mOff=0;    qOff=0; }
    else if (x < 512) { x-=256; bm=bm_gq; Mrows=NG; N=NQ; N32=NQ/32; mOff=1024; qOff=1024; }
    else              { x-=512; bm=bm_qg; Mrows=NQ; N=NG; N32=NG/32; mOff=2048; qOff=1280; }
    int mt = x >> 4, ch = x & 15;
    int chunk = N / CHUNKS, subl = chunk >> 2;
    int ml = threadIdx.x & 63; int m = mt*64 + ml;
    int g = threadIdx.x >> 6;
    int n0 = ch*chunk + g*subl;
    __shared__ float sQ[64][8];
    for (int t2 = threadIdx.x; t2 < chunk*8; t2 += 256)
        sQ[t2>>3][t2&7] = qs3[((size_t)b*SEG + qOff + ch*chunk)*8 + t2];
    float ksv[8];
    size_t mo = ((size_t)b*SEG + mOff + m)*8;
    #pragma unroll
    for (int h = 0; h < 8; ++h) ksv[h] = ks3[mo+h];
    unsigned word = bm[((size_t)b*Mrows + m)*N32 + (n0>>5)];
    unsigned bits = (word >> (n0 & 31)) & ((1u << subl) - 1u);
    __syncthreads();
    int nb = g*subl;
    float mx[8];
    #pragma unroll
    for (int h = 0; h < 8; ++h) mx[h] = -INFINITY;
    for (int i = 0; i < subl; ++i){
        if ((bits >> i) & 1){
            #pragma unroll
            for (int h = 0; h < 8; ++h) mx[h] = fmaxf(mx[h], sQ[nb+i][h]);
        }
    }
    float cm[8], s[8];
    #pragma unroll
    for (int h = 0; h < 8; ++h){
        cm[h] = bits ? lrelu(mx[h] + ksv[h]) : NEGV;
        s[h] = 0.f;
    }
    for (int i = 0; i < subl; ++i){
        bool on = (bits >> i) & 1;
        #pragma unroll
        for (int h = 0; h < 8; ++h){
            float e = on ? lrelu(sQ[nb+i][h] + ksv[h]) : NEGV;
            s[h] += __expf(e - cm[h]);
        }
    }
    __shared__ float scm[4][64][8], ssm[4][64][8];
    #pragma unroll
    for (int h = 0; h < 8; ++h){ scm[g][ml][h] = cm[h]; ssm[g][ml][h] = s[h]; }
    __syncthreads();
    if (g == 0){
        #pragma unroll
        for (int h = 0; h < 8; ++h){
            float c0 = scm[0][ml][h], c1 = scm[1][ml][h], c2 = scm[2][ml][h], c3 = scm[3][ml][h];
            float CM = fmaxf(fmaxf(c0, c1), fmaxf(c2, c3));
            float S = ssm[0][ml][h]*__expf(c0-CM) + ssm[1][ml][h]*__expf(c1-CM)
                    + ssm[2][ml][h]*__expf(c2-CM) + ssm[3][ml][h]*__expf(c3-CM);
            size_t o = (((size_t)b*CHUNKS + ch)*SEG + mOff + m)*8 + h;
            pcm[o] = CM; psum[o] = S;
        }
    }
}

// ============ batched finalize: chunk-combine + repack -> ksh/cmh/ish [b][8][SEG] ============
__global__ __launch_bounds__(256) void colfin3_k(const float* __restrict__ pcm, const float* __restrict__ psum,
    const float* __restrict__ ks3, float* __restrict__ ksh, float* __restrict__ cmh,
    float* __restrict__ ish){
    int idx = blockIdx.x*256 + threadIdx.x;    // NB*SEG*8
    const int m8 = SEG*8;
    int b = idx / m8, rem = idx - b*m8;
    int m = rem >> 3, h = rem & 7;
    size_t base = (size_t)b*CHUNKS*m8 + rem;
    float c[CHUNKS], s[CHUNKS];
    #pragma unroll
    for (int ch = 0; ch < CHUNKS; ++ch){
        c[ch] = pcm[base + (size_t)ch*m8];
        s[ch] = psum[base + (size_t)ch*m8];
    }
    float CM = c[0];
    #pragma unroll
    for (int ch = 1; ch < CHUNKS; ++ch) CM = fmaxf(CM, c[ch]);
    float S = 0.f;
    #pragma unroll
    for (int ch = 0; ch < CHUNKS; ++ch) S += s[ch]*__expf(c[ch] - CM);
    size_t o = ((size_t)b*8 + h)*SEG + m;
    ksh[o] = ks3[idx]; cmh[o] = CM; ish[o] = 1.f/S;
}

// ============ 3-pass fusion body (shared LDS passed in) ============
__device__ __forceinline__ void fusion3_body(int F,
    unsigned short* aHs, unsigned short* bHs, unsigned short* aLs, unsigned short* bLs,
    unsigned short* wHs, unsigned short* wLs,
    const unsigned short* aHi, const unsigned short* aLo,
    const unsigned short* bHi, const unsigned short* bLo,
    const unsigned short* Whi, const unsigned short* Wlo,
    unsigned short* dst, unsigned short* dstLo,
    unsigned short* dstT, unsigned short* dstTLo,
    float* dstF, int rows){
    int nY = rows >> 6;
    int ppg = (nY * NB) >> 3;
    int xcd = F & 7, t = F >> 3;
    int c0i = t / ppg;
    int p = xcd + ((t - c0i*ppg) << 3);
    int r0 = (p % nY) << 6, c0 = c0i << 6;
    int b = p / nY;
    int tid = threadIdx.x;
    size_t actOff = (size_t)b*rows*512;
    const unsigned short* aHG = aHi + actOff;
    const unsigned short* bHG = bHi + actOff;
    const unsigned short* aLG = aLo ? aLo + actOff : nullptr;
    const unsigned short* bLG = bLo ? bLo + actOff : nullptr;
    bool hasALo = (aLG != nullptr);
    bool hasBLo = (bLG != nullptr);
    int w = tid >> 6, lane = tid & 63;
    int wr = w >> 1, wc = w & 1;
    int lrow = lane & 15, quad = lane >> 4;
    int sr = tid >> 2;
    int sq = (tid & 3) ^ ((sr >> 1) & 3);
    size_t aRow = (size_t)(r0 + sr)*512 + sq*8;
    size_t wPk = (size_t)c0i*16*8192 + (size_t)sr*32 + sq*8;
    unsigned short* ldsA  = &aHs[w << 9];
    unsigned short* ldsB  = &bHs[w << 9];
    unsigned short* ldsAL = &aLs[w << 9];
    unsigned short* ldsBL = &bLs[w << 9];
    v4f accN[2][2], accF[2][2];
    #pragma unroll
    for (int r = 0; r < 2; ++r)
        #pragma unroll
        for (int cf = 0; cf < 2; ++cf){ accN[r][cf] = (v4f)0.f; accF[r][cf] = (v4f)0.f; }
    for (int kt = 0; kt < 512; kt += 32){
        __syncthreads();
        GLDS(aHG + aRow + kt, ldsA);
        GLDS(bHG + aRow + kt, ldsB);
        if (hasALo) GLDS(aLG + aRow + kt, ldsAL);
        if (hasBLo) GLDS(bLG + aRow + kt, ldsBL);
        size_t wk = wPk + (size_t)(kt >> 5)*8192;
        #pragma unroll
        for (int m = 0; m < 4; ++m){
            GLDS(Whi + wk + (m<<11), &wHs[(m<<11) + (w<<9)]);
            GLDS(Wlo + wk + (m<<11), &wLs[(m<<11) + (w<<9)]);
        }
        __syncthreads();
        v8h ah[2], bh[2], al[2], bl[2];
        #pragma unroll
        for (int r = 0; r < 2; ++r){
            int ao = ldsw(wr*32 + r*16 + lrow, quad);
            ah[r] = *(const v8h*)&aHs[ao];
            bh[r] = *(const v8h*)&bHs[ao];
            if (hasALo) al[r] = *(const v8h*)&aLs[ao];
            if (hasBLo) bl[r] = *(const v8h*)&bLs[ao];
        }
        #pragma unroll
        for (int cf = 0; cf < 2; ++cf){
            int wo = ldsw(wc*32 + cf*16 + lrow, quad);
            v8h w0 = *(const v8h*)&wHs[wo];
            v8h w1 = *(const v8h*)&wHs[2048 + wo];
            v8h w2 = *(const v8h*)&wHs[4096 + wo];
            v8h w3 = *(const v8h*)&wHs[6144 + wo];
            v8h l0 = *(const v8h*)&wLs[wo];
            v8h l1 = *(const v8h*)&wLs[2048 + wo];
            v8h l2 = *(const v8h*)&wLs[4096 + wo];
            v8h l3 = *(const v8h*)&wLs[6144 + wo];
            #pragma unroll
            for (int r = 0; r < 2; ++r){
                accN[r][cf] = MFMA16(ah[r], w0, accN[r][cf]);
                accN[r][cf] = MFMA16(bh[r], w1, accN[r][cf]);
                accF[r][cf] = MFMA16(ah[r], w2, accF[r][cf]);
                accF[r][cf] = MFMA16(bh[r], w3, accF[r][cf]);
                if (hasALo){ accN[r][cf] = MFMA16(al[r], w0, accN[r][cf]); accF[r][cf] = MFMA16(al[r], w2, accF[r][cf]); }
                if (hasBLo){ accN[r][cf] = MFMA16(bl[r], w1, accN[r][cf]); accF[r][cf] = MFMA16(bl[r], w3, accF[r][cf]); }
                accN[r][cf] = MFMA16(ah[r], l0, accN[r][cf]);
                accN[r][cf] = MFMA16(bh[r], l1, accN[r][cf]);
                accF[r][cf] = MFMA16(ah[r], l2, accF[r][cf]);
                accF[r][cf] = MFMA16(bh[r], l3, accF[r][cf]);
            }
        }
    }
    #pragma unroll
    for (int r = 0; r < 2; ++r)
        #pragma unroll
        for (int cf = 0; cf < 2; ++cf){
            int colg = c0 + wc*32 + cf*16 + lrow;
            int rbase = r0 + wr*32 + r*16 + quad*4;
            float o4[4];
            #pragma unroll
            for (int reg = 0; reg < 4; ++reg){
                float f = 1.f/(1.f + __expf(-accF[r][cf][reg]));
                size_t ai = (size_t)(rbase+reg)*512 + colg;
                float ao = h2f(aHG[ai]);
                if (aLG) ao += h2f(aLG[ai]);
                o4[reg] = f*accN[r][cf][reg] + (1.f - f)*ao;
                size_t oo = ((size_t)b*rows + rbase + reg)*512 + colg;
                unsigned short hv = f2h(o4[reg]);
                dst[oo] = hv;
                if (dstLo) dstLo[oo] = f2h(o4[reg] - h2f(hv));
                if (dstF) dstF[oo] = o4[reg];
            }
            if (dstT){
                unsigned short h0 = f2h(o4[0]), h1 = f2h(o4[1]), h2 = f2h(o4[2]), h3 = f2h(o4[3]);
                size_t to = ((size_t)b*512 + colg)*rows + rbase;
                *(ushort4*)&dstT[to] = ushort4{h0,h1,h2,h3};
                if (dstTLo)
                    *(ushort4*)&dstTLo[to] = ushort4{f2h(o4[0]-h2f(h0)), f2h(o4[1]-h2f(h1)),
                                                     f2h(o4[2]-h2f(h2)), f2h(o4[3]-h2f(h3))};
            }
        }
}

// ============ batched 3-pass fusion: seg0 clip_1 (NC), seg1 gloss_2 (NG) ============
__global__ __launch_bounds__(256) void fusion3b_k(
    const unsigned short* __restrict__ a0, const unsigned short* __restrict__ a0Lo,
    const unsigned short* __restrict__ b0, const unsigned short* __restrict__ b0Lo,
    const unsigned short* __restrict__ W0hi, const unsigned short* __restrict__ W0lo,
    unsigned short* __restrict__ d0, unsigned short* __restrict__ d0Lo, float* __restrict__ d0F,
    const unsigned short* __restrict__ a1, const unsigned short* __restrict__ a1Lo,
    const unsigned short* __restrict__ b1,
    const unsigned short* __restrict__ W1hi, const unsigned short* __restrict__ W1lo,
    unsigned short* __restrict__ d1, unsigned short* __restrict__ d1Lo,
    unsigned short* __restrict__ d1T, unsigned short* __restrict__ d1TLo, float* __restrict__ d1F){
    __shared__ alignas(16) unsigned short aHs[2048], bHs[2048], aLs[2048], bLs[2048];
    __shared__ alignas(16) unsigned short wHs[8192], wLs[8192];
    int F = blockIdx.x;
    const int S0 = 8*(NC/64)*NB;
    if (F < S0)
        fusion3_body(F, aHs, bHs, aLs, bLs, wHs, wLs,
                     a0, a0Lo, b0, b0Lo, W0hi, W0lo,
                     d0, d0Lo, nullptr, nullptr, d0F, NC);
    else
        fusion3_body(F - S0, aHs, bHs, aLs, bLs, wHs, wLs,
                     a1, a1Lo, b1, nullptr, W1hi, W1lo,
                     d1, d1Lo, d1T, d1TLo, d1F, NG);
}

// ============ 1-pass fusion body (double-buffered; shared LDS passed in) ============
__device__ __forceinline__ void fusion1_body(int F,
    unsigned short (*aHs)[2048], unsigned short (*bHs)[2048], unsigned short (*wHs)[8192],
    const unsigned short* aHi, const unsigned short* aLo,
    const unsigned short* bHi, const unsigned short* Whi,
    unsigned short* dst, unsigned short* dstLo, float* dstF, int rows){
    int nY = rows >> 6;
    int ppg = (nY * NB) >> 3;
    int xcd = F & 7, t = F >> 3;
    int c0i = t / ppg;
    int p = xcd + ((t - c0i*ppg) << 3);
    int r0 = (p % nY) << 6, c0 = c0i << 6;
    int b = p / nY;
    int tid = threadIdx.x;
    size_t actOff = (size_t)b*rows*512;
    const unsigned short* aHG = aHi + actOff;
    const unsigned short* bHG = bHi + actOff;
    const unsigned short* aLG = aLo ? aLo + actOff : nullptr;
    int w = tid >> 6, lane = tid & 63;
    int wr = w >> 1, wc = w & 1;
    int lrow = lane & 15, quad = lane >> 4;
    int sr = tid >> 2;
    int sq = (tid & 3) ^ ((sr >> 1) & 3);
    size_t aRow = (size_t)(r0 + sr)*512 + sq*8;
    size_t wPk = (size_t)c0i*16*8192 + (size_t)sr*32 + sq*8;
    v4f accN[2][2], accF[2][2];
    #pragma unroll
    for (int r = 0; r < 2; ++r)
        #pragma unroll
        for (int cf = 0; cf < 2; ++cf){ accN[r][cf] = (v4f)0.f; accF[r][cf] = (v4f)0.f; }

    #define F1STAGE(bb, kk) do{ \
        GLDS(aHG + aRow + (kk), &aHs[bb][w << 9]); \
        GLDS(bHG + aRow + (kk), &bHs[bb][w << 9]); \
        size_t wk_ = wPk + (size_t)((kk) >> 5)*8192; \
        GLDS(Whi + wk_,          &wHs[bb][(0<<11) + (w<<9)]); \
        GLDS(Whi + wk_ + (1<<11), &wHs[bb][(1<<11) + (w<<9)]); \
        GLDS(Whi + wk_ + (2<<11), &wHs[bb][(2<<11) + (w<<9)]); \
        GLDS(Whi + wk_ + (3<<11), &wHs[bb][(3<<11) + (w<<9)]); \
    } while(0)

    F1STAGE(0, 0);
    __syncthreads();
    int buf = 0;
    for (int kt = 0; kt < 512; kt += 32){
        if (kt + 32 < 512) F1STAGE(buf^1, kt + 32);
        v8h ah[2], bh[2];
        #pragma unroll
        for (int r = 0; r < 2; ++r){
            int ao = ldsw(wr*32 + r*16 + lrow, quad);
            ah[r] = *(const v8h*)&aHs[buf][ao];
            bh[r] = *(const v8h*)&bHs[buf][ao];
        }
        #pragma unroll
        for (int cf = 0; cf < 2; ++cf){
            int wo = ldsw(wc*32 + cf*16 + lrow, quad);
            v8h w0 = *(const v8h*)&wHs[buf][wo];
            v8h w1 = *(const v8h*)&wHs[buf][2048 + wo];
            v8h w2 = *(const v8h*)&wHs[buf][4096 + wo];
            v8h w3 = *(const v8h*)&wHs[buf][6144 + wo];
            #pragma unroll
            for (int r = 0; r < 2; ++r){
                accN[r][cf] = MFMA16(ah[r], w0, accN[r][cf]);
                accN[r][cf] = MFMA16(bh[r], w1, accN[r][cf]);
                accF[r][cf] = MFMA16(ah[r], w2, accF[r][cf]);
                accF[r][cf] = MFMA16(bh[r], w3, accF[r][cf]);
            }
        }
        __syncthreads();
        buf ^= 1;
    }
    #undef F1STAGE
    #pragma unroll
    for (int r = 0; r < 2; ++r)
        #pragma unroll
        for (int cf = 0; cf < 2; ++cf){
            int colg = c0 + wc*32 + cf*16 + lrow;
            int rbase = r0 + wr*32 + r*16 + quad*4;
            #pragma unroll
            for (int reg = 0; reg < 4; ++reg){
                float f = 1.f/(1.f + __expf(-accF[r][cf][reg]));
                size_t ai = (size_t)(rbase+reg)*512 + colg;
                float ao = h2f(aHG[ai]);
                if (aLG) ao += h2f(aLG[ai]);
                float o = f*accN[r][cf][reg] + (1.f - f)*ao;
                size_t oo = ((size_t)b*rows + rbase + reg)*512 + colg;
                unsigned short hv = f2h(o);
                dst[oo] = hv;
                if (dstLo) dstLo[oo] = f2h(o - h2f(hv));
                if (dstF) dstF[oo] = o;
            }
        }
}

// ============ batched 1-pass fusion: seg0 gloss_1 (NG), seg1 question_1 (NQ) ============
__global__ __launch_bounds__(256) void fusion1b_k(
    const unsigned short* __restrict__ a0, const unsigned short* __restrict__ a0Lo,
    const unsigned short* __restrict__ b0, const unsigned short* __restrict__ W0,
    unsigned short* __restrict__ d0, unsigned short* __restrict__ d0Lo,
    const unsigned short* __restrict__ a1, const unsigned short* __restrict__ b1,
    const unsigned short* __restrict__ W1,
    unsigned short* __restrict__ d1, float* __restrict__ d1F){
    __shared__ alignas(16) unsigned short aHs[2][2048], bHs[2][2048];
    __shared__ alignas(16) unsigned short wHs[2][8192];
    int F = blockIdx.x;
    const int S0 = 8*(NG/64)*NB;
    if (F < S0)
        fusion1_body(F, aHs, bHs, wHs, a0, a0Lo, b0, W0, d0, d0Lo, nullptr, NG);
    else
        fusion1_body(F - S0, aHs, bHs, wHs, a1, nullptr, b1, W1, d1, nullptr, d1F, NQ);
}

// ============ generic MFMA GEMM (64-row tiles, double-buffered) — gloss_same only ============
__global__ __launch_bounds__(256) void gemmT_mfma_k(
    const unsigned short* __restrict__ A, size_t aStride,
    const unsigned short* __restrict__ BT, const unsigned short* __restrict__ BT2, size_t bStride,
    int K, int rowsPB,
    unsigned short* __restrict__ outRM, unsigned short* __restrict__ outLo,
    unsigned short* __restrict__ outT){
    int b = blockIdx.z;
    int r0 = blockIdx.y*64, c0 = blockIdx.x*64;
    int tid = threadIdx.x;
    __shared__ alignas(16) unsigned short aS[2][2048], bS[2][2048];
    const unsigned short* aG = A + (size_t)b*aStride;
    const unsigned short* bG0 = BT + (size_t)b*bStride;
    const unsigned short* bG1 = BT2 ? BT2 + (size_t)b*bStride : nullptr;
    int w = tid >> 6, lane = tid & 63;
    int lrow = lane & 15, quad = lane >> 4;
    int sr = tid >> 2;
    int sq = (tid & 3) ^ ((sr >> 1) & 3);
    size_t aRow = (size_t)(r0 + sr)*K + sq*8;
    size_t bRow = (size_t)(c0 + sr)*K + sq*8;
    int spp = K >> 5;
    int nsteps = (BT2 ? 2 : 1)*spp;
    v4f acc[4];
    #pragma unroll
    for (int cf = 0; cf < 4; ++cf) acc[cf] = (v4f)0.f;
    GLDS(aG + aRow, &aS[0][w << 9]);
    GLDS(bG0 + bRow, &bS[0][w << 9]);
    __syncthreads();
    int buf = 0;
    for (int s = 0; s < nsteps; ++s){
        int sn = s + 1;
        if (sn < nsteps){
            int ktn = ((sn >= spp) ? (sn - spp) : sn) << 5;
            const unsigned short* bgn = (sn >= spp) ? bG1 : bG0;
            GLDS(aG + aRow + ktn, &aS[buf^1][w << 9]);
            GLDS(bgn + bRow + ktn, &bS[buf^1][w << 9]);
        }
        v8h af = *(const v8h*)&aS[buf][ldsw(w*16 + lrow, quad)];
        #pragma unroll
        for (int cf = 0; cf < 4; ++cf){
            v8h bf = *(const v8h*)&bS[buf][ldsw(cf*16 + lrow, quad)];
            acc[cf] = MFMA16(af, bf, acc[cf]);
        }
        __syncthreads();
        buf ^= 1;
    }
    #pragma unroll
    for (int cf = 0; cf < 4; ++cf){
        int colg = c0 + cf*16 + lrow;
        int rbase = r0 + w*16 + quad*4;
        if (outRM){
            #pragma unroll
            for (int reg = 0; reg < 4; ++reg){
                float v = acc[cf][reg];
                unsigned short hv = f2h(v);
                size_t oo = ((size_t)b*rowsPB + rbase + reg)*512 + colg;
                outRM[oo] = hv;
                if (outLo) outLo[oo] = f2h(v - h2f(hv));
            }
        }
        if (outT){
            ushort4 pk{f2h(acc[cf][0]), f2h(acc[cf][1]), f2h(acc[cf][2]), f2h(acc[cf][3])};
            *(ushort4*)&outT[((size_t)b*512 + colg)*rowsPB + rbase] = pk;
        }
    }
}

// ============ attention output body (shared LDS passed in) ============
__device__ __forceinline__ void attn_body(int F,
    unsigned short* pS, unsigned short* wS, float* qsS, float* sKs, float* sCm, float* sIs,
    const unsigned* bmN, int M32,
    const float* qs3, int qOff,
    const float* ksh, const float* cmh, const float* ish,
    int mOff, const unsigned short* WkT3,
    unsigned short* outp, int N, int M){
    int nN0 = N >> 6;
    int xcd = F & 7, t = F >> 3;
    int bh = xcd*4 + t/nN0;
    int n0 = (t % nN0) << 6;
    int b = bh >> 3, h = bh & 7;
    int tid = threadIdx.x;
    const float* ksb = ksh + ((size_t)b*8 + h)*SEG + mOff;
    const float* cmb = cmh + ((size_t)b*8 + h)*SEG + mOff;
    const float* isb = ish + ((size_t)b*8 + h)*SEG + mOff;
    const unsigned short* wkb = WkT3 + ((size_t)b*512 + h*64)*SEG + mOff;
    int w = tid >> 6, lane = tid & 63;
    int lrow = lane & 15, quad = lane >> 4;
    int pn = tid >> 2, pm = (tid & 3)*8;
    int sr = tid >> 2;
    int sq = (tid & 3) ^ ((sr >> 1) & 3);
    for (int o = w*256; o < M; o += 1024){
        GLDS(ksb + o + lane*4, &sKs[o]);
        GLDS(cmb + o + lane*4, &sCm[o]);
        GLDS(isb + o + lane*4, &sIs[o]);
    }
    if (tid < 64) qsS[tid] = qs3[((size_t)b*SEG + qOff + n0 + tid)*8 + h];
    const unsigned* bmrow = bmN + ((size_t)b*N + n0 + pn)*M32;
    v4f acc[4];
    #pragma unroll
    for (int cf = 0; cf < 4; ++cf) acc[cf] = (v4f)0.f;
    uint2 CW = *(const uint2*)(bmrow);
    uint2 NW;
    __syncthreads();
    float qv = qsS[pn];
    for (int mt = 0; mt < M; mt += 64){
        int mtB = mt + 32;
        int mtN = (mt + 64 < M) ? (mt + 64) : 0;
        GLDS(wkb + (size_t)sr*SEG + mt + sq*8, &wS[w << 9]);
        {
            unsigned bb = (CW.x >> pm) & 0xffu;
            float4 k0 = *(const float4*)&sKs[mt+pm], k1 = *(const float4*)&sKs[mt+pm+4];
            float4 c0 = *(const float4*)&sCm[mt+pm], c1 = *(const float4*)&sCm[mt+pm+4];
            float4 i0 = *(const float4*)&sIs[mt+pm], i1 = *(const float4*)&sIs[mt+pm+4];
            float p[8];
            const float* kk0 = &k0.x; const float* kk1 = &k1.x;
            const float* cc0 = &c0.x; const float* cc1 = &c1.x;
            const float* ii0 = &i0.x; const float* ii1 = &i1.x;
            #pragma unroll
            for (int j = 0; j < 4; ++j){
                float e = ((bb >> j) & 1) ? lrelu(qv + kk0[j]) : NEGV;
                p[j] = __expf(e - cc0[j]) * ii0[j];
            }
            #pragma unroll
            for (int j = 0; j < 4; ++j){
                float e = ((bb >> (4+j)) & 1) ? lrelu(qv + kk1[j]) : NEGV;
                p[4+j] = __expf(e - cc1[j]) * ii1[j];
            }
            *(ushort4*)&pS[pn*LSTR + pm]     = ushort4{f2h(p[0]), f2h(p[1]), f2h(p[2]), f2h(p[3])};
            *(ushort4*)&pS[pn*LSTR + pm + 4] = ushort4{f2h(p[4]), f2h(p[5]), f2h(p[6]), f2h(p[7])};
        }
        __syncthreads();
        {
            v8h af = *(const v8h*)&pS[(w*16 + lrow)*LSTR + quad*8];
            #pragma unroll
            for (int cf = 0; cf < 4; ++cf){
                v8h bf = *(const v8h*)&wS[ldsw(cf*16 + lrow, quad)];
                acc[cf] = MFMA16(af, bf, acc[cf]);
            }
        }
        GLDS(wkb + (size_t)sr*SEG + mtB + sq*8, &wS[2048 + (w << 9)]);
        NW = *(const uint2*)(bmrow + (mtN >> 5));
        {
            unsigned bb = (CW.y >> pm) & 0xffu;
            float4 k0 = *(const float4*)&sKs[mtB+pm], k1 = *(const float4*)&sKs[mtB+pm+4];
            float4 c0 = *(const float4*)&sCm[mtB+pm], c1 = *(const float4*)&sCm[mtB+pm+4];
            float4 i0 = *(const float4*)&sIs[mtB+pm], i1 = *(const float4*)&sIs[mtB+pm+4];
            float p[8];
            const float* kk0 = &k0.x; const float* kk1 = &k1.x;
            const float* cc0 = &c0.x; const float* cc1 = &c1.x;
            const float* ii0 = &i0.x; const float* ii1 = &i1.x;
            #pragma unroll
            for (int j = 0; j < 4; ++j){
                float e = ((bb >> j) & 1) ? lrelu(qv + kk0[j]) : NEGV;
                p[j] = __expf(e - cc0[j]) * ii0[j];
            }
            #pragma unroll
            for (int j = 0; j < 4; ++j){
                float e = ((bb >> (4+j)) & 1) ? lrelu(qv + kk1[j]) : NEGV;
                p[4+j] = __expf(e - cc1[j]) * ii1[j];
            }
            *(ushort4*)&pS[2304 + pn*LSTR + pm]     = ushort4{f2h(p[0]), f2h(p[1]), f2h(p[2]), f2h(p[3])};
            *(ushort4*)&pS[2304 + pn*LSTR + pm + 4] = ushort4{f2h(p[4]), f2h(p[5]), f2h(p[6]), f2h(p[7])};
        }
        __syncthreads();
        {
            v8h af = *(const v8h*)&pS[2304 + (w*16 + lrow)*LSTR + quad*8];
            #pragma unroll
            for (int cf = 0; cf < 4; ++cf){
                v8h bf = *(const v8h*)&wS[2048 + ldsw(cf*16 + lrow, quad)];
                acc[cf] = MFMA16(af, bf, acc[cf]);
            }
        }
        CW = NW;
    }
    #pragma unroll
    for (int cf = 0; cf < 4; ++cf){
        int colg = h*64 + cf*16 + lrow;
        int rbase = n0 + w*16 + quad*4;
        #pragma unroll
        for (int reg = 0; reg < 4; ++reg){
            float v = acc[cf][reg];
            v = (v > 0.f) ? v : (__expf(v) - 1.f);
            outp[((size_t)b*N + rbase + reg)*512 + colg] = f2h(v);
        }
    }
}

// ============ batched attention: attn0 (512 blk) + attn1 (128) + attn2 (512) ============
__global__ __launch_bounds__(256) void attn_all_k(
    const unsigned* __restrict__ bm_gc, const unsigned* __restrict__ bm_qg,
    const unsigned* __restrict__ bm_gq,
    const float* __restrict__ qs3,
    const float* __restrict__ ksh, const float* __restrict__ cmh, const float* __restrict__ ish,
    const unsigned short* __restrict__ WkT3,
    unsigned short* __restrict__ agg0, unsigned short* __restrict__ agg1,
    unsigned short* __restrict__ agg2){
    __shared__ unsigned short pS[2*64*LSTR];
    __shared__ alignas(16) unsigned short wS[2*2048];
    __shared__ float qsS[64];
    __shared__ alignas(16) float sKs[1024], sCm[1024], sIs[1024];
    int F = blockIdx.x;
    const int S0 = (NG/64)*32;            // 512
    const int S1 = S0 + (NQ/64)*32;       // 640
    if (F < S0)
        attn_body(F, pS, wS, qsS, sKs, sCm, sIs, bm_gc, NC/32, qs3, 0,
                  ksh, cmh, ish, 0, WkT3, agg0, NG, NC);
    else if (F < S1)
        attn_body(F - S0, pS, wS, qsS, sKs, sCm, sIs, bm_qg, NG/32, qs3, 1024,
                  ksh, cmh, ish, 1024, WkT3, agg1, NQ, NG);
    else
        attn_body(F - S1, pS, wS, qsS, sKs, sCm, sIs, bm_gq, NQ/32, qs3, 1280,
                  ksh, cmh, ish, 2048, WkT3, agg2, NG, NQ);
}

extern "C" void kernel_launch(void* const* d_in, const int* in_sizes, int n_in,
                              void* d_out, int out_size, void* d_ws, size_t ws_size,
                              hipStream_t stream){
    const float* in_gloss = (const float*)d_in[0];
    const float* in_clip  = (const float*)d_in[1];
    const float* in_q     = (const float*)d_in[2];
    const int*   adj_gc   = (const int*)d_in[3];
    const int*   adj_gq   = (const int*)d_in[4];
    const float* c2gW  = (const float*)d_in[5];
    const float* c2ga1 = (const float*)d_in[6];
    const float* c2ga2 = (const float*)d_in[7];
    const float* g2qW  = (const float*)d_in[8];
    const float* g2qa1 = (const float*)d_in[9];
    const float* g2qa2 = (const float*)d_in[10];
    const float* q2gW  = (const float*)d_in[11];
    const float* q2ga1 = (const float*)d_in[12];
    const float* q2ga2 = (const float*)d_in[13];
    const float* fusW  = (const float*)d_in[14];
    const float* fusU  = (const float*)d_in[15];
    const float* fusWf = (const float*)d_in[16];
    const float* fusUf = (const float*)d_in[17];
    float* out = (float*)d_out;
    float* out_gloss = out;
    float* out_clip  = out + (size_t)NB*NG*NFEAT;
    float* out_q     = out + (size_t)NB*NG*NFEAT*2;

    char* wsB = (char*)d_ws;
    size_t off = 0;
    auto alloc = [&](size_t bytes){ void* p = wsB + off; off += (bytes + 255) & ~(size_t)255; return p; };
    float* wa13  = (float*)alloc(3*4096*4);
    float* wa23  = (float*)alloc(3*4096*4);
    float* qs3   = (float*)alloc((size_t)NB*SEG*8*4);
    float* ks3   = (float*)alloc((size_t)NB*SEG*8*4);
    float* ksh3  = (float*)alloc((size_t)NB*8*SEG*4);
    float* cmh3  = (float*)alloc((size_t)NB*8*SEG*4);
    float* ish3  = (float*)alloc((size_t)NB*8*SEG*4);
    float* pcm   = (float*)alloc((size_t)NB*CHUNKS*SEG*8*4);
    float* psum  = (float*)alloc((size_t)NB*CHUNKS*SEG*8*4);
    unsigned short* WflatT3 = (unsigned short*)alloc((size_t)3*FF*2);
    unsigned short* WkT3    = (unsigned short*)alloc((size_t)NB*512*SEG*2);
    unsigned short* wtAll   = (unsigned short*)alloc((size_t)32*FF*2);
    unsigned short* wtAllLo = (unsigned short*)alloc((size_t)32*FF*2);
    unsigned short* adjTgc  = (unsigned short*)alloc((size_t)NB*NC*NG*2);
    unsigned short* g_bf0   = (unsigned short*)alloc((size_t)NB*NG*NFEAT*2);
    unsigned short* gLo0    = (unsigned short*)alloc((size_t)NB*NG*NFEAT*2);
    unsigned short* g_bf1   = (unsigned short*)alloc((size_t)NB*NG*NFEAT*2);
    unsigned short* gLo1    = (unsigned short*)alloc((size_t)NB*NG*NFEAT*2);
    unsigned short* gT      = (unsigned short*)alloc((size_t)NB*NFEAT*NG*2);
    unsigned short* gTlo    = (unsigned short*)alloc((size_t)NB*NFEAT*NG*2);
    unsigned short* gA_bf   = (unsigned short*)alloc((size_t)NB*NG*NFEAT*2);
    unsigned short* gALo    = (unsigned short*)alloc((size_t)NB*NG*NFEAT*2);
    unsigned short* c_bf0   = (unsigned short*)alloc((size_t)NB*NC*NFEAT*2);
    unsigned short* cLo0    = (unsigned short*)alloc((size_t)NB*NC*NFEAT*2);
    unsigned short* c_bf1   = (unsigned short*)alloc((size_t)NB*NC*NFEAT*2);
    unsigned short* cLo1    = (unsigned short*)alloc((size_t)NB*NC*NFEAT*2);
    unsigned short* q_bf0   = (unsigned short*)alloc((size_t)NB*NQ*NFEAT*2);
    unsigned short* q_bf1   = (unsigned short*)alloc((size_t)NB*NQ*NFEAT*2);
    unsigned short* agg_bf  = (unsigned short*)alloc((size_t)NB*NG*NFEAT*2);
    unsigned short* aggLo   = (unsigned short*)alloc((size_t)NB*NG*NFEAT*2);
    unsigned short* agg0    = (unsigned short*)alloc((size_t)NB*NG*NFEAT*2);
    unsigned short* agg1    = (unsigned short*)alloc((size_t)NB*NQ*NFEAT*2);
    unsigned short* agg2    = (unsigned short*)alloc((size_t)NB*NG*NFEAT*2);
    int* adjTgq = (int*)alloc((size_t)NB*NQ*NG*4);
    unsigned* bm_gc = (unsigned*)alloc((size_t)NB*NG*(NC/32)*4);
    unsigned* bm_cg = (unsigned*)alloc((size_t)NB*NC*(NG/32)*4);
    unsigned* bm_gq = (unsigned*)alloc((size_t)NB*NG*(NQ/32)*4);
    unsigned* bm_qg = (unsigned*)alloc((size_t)NB*NQ*(NG/32)*4);
    (void)ws_size; (void)in_sizes; (void)n_in; (void)out_size;

    const size_t HFD = (size_t)NHEADS*NFEAT*HDIM;
    const size_t HD  = (size_t)NHEADS*HDIM;

    // ---- prep ----
    wtT_k<<<2048, 256, 0, stream>>>(fusW, fusU, fusWf, fusUf, wtAll, wtAllLo);
    adjT_h_k<<<dim3(NC/64, NG/64, NB), 256, 0, stream>>>(adj_gc, adjTgc,
        (unsigned long long*)bm_gc, (unsigned long long*)bm_cg);
    adjT_int_k<<<dim3(NQ/64, NG/64, NB), 256, 0, stream>>>(adj_gq, adjTgq,
        (unsigned long long*)bm_gq, (unsigned long long*)bm_qg);
    cvt_hl_k<<<(NB*NC*NFEAT)/2048, 256, 0, stream>>>(in_clip,  c_bf0, cLo0);
    cvt_h_k<<<(NB*NQ*NFEAT)/2048, 256, 0, stream>>>(in_q,     q_bf0);
    actT_hl_k<<<dim3(8, NG/64, NB), 256, 0, stream>>>(in_gloss, gT, gTlo, g_bf0, gLo0, NG);

    for (int l = 0; l < 2; ++l){
        const unsigned short* g_cur = (l == 0) ? g_bf0 : g_bf1;
        const unsigned short* gLoC  = (l == 0) ? gLo0  : gLo1;
        const unsigned short* c_cur = (l == 0) ? c_bf0 : c_bf1;
        const unsigned short* cLoC  = (l == 0) ? cLo0  : cLo1;
        const unsigned short* q_cur = (l == 0) ? q_bf0 : q_bf1;
        unsigned short* g_nxt = (l == 0) ? g_bf1 : g_bf0;
        unsigned short* gLoN  = (l == 0) ? gLo1  : nullptr;
        unsigned short* c_nxt = (l == 0) ? c_bf1 : c_bf0;
        unsigned short* cLoN  = (l == 0) ? cLo1  : nullptr;
        unsigned short* q_nxt = (l == 0) ? q_bf1 : q_bf0;
        float* gF = (l == 1) ? out_gloss : nullptr;
        float* cF = (l == 1) ? out_clip  : nullptr;
        float* qF = (l == 1) ? out_q     : nullptr;

        // ---- batched attention prep (depends only on layer inputs) ----
        prep_attnW3_k<<<240, 256, 0, stream>>>(
            c2gW + l*HFD, c2ga1 + l*HD, c2ga2 + l*HD,
            g2qW + l*HFD, g2qa1 + l*HD, g2qa2 + l*HD,
            q2gW + l*HFD, q2ga1 + l*HD, q2ga2 + l*HD,
            WflatT3, wa13, wa23);
        scores3_k<<<(NB*4608)/4, 256, 0, stream>>>(g_cur, c_cur, q_cur, wa13, wa23, qs3, ks3);
        wkt3_mfma_k<<<dim3(8, 36, NB), 256, 0, stream>>>(c_cur, g_cur, q_cur, WflatT3, WkT3);
        colstat3_k<<<dim3(576, 1, NB), 256, 0, stream>>>(bm_cg, bm_gq, bm_qg, qs3, ks3, pcm, psum);
        colfin3_k<<<(NB*SEG*8)/256, 256, 0, stream>>>(pcm, psum, ks3, ksh3, cmh3, ish3);

        // gloss_same = adj_gc^T @ gloss (hi/lo B, hi/lo out)
        gemmT_mfma_k<<<dim3(8, NC/64, NB), 256, 0, stream>>>(adjTgc, (size_t)NC*NG, gT, gTlo,
                                                             (size_t)512*NG, NG, NC,
                                                             agg_bf, aggLo, nullptr);
        // all 3 attentions in one launch -> agg0 (clip_agg), agg1 (gloss_agg), agg2 (question_agg)
        attn_all_k<<<(NG/64)*32 + (NQ/64)*32 + (NG/64)*32, 256, 0, stream>>>(
            bm_gc, bm_qg, bm_gq, qs3, ksh3, cmh3, ish3, WkT3, agg0, agg1, agg2);
        // gloss_1 + question_1 in one launch
        fusion1b_k<<<8*(NG/64)*NB + 8*(NQ/64)*NB, 256, 0, stream>>>(
            g_cur, gLoC, agg0, wtAll + (size_t)((l*4 + 1)*4)*FF, gA_bf, gALo,
            q_cur, agg1, wtAll + (size_t)((l*4 + 2)*4)*FF, q_nxt, qF);
        // clip_1 + gloss_2 in one launch
        fusion3b_k<<<8*(NC/64)*NB + 8*(NG/64)*NB, 256, 0, stream>>>(
            c_cur, cLoC, agg_bf, aggLo,
            wtAll + (size_t)((l*4 + 0)*4)*FF, wtAllLo + (size_t)((l*4 + 0)*4)*FF,
            c_nxt, cLoN, cF,
            gA_bf, gALo, agg2,
            wtAll + (size_t)((l*4 + 3)*4)*FF, wtAllLo + (size_t)((l*4 + 3)*4)*FF,
            g_nxt, gLoN, (l == 0) ? gT : nullptr, (l == 0) ? gTlo : nullptr, gF);
    }
}

// Round 9
// 624.978 us; speedup vs baseline: 1.4497x; 1.0222x over previous
//
#include <hip/hip_runtime.h>
#include <math.h>

#define NFEAT 512
#define NHEADS 8
#define HDIM 64
#define NB 4
#define NG 1024
#define NC 1024
#define NQ 256
#define NEGV -9e15f
#define CHUNKS 16
#define FF ((size_t)NFEAT*NFEAT)
#define LSTR 36   // LDS row stride (ushorts) for reg-written P tiles only
#define SEG 2304  // segmented attn rows per batch

typedef _Float16 v8h __attribute__((ext_vector_type(8)));
typedef float v4f __attribute__((ext_vector_type(4)));
#define MFMA16(a,b,c) __builtin_amdgcn_mfma_f32_16x16x32_f16((a),(b),(c),0,0,0)

// async global->LDS, 16B/lane, lane-linear LDS dest (wave-uniform base + lane*16)
#define GLDS(g, l) __builtin_amdgcn_global_load_lds( \
    (__attribute__((address_space(1))) void*)(g), \
    (__attribute__((address_space(3))) void*)(l), 16, 0, 0)

// XOR swizzle for 64B-row linear LDS tiles: physical 16B slot = quad ^ ((row>>1)&3).
__device__ __forceinline__ int ldsw(int row, int quad){
    return row*32 + (((quad) ^ ((row>>1)&3)) << 3);
}

__device__ __forceinline__ float lrelu(float x){ return fmaxf(x, 0.2f*x); }
__device__ __forceinline__ unsigned short f2h(float x){ union{_Float16 h; unsigned short u;} v; v.h = (_Float16)x; return v.u; }
__device__ __forceinline__ float h2f(unsigned short u){ union{_Float16 h; unsigned short u;} v; v.u = u; return (float)v.h; }

// ============ prep: fp32 -> fp16 flat ============
__global__ __launch_bounds__(256) void cvt_h_k(const float* __restrict__ src, unsigned short* __restrict__ dst){
    int idx = blockIdx.x*256 + threadIdx.x;
    const float4* s = (const float4*)(src + (size_t)idx*8);
    float4 a = s[0], b = s[1];
    ushort4 p0{f2h(a.x),f2h(a.y),f2h(a.z),f2h(a.w)};
    ushort4 p1{f2h(b.x),f2h(b.y),f2h(b.z),f2h(b.w)};
    *(ushort4*)(dst + (size_t)idx*8) = p0;
    *(ushort4*)(dst + (size_t)idx*8 + 4) = p1;
}

// ============ prep: fp32 -> fp16 hi/lo flat ============
__global__ __launch_bounds__(256) void cvt_hl_k(const float* __restrict__ src,
    unsigned short* __restrict__ dstHi, unsigned short* __restrict__ dstLo){
    int idx = blockIdx.x*256 + threadIdx.x;
    const float4* s = (const float4*)(src + (size_t)idx*8);
    float4 a = s[0], b = s[1];
    float x[8] = {a.x,a.y,a.z,a.w,b.x,b.y,b.z,b.w};
    unsigned short hi[8], lo[8];
    #pragma unroll
    for (int j = 0; j < 8; ++j){ hi[j] = f2h(x[j]); lo[j] = f2h(x[j] - h2f(hi[j])); }
    *(ushort4*)(dstHi + (size_t)idx*8)     = ushort4{hi[0],hi[1],hi[2],hi[3]};
    *(ushort4*)(dstHi + (size_t)idx*8 + 4) = ushort4{hi[4],hi[5],hi[6],hi[7]};
    *(ushort4*)(dstLo + (size_t)idx*8)     = ushort4{lo[0],lo[1],lo[2],lo[3]};
    *(ushort4*)(dstLo + (size_t)idx*8 + 4) = ushort4{lo[4],lo[5],lo[6],lo[7]};
}

// ============ prep: fusion weights -> PACKED transposed fp16 hi/lo ============
// packed layout per group li: [c0i(8)][ktI(16)][mat(4)][row64][k32]
__global__ __launch_bounds__(256) void wtT_k(const float* __restrict__ w0, const float* __restrict__ w1,
    const float* __restrict__ w2, const float* __restrict__ w3,
    unsigned short* __restrict__ dstHi, unsigned short* __restrict__ dstLo){
    int bx = blockIdx.x;
    int mat = bx >> 6, t = bx & 63;
    int a = mat & 3, li = mat >> 2;
    const float* src = (a==0?w0:a==1?w1:a==2?w2:w3) + (size_t)li*FF;
    int fo0 = (t>>3)*64, fi0 = (t&7)*64;
    __shared__ float sT[64][65];
    int tid = threadIdx.x;
    #pragma unroll
    for (int it = 0; it < 4; ++it){
        int idx = it*256 + tid;
        int r = idx >> 4, c4 = idx & 15;
        float4 v = *(const float4*)(src + (size_t)(fi0+r)*512 + fo0 + c4*4);
        sT[r][c4*4+0]=v.x; sT[r][c4*4+1]=v.y; sT[r][c4*4+2]=v.z; sT[r][c4*4+3]=v.w;
    }
    __syncthreads();
    #pragma unroll
    for (int it = 0; it < 2; ++it){
        int idx = it*256 + tid;
        int dd = idx >> 3, c8 = idx & 7;
        unsigned short hi[8], lo[8];
        #pragma unroll
        for (int j = 0; j < 8; ++j){
            float x = sT[c8*8+j][dd];
            hi[j] = f2h(x);
            lo[j] = f2h(x - h2f(hi[j]));
        }
        int ktI = (fi0 >> 5) + (c8 >> 2);
        int k31 = (c8 & 3)*8;
        size_t oo = (size_t)li*4*FF + ((((size_t)(fo0>>6)*16 + ktI)*4 + a)*64 + dd)*32 + k31;
        *(ushort4*)(dstHi+oo)   = ushort4{hi[0],hi[1],hi[2],hi[3]};
        *(ushort4*)(dstHi+oo+4) = ushort4{hi[4],hi[5],hi[6],hi[7]};
        *(ushort4*)(dstLo+oo)   = ushort4{lo[0],lo[1],lo[2],lo[3]};
        *(ushort4*)(dstLo+oo+4) = ushort4{lo[4],lo[5],lo[6],lo[7]};
    }
}

// ============ prep: 3 attn W repacks (blocks 0..191) + wa vectors (blocks 192..239) ============
__global__ __launch_bounds__(256) void prep_attnW3_k(
    const float* __restrict__ W0, const float* __restrict__ a10, const float* __restrict__ a20,
    const float* __restrict__ W1, const float* __restrict__ a11, const float* __restrict__ a21,
    const float* __restrict__ W2, const float* __restrict__ a12, const float* __restrict__ a22,
    unsigned short* __restrict__ WT3, float* __restrict__ wa13, float* __restrict__ wa23){
    int bx = blockIdx.x;
    int tid = threadIdx.x;
    if (bx >= 192){
        int r = bx - 192;
        int a = r >> 4;
        const float* W  = (a==0?W0:a==1?W1:W2);
        const float* a1 = (a==0?a10:a==1?a11:a12);
        const float* a2 = (a==0?a20:a==1?a21:a22);
        int idx = (r & 15)*256 + tid;
        int h = idx >> 9;
        const float* Wp = W + (size_t)idx*64;
        float s1 = 0.f, s2 = 0.f;
        #pragma unroll
        for (int d = 0; d < 64; ++d){ float w = Wp[d]; s1 += w*a1[(h<<6)+d]; s2 += w*a2[(h<<6)+d]; }
        wa13[a*4096 + idx] = s1; wa23[a*4096 + idx] = s2;
        return;
    }
    int a = bx >> 6, bxl = bx & 63;
    const float* W = (a==0?W0:a==1?W1:W2);
    unsigned short* WT = WT3 + (size_t)a*FF;
    int h = bxl >> 3, f0 = (bxl & 7)*64;
    __shared__ float sT[64][65];
    #pragma unroll
    for (int it = 0; it < 4; ++it){
        int idx = it*256 + tid;
        int r = idx >> 4, c4 = idx & 15;
        float4 v = *(const float4*)(W + ((size_t)h*512 + f0 + r)*64 + c4*4);
        sT[r][c4*4+0]=v.x; sT[r][c4*4+1]=v.y; sT[r][c4*4+2]=v.z; sT[r][c4*4+3]=v.w;
    }
    __syncthreads();
    #pragma unroll
    for (int it = 0; it < 2; ++it){
        int idx = it*256 + tid;
        int dd = idx >> 3, c8 = idx & 7;
        ushort4 p0{f2h(sT[c8*8+0][dd]),f2h(sT[c8*8+1][dd]),f2h(sT[c8*8+2][dd]),f2h(sT[c8*8+3][dd])};
        ushort4 p1{f2h(sT[c8*8+4][dd]),f2h(sT[c8*8+5][dd]),f2h(sT[c8*8+6][dd]),f2h(sT[c8*8+7][dd])};
        unsigned short* o = WT + ((size_t)h*64 + dd)*512 + f0 + c8*8;
        *(ushort4*)o = p0; *(ushort4*)(o+4) = p1;
    }
}

// ============ prep: adj_gc int -> adjT fp16 [b][c][g] + bitmasks both orientations ============
__global__ __launch_bounds__(256) void adjT_h_k(const int* __restrict__ adj, unsigned short* __restrict__ dst,
    unsigned long long* __restrict__ bm_gc, unsigned long long* __restrict__ bm_cg){
    int b = blockIdx.z;
    int c0 = blockIdx.x*64, g0 = blockIdx.y*64;
    __shared__ int sI[64][65];
    int tid = threadIdx.x;
    #pragma unroll
    for (int it = 0; it < 4; ++it){
        int idx = it*256 + tid;
        int r = idx >> 4, c4 = idx & 15;
        int4 v = *(const int4*)(adj + ((size_t)b*NG + g0 + r)*NC + c0 + c4*4);
        sI[r][c4*4+0]=v.x; sI[r][c4*4+1]=v.y; sI[r][c4*4+2]=v.z; sI[r][c4*4+3]=v.w;
    }
    __syncthreads();
    int wv = tid >> 6, lane = tid & 63;
    #pragma unroll
    for (int it = 0; it < 2; ++it){
        int idx = it*256 + tid;
        int dd = idx >> 3, c8 = idx & 7;
        ushort4 p0, p1;
        #pragma unroll
        for (int j = 0; j < 4; ++j) (&p0.x)[j] = sI[c8*8+j][dd] > 0 ? (unsigned short)0x3C00 : (unsigned short)0;
        #pragma unroll
        for (int j = 0; j < 4; ++j) (&p1.x)[j] = sI[c8*8+4+j][dd] > 0 ? (unsigned short)0x3C00 : (unsigned short)0;
        unsigned short* o = dst + ((size_t)b*NC + c0 + dd)*NG + g0 + c8*8;
        *(ushort4*)o = p0; *(ushort4*)(o+4) = p1;
    }
    #pragma unroll
    for (int rr = wv; rr < 64; rr += 4){
        unsigned long long m = __ballot(sI[rr][lane] > 0);
        if (lane == 0) bm_gc[((size_t)b*NG + g0 + rr)*(NC/64) + (c0>>6)] = m;
    }
    #pragma unroll
    for (int cc = wv; cc < 64; cc += 4){
        unsigned long long m = __ballot(sI[lane][cc] > 0);
        if (lane == 0) bm_cg[((size_t)b*NC + c0 + cc)*(NG/64) + (g0>>6)] = m;
    }
}

// ============ prep: adj_gq int -> adjT int [b][q][g] + bitmasks both orientations ============
__global__ __launch_bounds__(256) void adjT_int_k(const int* __restrict__ adj, int* __restrict__ dst,
    unsigned long long* __restrict__ bm_gq, unsigned long long* __restrict__ bm_qg){
    int b = blockIdx.z;
    int q0 = blockIdx.x*64, g0 = blockIdx.y*64;
    __shared__ int sI[64][65];
    int tid = threadIdx.x;
    #pragma unroll
    for (int it = 0; it < 4; ++it){
        int idx = it*256 + tid;
        int r = idx >> 4, c4 = idx & 15;
        int4 v = *(const int4*)(adj + ((size_t)b*NG + g0 + r)*NQ + q0 + c4*4);
        sI[r][c4*4+0]=v.x; sI[r][c4*4+1]=v.y; sI[r][c4*4+2]=v.z; sI[r][c4*4+3]=v.w;
    }
    __syncthreads();
    int wv = tid >> 6, lane = tid & 63;
    #pragma unroll
    for (int it = 0; it < 4; ++it){
        int idx = it*256 + tid;
        int dd = idx >> 4, c4 = idx & 15;
        int4 v{sI[c4*4+0][dd], sI[c4*4+1][dd], sI[c4*4+2][dd], sI[c4*4+3][dd]};
        *(int4*)(dst + ((size_t)b*NQ + q0 + dd)*NG + g0 + c4*4) = v;
    }
    #pragma unroll
    for (int rr = wv; rr < 64; rr += 4){
        unsigned long long m = __ballot(sI[rr][lane] > 0);
        if (lane == 0) bm_gq[((size_t)b*NG + g0 + rr)*(NQ/64) + (q0>>6)] = m;
    }
    #pragma unroll
    for (int cc = wv; cc < 64; cc += 4){
        unsigned long long m = __ballot(sI[lane][cc] > 0);
        if (lane == 0) bm_qg[((size_t)b*NQ + q0 + cc)*(NG/64) + (g0>>6)] = m;
    }
}

// ============ prep: gloss fp32 -> transposed hi/lo [b][512][N] AND row-major hi/lo ============
__global__ __launch_bounds__(256) void actT_hl_k(const float* __restrict__ src,
    unsigned short* __restrict__ dstHi, unsigned short* __restrict__ dstLo,
    unsigned short* __restrict__ rmHi, unsigned short* __restrict__ rmLo, int Nrows){
    int b = blockIdx.z;
    int f0 = blockIdx.x*64, g0 = blockIdx.y*64;
    __shared__ float sF[64][65];
    int tid = threadIdx.x;
    #pragma unroll
    for (int it = 0; it < 4; ++it){
        int idx = it*256 + tid;
        int r = idx >> 4, c4 = idx & 15;
        float4 v = *(const float4*)(src + ((size_t)b*Nrows + g0 + r)*512 + f0 + c4*4);
        sF[r][c4*4+0]=v.x; sF[r][c4*4+1]=v.y; sF[r][c4*4+2]=v.z; sF[r][c4*4+3]=v.w;
    }
    __syncthreads();
    #pragma unroll
    for (int it = 0; it < 2; ++it){
        int idx = it*256 + tid;
        int dd = idx >> 3, c8 = idx & 7;
        unsigned short hi[8], lo[8];
        #pragma unroll
        for (int j = 0; j < 8; ++j){
            float x = sF[c8*8+j][dd];
            hi[j] = f2h(x);
            lo[j] = f2h(x - h2f(hi[j]));
        }
        size_t oo = ((size_t)b*512 + f0 + dd)*Nrows + g0 + c8*8;
        *(ushort4*)(dstHi+oo)   = ushort4{hi[0],hi[1],hi[2],hi[3]};
        *(ushort4*)(dstHi+oo+4) = ushort4{hi[4],hi[5],hi[6],hi[7]};
        *(ushort4*)(dstLo+oo)   = ushort4{lo[0],lo[1],lo[2],lo[3]};
        *(ushort4*)(dstLo+oo+4) = ushort4{lo[4],lo[5],lo[6],lo[7]};
    }
    #pragma unroll
    for (int it = 0; it < 2; ++it){
        int idx = it*256 + tid;
        int r = idx >> 3, c8 = idx & 7;
        unsigned short hi[8], lo[8];
        #pragma unroll
        for (int j = 0; j < 8; ++j){
            float x = sF[r][c8*8+j];
            hi[j] = f2h(x);
            lo[j] = f2h(x - h2f(hi[j]));
        }
        size_t oo = ((size_t)b*Nrows + g0 + r)*512 + f0 + c8*8;
        *(ushort4*)(rmHi+oo)   = ushort4{hi[0],hi[1],hi[2],hi[3]};
        *(ushort4*)(rmHi+oo+4) = ushort4{hi[4],hi[5],hi[6],hi[7]};
        *(ushort4*)(rmLo+oo)   = ushort4{lo[0],lo[1],lo[2],lo[3]};
        *(ushort4*)(rmLo+oo+4) = ushort4{lo[4],lo[5],lo[6],lo[7]};
    }
}

// ============ batched scores: all 3 attns' q and k scores in one launch ============
__global__ __launch_bounds__(256) void scores3_k(
    const unsigned short* __restrict__ g, const unsigned short* __restrict__ c,
    const unsigned short* __restrict__ q,
    const float* __restrict__ wa13, const float* __restrict__ wa23,
    float* __restrict__ qs3, float* __restrict__ ks3){
    int lane = threadIdx.x & 63;
    int grow = blockIdx.x*4 + (threadIdx.x >> 6);
    int b = grow / 4608; int r = grow - b*4608;
    const unsigned short* X; const float* wa; float* out; int n, oOff, rowsX;
    if (r < SEG){
        out = qs3;
        if (r < 1024)      { X=g; wa=wa13;        n=r;        oOff=0;    rowsX=NG; }
        else if (r < 1280) { X=q; wa=wa13+4096;   n=r-1024;   oOff=1024; rowsX=NQ; }
        else               { X=g; wa=wa13+8192;   n=r-1280;   oOff=1280; rowsX=NG; }
    } else {
        out = ks3; r -= SEG;
        if (r < 1024)      { X=c; wa=wa23;        n=r;        oOff=0;    rowsX=NC; }
        else if (r < 2048) { X=g; wa=wa23+4096;   n=r-1024;   oOff=1024; rowsX=NG; }
        else               { X=q; wa=wa23+8192;   n=r-2048;   oOff=2048; rowsX=NQ; }
    }
    const unsigned short* Xr = X + ((size_t)b*rowsX + n)*NFEAT;
    float p[NHEADS];
    #pragma unroll
    for (int h = 0; h < NHEADS; ++h) p[h] = 0.f;
    #pragma unroll
    for (int cc = 0; cc < 8; ++cc){
        float x = h2f(Xr[(cc<<6) + lane]);
        #pragma unroll
        for (int h = 0; h < NHEADS; ++h) p[h] += x * wa[(h<<9) + (cc<<6) + lane];
    }
    #pragma unroll
    for (int h = 0; h < NHEADS; ++h){
        float v = p[h];
        #pragma unroll
        for (int off = 32; off > 0; off >>= 1) v += __shfl_xor(v, off);
        if (lane == 0) out[((size_t)b*SEG + oOff + n)*8 + h] = v;
    }
}

// ============ batched WkT gemm: WkT3[b][512][2304] = {clip,gloss,question} @ WT3[a]^T ============
__global__ __launch_bounds__(256) void wkt3_mfma_k(
    const unsigned short* __restrict__ c, const unsigned short* __restrict__ g,
    const unsigned short* __restrict__ q, const unsigned short* __restrict__ WT3,
    unsigned short* __restrict__ WkT3){
    int b = blockIdx.z;
    int y = blockIdx.y;
    const unsigned short* kv; int rowsX, mOff, a;
    if (y < 16)      { a=0; kv=c; rowsX=NC; mOff=0; }
    else if (y < 32) { a=1; y-=16; kv=g; rowsX=NG; mOff=1024; }
    else             { a=2; y-=32; kv=q; rowsX=NQ; mOff=2048; }
    int r0 = y*64, c0 = blockIdx.x*64;
    int tid = threadIdx.x;
    __shared__ alignas(16) unsigned short aS[2][2048], bS[2][2048];
    const unsigned short* aG = kv + (size_t)b*rowsX*512;
    const unsigned short* bG = WT3 + (size_t)a*FF;
    int w = tid >> 6, lane = tid & 63;
    int lrow = lane & 15, quad = lane >> 4;
    int sr = tid >> 2;
    int sq = (tid & 3) ^ ((sr >> 1) & 3);
    size_t aRow = (size_t)(r0 + sr)*512 + sq*8;
    size_t bRow = (size_t)(c0 + sr)*512 + sq*8;
    v4f acc[4];
    #pragma unroll
    for (int cf = 0; cf < 4; ++cf) acc[cf] = (v4f)0.f;
    GLDS(aG + aRow, &aS[0][w << 9]);
    GLDS(bG + bRow, &bS[0][w << 9]);
    __syncthreads();
    int buf = 0;
    for (int s = 0; s < 16; ++s){
        if (s < 15){
            int ktn = (s + 1) << 5;
            GLDS(aG + aRow + ktn, &aS[buf^1][w << 9]);
            GLDS(bG + bRow + ktn, &bS[buf^1][w << 9]);
        }
        v8h af = *(const v8h*)&aS[buf][ldsw(w*16 + lrow, quad)];
        #pragma unroll
        for (int cf = 0; cf < 4; ++cf){
            v8h bf = *(const v8h*)&bS[buf][ldsw(cf*16 + lrow, quad)];
            acc[cf] = MFMA16(af, bf, acc[cf]);
        }
        __syncthreads();
        buf ^= 1;
    }
    #pragma unroll
    for (int cf = 0; cf < 4; ++cf){
        int colg = c0 + cf*16 + lrow;
        int rbase = r0 + w*16 + quad*4;
        ushort4 pk{f2h(acc[cf][0]), f2h(acc[cf][1]), f2h(acc[cf][2]), f2h(acc[cf][3])};
        *(ushort4*)&WkT3[((size_t)b*512 + colg)*SEG + mOff + rbase] = pk;
    }
}

// ============ batched colstat: all 3 attns, per-chunk (cm, sum) via bitmasks ============
__global__ __launch_bounds__(256) void colstat3_k(
    const unsigned* __restrict__ bm_cg, const unsigned* __restrict__ bm_gq,
    const unsigned* __restrict__ bm_qg,
    const float* __restrict__ qs3, const float* __restrict__ ks3,
    float* __restrict__ pcm, float* __restrict__ psum){
    int x = blockIdx.x, b = blockIdx.z;
    const unsigned* bm; int Mrows, N, N32, mOff, qOff;
    if (x < 256)      { bm=bm_cg; Mrows=NC; N=NG; N32=NG/32; mOff=0;    qOff=0; }
    else if (x < 512) { x-=256; bm=bm_gq; Mrows=NG; N=NQ; N32=NQ/32; mOff=1024; qOff=1024; }
    else              { x-=512; bm=bm_qg; Mrows=NQ; N=NG; N32=NG/32; mOff=2048; qOff=1280; }
    int mt = x >> 4, ch = x & 15;
    int chunk = N / CHUNKS, subl = chunk >> 2;
    int ml = threadIdx.x & 63; int m = mt*64 + ml;
    int g = threadIdx.x >> 6;
    int n0 = ch*chunk + g*subl;
    __shared__ float sQ[64][8];
    for (int t2 = threadIdx.x; t2 < chunk*8; t2 += 256)
        sQ[t2>>3][t2&7] = qs3[((size_t)b*SEG + qOff + ch*chunk)*8 + t2];
    float ksv[8];
    size_t mo = ((size_t)b*SEG + mOff + m)*8;
    #pragma unroll
    for (int h = 0; h < 8; ++h) ksv[h] = ks3[mo+h];
    unsigned word = bm[((size_t)b*Mrows + m)*N32 + (n0>>5)];
    unsigned bits = (word >> (n0 & 31)) & ((1u << subl) - 1u);
    __syncthreads();
    int nb = g*subl;
    float mx[8];
    #pragma unroll
    for (int h = 0; h < 8; ++h) mx[h] = -INFINITY;
    for (int i = 0; i < subl; ++i){
        if ((bits >> i) & 1){
            #pragma unroll
            for (int h = 0; h < 8; ++h) mx[h] = fmaxf(mx[h], sQ[nb+i][h]);
        }
    }
    float cm[8], s[8];
    #pragma unroll
    for (int h = 0; h < 8; ++h){
        cm[h] = bits ? lrelu(mx[h] + ksv[h]) : NEGV;
        s[h] = 0.f;
    }
    for (int i = 0; i < subl; ++i){
        bool on = (bits >> i) & 1;
        #pragma unroll
        for (int h = 0; h < 8; ++h){
            float e = on ? lrelu(sQ[nb+i][h] + ksv[h]) : NEGV;
            s[h] += __expf(e - cm[h]);
        }
    }
    __shared__ float scm[4][64][8], ssm[4][64][8];
    #pragma unroll
    for (int h = 0; h < 8; ++h){ scm[g][ml][h] = cm[h]; ssm[g][ml][h] = s[h]; }
    __syncthreads();
    if (g == 0){
        #pragma unroll
        for (int h = 0; h < 8; ++h){
            float c0 = scm[0][ml][h], c1 = scm[1][ml][h], c2 = scm[2][ml][h], c3 = scm[3][ml][h];
            float CM = fmaxf(fmaxf(c0, c1), fmaxf(c2, c3));
            float S = ssm[0][ml][h]*__expf(c0-CM) + ssm[1][ml][h]*__expf(c1-CM)
                    + ssm[2][ml][h]*__expf(c2-CM) + ssm[3][ml][h]*__expf(c3-CM);
            size_t o = (((size_t)b*CHUNKS + ch)*SEG + mOff + m)*8 + h;
            pcm[o] = CM; psum[o] = S;
        }
    }
}

// ============ batched finalize: chunk-combine + repack -> ksh/cmh/ish [b][8][SEG] ============
__global__ __launch_bounds__(256) void colfin3_k(const float* __restrict__ pcm, const float* __restrict__ psum,
    const float* __restrict__ ks3, float* __restrict__ ksh, float* __restrict__ cmh,
    float* __restrict__ ish){
    int idx = blockIdx.x*256 + threadIdx.x;    // NB*SEG*8
    const int m8 = SEG*8;
    int b = idx / m8, rem = idx - b*m8;
    int m = rem >> 3, h = rem & 7;
    size_t base = (size_t)b*CHUNKS*m8 + rem;
    float c[CHUNKS], s[CHUNKS];
    #pragma unroll
    for (int ch = 0; ch < CHUNKS; ++ch){
        c[ch] = pcm[base + (size_t)ch*m8];
        s[ch] = psum[base + (size_t)ch*m8];
    }
    float CM = c[0];
    #pragma unroll
    for (int ch = 1; ch < CHUNKS; ++ch) CM = fmaxf(CM, c[ch]);
    float S = 0.f;
    #pragma unroll
    for (int ch = 0; ch < CHUNKS; ++ch) S += s[ch]*__expf(c[ch] - CM);
    size_t o = ((size_t)b*8 + h)*SEG + m;
    ksh[o] = ks3[idx]; cmh[o] = CM; ish[o] = 1.f/S;
}

// ============ 3-pass fusion body: 128-row tile, shared weight staging ============
__device__ __forceinline__ void fusion3_body(int F,
    unsigned short* aHs, unsigned short* bHs, unsigned short* aLs, unsigned short* bLs,
    unsigned short* wHs, unsigned short* wLs,
    const unsigned short* aHi, const unsigned short* aLo,
    const unsigned short* bHi, const unsigned short* bLo,
    const unsigned short* Whi, const unsigned short* Wlo,
    unsigned short* dst, unsigned short* dstLo,
    unsigned short* dstT, unsigned short* dstTLo,
    float* dstF, int rows){
    int nY = rows >> 7;                  // 128-row tiles
    int ppg = (nY * NB) >> 3;
    int xcd = F & 7, t = F >> 3;
    int c0i = t / ppg;
    int p = xcd + ((t - c0i*ppg) << 3);
    int r0 = (p % nY) << 7, c0 = c0i << 6;
    int b = p / nY;
    int tid = threadIdx.x;
    size_t actOff = (size_t)b*rows*512;
    const unsigned short* aHG = aHi + actOff;
    const unsigned short* bHG = bHi + actOff;
    const unsigned short* aLG = aLo ? aLo + actOff : nullptr;
    const unsigned short* bLG = bLo ? bLo + actOff : nullptr;
    bool hasALo = (aLG != nullptr);
    bool hasBLo = (bLG != nullptr);
    int w = tid >> 6, lane = tid & 63;
    int wr = w >> 1, wc = w & 1;
    int lrow = lane & 15, quad = lane >> 4;
    int sr = tid >> 2;
    int sq = (tid & 3) ^ ((sr >> 1) & 3);
    size_t aRow0 = (size_t)(r0 + sr)*512 + sq*8;
    size_t aRow1 = (size_t)(r0 + 64 + sr)*512 + sq*8;
    size_t wPk = (size_t)c0i*16*8192 + (size_t)sr*32 + sq*8;
    int d0 = w << 9, d1 = 2048 + (w << 9);
    v4f accN[2][2][2], accF[2][2][2];     // [rt][r][cf]
    #pragma unroll
    for (int rt = 0; rt < 2; ++rt)
        #pragma unroll
        for (int r = 0; r < 2; ++r)
            #pragma unroll
            for (int cf = 0; cf < 2; ++cf){ accN[rt][r][cf] = (v4f)0.f; accF[rt][r][cf] = (v4f)0.f; }
    for (int kt = 0; kt < 512; kt += 32){
        __syncthreads();
        GLDS(aHG + aRow0 + kt, &aHs[d0]);
        GLDS(aHG + aRow1 + kt, &aHs[d1]);
        GLDS(bHG + aRow0 + kt, &bHs[d0]);
        GLDS(bHG + aRow1 + kt, &bHs[d1]);
        if (hasALo){ GLDS(aLG + aRow0 + kt, &aLs[d0]); GLDS(aLG + aRow1 + kt, &aLs[d1]); }
        if (hasBLo){ GLDS(bLG + aRow0 + kt, &bLs[d0]); GLDS(bLG + aRow1 + kt, &bLs[d1]); }
        size_t wk = wPk + (size_t)(kt >> 5)*8192;
        #pragma unroll
        for (int m = 0; m < 4; ++m){
            GLDS(Whi + wk + (m<<11), &wHs[(m<<11) + d0]);
            GLDS(Wlo + wk + (m<<11), &wLs[(m<<11) + d0]);
        }
        __syncthreads();
        #pragma unroll
        for (int rt = 0; rt < 2; ++rt){
            v8h ah[2], bh[2], al[2], bl[2];
            #pragma unroll
            for (int r = 0; r < 2; ++r){
                int ao = ldsw(rt*64 + wr*32 + r*16 + lrow, quad);
                ah[r] = *(const v8h*)&aHs[ao];
                bh[r] = *(const v8h*)&bHs[ao];
                if (hasALo) al[r] = *(const v8h*)&aLs[ao];
                if (hasBLo) bl[r] = *(const v8h*)&bLs[ao];
            }
            #pragma unroll
            for (int cf = 0; cf < 2; ++cf){
                int wo = ldsw(wc*32 + cf*16 + lrow, quad);
                v8h w0 = *(const v8h*)&wHs[wo];
                v8h w1 = *(const v8h*)&wHs[2048 + wo];
                v8h w2 = *(const v8h*)&wHs[4096 + wo];
                v8h w3 = *(const v8h*)&wHs[6144 + wo];
                v8h l0 = *(const v8h*)&wLs[wo];
                v8h l1 = *(const v8h*)&wLs[2048 + wo];
                v8h l2 = *(const v8h*)&wLs[4096 + wo];
                v8h l3 = *(const v8h*)&wLs[6144 + wo];
                #pragma unroll
                for (int r = 0; r < 2; ++r){
                    accN[rt][r][cf] = MFMA16(ah[r], w0, accN[rt][r][cf]);
                    accN[rt][r][cf] = MFMA16(bh[r], w1, accN[rt][r][cf]);
                    accF[rt][r][cf] = MFMA16(ah[r], w2, accF[rt][r][cf]);
                    accF[rt][r][cf] = MFMA16(bh[r], w3, accF[rt][r][cf]);
                    if (hasALo){ accN[rt][r][cf] = MFMA16(al[r], w0, accN[rt][r][cf]); accF[rt][r][cf] = MFMA16(al[r], w2, accF[rt][r][cf]); }
                    if (hasBLo){ accN[rt][r][cf] = MFMA16(bl[r], w1, accN[rt][r][cf]); accF[rt][r][cf] = MFMA16(bl[r], w3, accF[rt][r][cf]); }
                    accN[rt][r][cf] = MFMA16(ah[r], l0, accN[rt][r][cf]);
                    accN[rt][r][cf] = MFMA16(bh[r], l1, accN[rt][r][cf]);
                    accF[rt][r][cf] = MFMA16(ah[r], l2, accF[rt][r][cf]);
                    accF[rt][r][cf] = MFMA16(bh[r], l3, accF[rt][r][cf]);
                }
            }
        }
    }
    #pragma unroll
    for (int rt = 0; rt < 2; ++rt)
        #pragma unroll
        for (int r = 0; r < 2; ++r)
            #pragma unroll
            for (int cf = 0; cf < 2; ++cf){
                int colg = c0 + wc*32 + cf*16 + lrow;
                int rbase = r0 + rt*64 + wr*32 + r*16 + quad*4;
                float o4[4];
                #pragma unroll
                for (int reg = 0; reg < 4; ++reg){
                    float f = 1.f/(1.f + __expf(-accF[rt][r][cf][reg]));
                    size_t ai = (size_t)(rbase+reg)*512 + colg;
                    float ao = h2f(aHG[ai]);
                    if (aLG) ao += h2f(aLG[ai]);
                    o4[reg] = f*accN[rt][r][cf][reg] + (1.f - f)*ao;
                    size_t oo = ((size_t)b*rows + rbase + reg)*512 + colg;
                    unsigned short hv = f2h(o4[reg]);
                    dst[oo] = hv;
                    if (dstLo) dstLo[oo] = f2h(o4[reg] - h2f(hv));
                    if (dstF) dstF[oo] = o4[reg];
                }
                if (dstT){
                    unsigned short h0 = f2h(o4[0]), h1 = f2h(o4[1]), h2 = f2h(o4[2]), h3 = f2h(o4[3]);
                    size_t to = ((size_t)b*512 + colg)*rows + rbase;
                    *(ushort4*)&dstT[to] = ushort4{h0,h1,h2,h3};
                    if (dstTLo)
                        *(ushort4*)&dstTLo[to] = ushort4{f2h(o4[0]-h2f(h0)), f2h(o4[1]-h2f(h1)),
                                                         f2h(o4[2]-h2f(h2)), f2h(o4[3]-h2f(h3))};
                }
            }
}

// ============ batched 3-pass fusion (128-row tiles): seg0 clip_1 (NC), seg1 gloss_2 (NG) ============
__global__ __launch_bounds__(256) void fusion3b_k(
    const unsigned short* __restrict__ a0, const unsigned short* __restrict__ a0Lo,
    const unsigned short* __restrict__ b0, const unsigned short* __restrict__ b0Lo,
    const unsigned short* __restrict__ W0hi, const unsigned short* __restrict__ W0lo,
    unsigned short* __restrict__ d0, unsigned short* __restrict__ d0Lo, float* __restrict__ d0F,
    const unsigned short* __restrict__ a1, const unsigned short* __restrict__ a1Lo,
    const unsigned short* __restrict__ b1,
    const unsigned short* __restrict__ W1hi, const unsigned short* __restrict__ W1lo,
    unsigned short* __restrict__ d1, unsigned short* __restrict__ d1Lo,
    unsigned short* __restrict__ d1T, unsigned short* __restrict__ d1TLo, float* __restrict__ d1F){
    __shared__ alignas(16) unsigned short aHs[4096], bHs[4096], aLs[4096], bLs[4096];
    __shared__ alignas(16) unsigned short wHs[8192], wLs[8192];
    int F = blockIdx.x;
    const int S0 = 8*(NC/128)*NB;
    if (F < S0)
        fusion3_body(F, aHs, bHs, aLs, bLs, wHs, wLs,
                     a0, a0Lo, b0, b0Lo, W0hi, W0lo,
                     d0, d0Lo, nullptr, nullptr, d0F, NC);
    else
        fusion3_body(F - S0, aHs, bHs, aLs, bLs, wHs, wLs,
                     a1, a1Lo, b1, nullptr, W1hi, W1lo,
                     d1, d1Lo, d1T, d1TLo, d1F, NG);
}

// ============ 1-pass fusion body (double-buffered; shared LDS passed in) ============
__device__ __forceinline__ void fusion1_body(int F,
    unsigned short (*aHs)[2048], unsigned short (*bHs)[2048], unsigned short (*wHs)[8192],
    const unsigned short* aHi, const unsigned short* aLo,
    const unsigned short* bHi, const unsigned short* Whi,
    unsigned short* dst, unsigned short* dstLo, float* dstF, int rows){
    int nY = rows >> 6;
    int ppg = (nY * NB) >> 3;
    int xcd = F & 7, t = F >> 3;
    int c0i = t / ppg;
    int p = xcd + ((t - c0i*ppg) << 3);
    int r0 = (p % nY) << 6, c0 = c0i << 6;
    int b = p / nY;
    int tid = threadIdx.x;
    size_t actOff = (size_t)b*rows*512;
    const unsigned short* aHG = aHi + actOff;
    const unsigned short* bHG = bHi + actOff;
    const unsigned short* aLG = aLo ? aLo + actOff : nullptr;
    int w = tid >> 6, lane = tid & 63;
    int wr = w >> 1, wc = w & 1;
    int lrow = lane & 15, quad = lane >> 4;
    int sr = tid >> 2;
    int sq = (tid & 3) ^ ((sr >> 1) & 3);
    size_t aRow = (size_t)(r0 + sr)*512 + sq*8;
    size_t wPk = (size_t)c0i*16*8192 + (size_t)sr*32 + sq*8;
    v4f accN[2][2], accF[2][2];
    #pragma unroll
    for (int r = 0; r < 2; ++r)
        #pragma unroll
        for (int cf = 0; cf < 2; ++cf){ accN[r][cf] = (v4f)0.f; accF[r][cf] = (v4f)0.f; }

    #define F1STAGE(bb, kk) do{ \
        GLDS(aHG + aRow + (kk), &aHs[bb][w << 9]); \
        GLDS(bHG + aRow + (kk), &bHs[bb][w << 9]); \
        size_t wk_ = wPk + (size_t)((kk) >> 5)*8192; \
        GLDS(Whi + wk_,          &wHs[bb][(0<<11) + (w<<9)]); \
        GLDS(Whi + wk_ + (1<<11), &wHs[bb][(1<<11) + (w<<9)]); \
        GLDS(Whi + wk_ + (2<<11), &wHs[bb][(2<<11) + (w<<9)]); \
        GLDS(Whi + wk_ + (3<<11), &wHs[bb][(3<<11) + (w<<9)]); \
    } while(0)

    F1STAGE(0, 0);
    __syncthreads();
    int buf = 0;
    for (int kt = 0; kt < 512; kt += 32){
        if (kt + 32 < 512) F1STAGE(buf^1, kt + 32);
        v8h ah[2], bh[2];
        #pragma unroll
        for (int r = 0; r < 2; ++r){
            int ao = ldsw(wr*32 + r*16 + lrow, quad);
            ah[r] = *(const v8h*)&aHs[buf][ao];
            bh[r] = *(const v8h*)&bHs[buf][ao];
        }
        #pragma unroll
        for (int cf = 0; cf < 2; ++cf){
            int wo = ldsw(wc*32 + cf*16 + lrow, quad);
            v8h w0 = *(const v8h*)&wHs[buf][wo];
            v8h w1 = *(const v8h*)&wHs[buf][2048 + wo];
            v8h w2 = *(const v8h*)&wHs[buf][4096 + wo];
            v8h w3 = *(const v8h*)&wHs[buf][6144 + wo];
            #pragma unroll
            for (int r = 0; r < 2; ++r){
                accN[r][cf] = MFMA16(ah[r], w0, accN[r][cf]);
                accN[r][cf] = MFMA16(bh[r], w1, accN[r][cf]);
                accF[r][cf] = MFMA16(ah[r], w2, accF[r][cf]);
                accF[r][cf] = MFMA16(bh[r], w3, accF[r][cf]);
            }
        }
        __syncthreads();
        buf ^= 1;
    }
    #undef F1STAGE
    #pragma unroll
    for (int r = 0; r < 2; ++r)
        #pragma unroll
        for (int cf = 0; cf < 2; ++cf){
            int colg = c0 + wc*32 + cf*16 + lrow;
            int rbase = r0 + wr*32 + r*16 + quad*4;
            #pragma unroll
            for (int reg = 0; reg < 4; ++reg){
                float f = 1.f/(1.f + __expf(-accF[r][cf][reg]));
                size_t ai = (size_t)(rbase+reg)*512 + colg;
                float ao = h2f(aHG[ai]);
                if (aLG) ao += h2f(aLG[ai]);
                float o = f*accN[r][cf][reg] + (1.f - f)*ao;
                size_t oo = ((size_t)b*rows + rbase + reg)*512 + colg;
                unsigned short hv = f2h(o);
                dst[oo] = hv;
                if (dstLo) dstLo[oo] = f2h(o - h2f(hv));
                if (dstF) dstF[oo] = o;
            }
        }
}

// ============ batched 1-pass fusion: seg0 gloss_1 (NG), seg1 question_1 (NQ) ============
__global__ __launch_bounds__(256) void fusion1b_k(
    const unsigned short* __restrict__ a0, const unsigned short* __restrict__ a0Lo,
    const unsigned short* __restrict__ b0, const unsigned short* __restrict__ W0,
    unsigned short* __restrict__ d0, unsigned short* __restrict__ d0Lo,
    const unsigned short* __restrict__ a1, const unsigned short* __restrict__ b1,
    const unsigned short* __restrict__ W1,
    unsigned short* __restrict__ d1, float* __restrict__ d1F){
    __shared__ alignas(16) unsigned short aHs[2][2048], bHs[2][2048];
    __shared__ alignas(16) unsigned short wHs[2][8192];
    int F = blockIdx.x;
    const int S0 = 8*(NG/64)*NB;
    if (F < S0)
        fusion1_body(F, aHs, bHs, wHs, a0, a0Lo, b0, W0, d0, d0Lo, nullptr, NG);
    else
        fusion1_body(F - S0, aHs, bHs, wHs, a1, nullptr, b1, W1, d1, nullptr, d1F, NQ);
}

// ============ generic MFMA GEMM (64-row tiles, double-buffered) — gloss_same only ============
__global__ __launch_bounds__(256) void gemmT_mfma_k(
    const unsigned short* __restrict__ A, size_t aStride,
    const unsigned short* __restrict__ BT, const unsigned short* __restrict__ BT2, size_t bStride,
    int K, int rowsPB,
    unsigned short* __restrict__ outRM, unsigned short* __restrict__ outLo,
    unsigned short* __restrict__ outT){
    int b = blockIdx.z;
    int r0 = blockIdx.y*64, c0 = blockIdx.x*64;
    int tid = threadIdx.x;
    __shared__ alignas(16) unsigned short aS[2][2048], bS[2][2048];
    const unsigned short* aG = A + (size_t)b*aStride;
    const unsigned short* bG0 = BT + (size_t)b*bStride;
    const unsigned short* bG1 = BT2 ? BT2 + (size_t)b*bStride : nullptr;
    int w = tid >> 6, lane = tid & 63;
    int lrow = lane & 15, quad = lane >> 4;
    int sr = tid >> 2;
    int sq = (tid & 3) ^ ((sr >> 1) & 3);
    size_t aRow = (size_t)(r0 + sr)*K + sq*8;
    size_t bRow = (size_t)(c0 + sr)*K + sq*8;
    int spp = K >> 5;
    int nsteps = (BT2 ? 2 : 1)*spp;
    v4f acc[4];
    #pragma unroll
    for (int cf = 0; cf < 4; ++cf) acc[cf] = (v4f)0.f;
    GLDS(aG + aRow, &aS[0][w << 9]);
    GLDS(bG0 + bRow, &bS[0][w << 9]);
    __syncthreads();
    int buf = 0;
    for (int s = 0; s < nsteps; ++s){
        int sn = s + 1;
        if (sn < nsteps){
            int ktn = ((sn >= spp) ? (sn - spp) : sn) << 5;
            const unsigned short* bgn = (sn >= spp) ? bG1 : bG0;
            GLDS(aG + aRow + ktn, &aS[buf^1][w << 9]);
            GLDS(bgn + bRow + ktn, &bS[buf^1][w << 9]);
        }
        v8h af = *(const v8h*)&aS[buf][ldsw(w*16 + lrow, quad)];
        #pragma unroll
        for (int cf = 0; cf < 4; ++cf){
            v8h bf = *(const v8h*)&bS[buf][ldsw(cf*16 + lrow, quad)];
            acc[cf] = MFMA16(af, bf, acc[cf]);
        }
        __syncthreads();
        buf ^= 1;
    }
    #pragma unroll
    for (int cf = 0; cf < 4; ++cf){
        int colg = c0 + cf*16 + lrow;
        int rbase = r0 + w*16 + quad*4;
        if (outRM){
            #pragma unroll
            for (int reg = 0; reg < 4; ++reg){
                float v = acc[cf][reg];
                unsigned short hv = f2h(v);
                size_t oo = ((size_t)b*rowsPB + rbase + reg)*512 + colg;
                outRM[oo] = hv;
                if (outLo) outLo[oo] = f2h(v - h2f(hv));
            }
        }
        if (outT){
            ushort4 pk{f2h(acc[cf][0]), f2h(acc[cf][1]), f2h(acc[cf][2]), f2h(acc[cf][3])};
            *(ushort4*)&outT[((size_t)b*512 + colg)*rowsPB + rbase] = pk;
        }
    }
}

// ============ attention output body (shared LDS passed in) ============
__device__ __forceinline__ void attn_body(int F,
    unsigned short* pS, unsigned short* wS, float* qsS, float* sKs, float* sCm, float* sIs,
    const unsigned* bmN, int M32,
    const float* qs3, int qOff,
    const float* ksh, const float* cmh, const float* ish,
    int mOff, const unsigned short* WkT3,
    unsigned short* outp, int N, int M){
    int nN0 = N >> 6;
    int xcd = F & 7, t = F >> 3;
    int bh = xcd*4 + t/nN0;
    int n0 = (t % nN0) << 6;
    int b = bh >> 3, h = bh & 7;
    int tid = threadIdx.x;
    const float* ksb = ksh + ((size_t)b*8 + h)*SEG + mOff;
    const float* cmb = cmh + ((size_t)b*8 + h)*SEG + mOff;
    const float* isb = ish + ((size_t)b*8 + h)*SEG + mOff;
    const unsigned short* wkb = WkT3 + ((size_t)b*512 + h*64)*SEG + mOff;
    int w = tid >> 6, lane = tid & 63;
    int lrow = lane & 15, quad = lane >> 4;
    int pn = tid >> 2, pm = (tid & 3)*8;
    int sr = tid >> 2;
    int sq = (tid & 3) ^ ((sr >> 1) & 3);
    for (int o = w*256; o < M; o += 1024){
        GLDS(ksb + o + lane*4, &sKs[o]);
        GLDS(cmb + o + lane*4, &sCm[o]);
        GLDS(isb + o + lane*4, &sIs[o]);
    }
    if (tid < 64) qsS[tid] = qs3[((size_t)b*SEG + qOff + n0 + tid)*8 + h];
    const unsigned* bmrow = bmN + ((size_t)b*N + n0 + pn)*M32;
    v4f acc[4];
    #pragma unroll
    for (int cf = 0; cf < 4; ++cf) acc[cf] = (v4f)0.f;
    uint2 CW = *(const uint2*)(bmrow);
    uint2 NW;
    __syncthreads();
    float qv = qsS[pn];
    for (int mt = 0; mt < M; mt += 64){
        int mtB = mt + 32;
        int mtN = (mt + 64 < M) ? (mt + 64) : 0;
        GLDS(wkb + (size_t)sr*SEG + mt + sq*8, &wS[w << 9]);
        {
            unsigned bb = (CW.x >> pm) & 0xffu;
            float4 k0 = *(const float4*)&sKs[mt+pm], k1 = *(const float4*)&sKs[mt+pm+4];
            float4 c0 = *(const float4*)&sCm[mt+pm], c1 = *(const float4*)&sCm[mt+pm+4];
            float4 i0 = *(const float4*)&sIs[mt+pm], i1 = *(const float4*)&sIs[mt+pm+4];
            float p[8];
            const float* kk0 = &k0.x; const float* kk1 = &k1.x;
            const float* cc0 = &c0.x; const float* cc1 = &c1.x;
            const float* ii0 = &i0.x; const float* ii1 = &i1.x;
            #pragma unroll
            for (int j = 0; j < 4; ++j){
                float e = ((bb >> j) & 1) ? lrelu(qv + kk0[j]) : NEGV;
                p[j] = __expf(e - cc0[j]) * ii0[j];
            }
            #pragma unroll
            for (int j = 0; j < 4; ++j){
                float e = ((bb >> (4+j)) & 1) ? lrelu(qv + kk1[j]) : NEGV;
                p[4+j] = __expf(e - cc1[j]) * ii1[j];
            }
            *(ushort4*)&pS[pn*LSTR + pm]     = ushort4{f2h(p[0]), f2h(p[1]), f2h(p[2]), f2h(p[3])};
            *(ushort4*)&pS[pn*LSTR + pm + 4] = ushort4{f2h(p[4]), f2h(p[5]), f2h(p[6]), f2h(p[7])};
        }
        __syncthreads();
        {
            v8h af = *(const v8h*)&pS[(w*16 + lrow)*LSTR + quad*8];
            #pragma unroll
            for (int cf = 0; cf < 4; ++cf){
                v8h bf = *(const v8h*)&wS[ldsw(cf*16 + lrow, quad)];
                acc[cf] = MFMA16(af, bf, acc[cf]);
            }
        }
        GLDS(wkb + (size_t)sr*SEG + mtB + sq*8, &wS[2048 + (w << 9)]);
        NW = *(const uint2*)(bmrow + (mtN >> 5));
        {
            unsigned bb = (CW.y >> pm) & 0xffu;
            float4 k0 = *(const float4*)&sKs[mtB+pm], k1 = *(const float4*)&sKs[mtB+pm+4];
            float4 c0 = *(const float4*)&sCm[mtB+pm], c1 = *(const float4*)&sCm[mtB+pm+4];
            float4 i0 = *(const float4*)&sIs[mtB+pm], i1 = *(const float4*)&sIs[mtB+pm+4];
            float p[8];
            const float* kk0 = &k0.x; const float* kk1 = &k1.x;
            const float* cc0 = &c0.x; const float* cc1 = &c1.x;
            const float* ii0 = &i0.x; const float* ii1 = &i1.x;
            #pragma unroll
            for (int j = 0; j < 4; ++j){
                float e = ((bb >> j) & 1) ? lrelu(qv + kk0[j]) : NEGV;
                p[j] = __expf(e - cc0[j]) * ii0[j];
            }
            #pragma unroll
            for (int j = 0; j < 4; ++j){
                float e = ((bb >> (4+j)) & 1) ? lrelu(qv + kk1[j]) : NEGV;
                p[4+j] = __expf(e - cc1[j]) * ii1[j];
            }
            *(ushort4*)&pS[2304 + pn*LSTR + pm]     = ushort4{f2h(p[0]), f2h(p[1]), f2h(p[2]), f2h(p[3])};
            *(ushort4*)&pS[2304 + pn*LSTR + pm + 4] = ushort4{f2h(p[4]), f2h(p[5]), f2h(p[6]), f2h(p[7])};
        }
        __syncthreads();
        {
            v8h af = *(const v8h*)&pS[2304 + (w*16 + lrow)*LSTR + quad*8];
            #pragma unroll
            for (int cf = 0; cf < 4; ++cf){
                v8h bf = *(const v8h*)&wS[2048 + ldsw(cf*16 + lrow, quad)];
                acc[cf] = MFMA16(af, bf, acc[cf]);
            }
        }
        CW = NW;
    }
    #pragma unroll
    for (int cf = 0; cf < 4; ++cf){
        int colg = h*64 + cf*16 + lrow;
        int rbase = n0 + w*16 + quad*4;
        #pragma unroll
        for (int reg = 0; reg < 4; ++reg){
            float v = acc[cf][reg];
            v = (v > 0.f) ? v : (__expf(v) - 1.f);
            outp[((size_t)b*N + rbase + reg)*512 + colg] = f2h(v);
        }
    }
}

// ============ batched attention: attn0 (512 blk) + attn1 (128) + attn2 (512) ============
__global__ __launch_bounds__(256) void attn_all_k(
    const unsigned* __restrict__ bm_gc, const unsigned* __restrict__ bm_qg,
    const unsigned* __restrict__ bm_gq,
    const float* __restrict__ qs3,
    const float* __restrict__ ksh, const float* __restrict__ cmh, const float* __restrict__ ish,
    const unsigned short* __restrict__ WkT3,
    unsigned short* __restrict__ agg0, unsigned short* __restrict__ agg1,
    unsigned short* __restrict__ agg2){
    __shared__ unsigned short pS[2*64*LSTR];
    __shared__ alignas(16) unsigned short wS[2*2048];
    __shared__ float qsS[64];
    __shared__ alignas(16) float sKs[1024], sCm[1024], sIs[1024];
    int F = blockIdx.x;
    const int S0 = (NG/64)*32;            // 512
    const int S1 = S0 + (NQ/64)*32;       // 640
    if (F < S0)
        attn_body(F, pS, wS, qsS, sKs, sCm, sIs, bm_gc, NC/32, qs3, 0,
                  ksh, cmh, ish, 0, WkT3, agg0, NG, NC);
    else if (F < S1)
        attn_body(F - S0, pS, wS, qsS, sKs, sCm, sIs, bm_qg, NG/32, qs3, 1024,
                  ksh, cmh, ish, 1024, WkT3, agg1, NQ, NG);
    else
        attn_body(F - S1, pS, wS, qsS, sKs, sCm, sIs, bm_gq, NQ/32, qs3, 1280,
                  ksh, cmh, ish, 2048, WkT3, agg2, NG, NQ);
}

extern "C" void kernel_launch(void* const* d_in, const int* in_sizes, int n_in,
                              void* d_out, int out_size, void* d_ws, size_t ws_size,
                              hipStream_t stream){
    const float* in_gloss = (const float*)d_in[0];
    const float* in_clip  = (const float*)d_in[1];
    const float* in_q     = (const float*)d_in[2];
    const int*   adj_gc   = (const int*)d_in[3];
    const int*   adj_gq   = (const int*)d_in[4];
    const float* c2gW  = (const float*)d_in[5];
    const float* c2ga1 = (const float*)d_in[6];
    const float* c2ga2 = (const float*)d_in[7];
    const float* g2qW  = (const float*)d_in[8];
    const float* g2qa1 = (const float*)d_in[9];
    const float* g2qa2 = (const float*)d_in[10];
    const float* q2gW  = (const float*)d_in[11];
    const float* q2ga1 = (const float*)d_in[12];
    const float* q2ga2 = (const float*)d_in[13];
    const float* fusW  = (const float*)d_in[14];
    const float* fusU  = (const float*)d_in[15];
    const float* fusWf = (const float*)d_in[16];
    const float* fusUf = (const float*)d_in[17];
    float* out = (float*)d_out;
    float* out_gloss = out;
    float* out_clip  = out + (size_t)NB*NG*NFEAT;
    float* out_q     = out + (size_t)NB*NG*NFEAT*2;

    char* wsB = (char*)d_ws;
    size_t off = 0;
    auto alloc = [&](size_t bytes){ void* p = wsB + off; off += (bytes + 255) & ~(size_t)255; return p; };
    float* wa13  = (float*)alloc(3*4096*4);
    float* wa23  = (float*)alloc(3*4096*4);
    float* qs3   = (float*)alloc((size_t)NB*SEG*8*4);
    float* ks3   = (float*)alloc((size_t)NB*SEG*8*4);
    float* ksh3  = (float*)alloc((size_t)NB*8*SEG*4);
    float* cmh3  = (float*)alloc((size_t)NB*8*SEG*4);
    float* ish3  = (float*)alloc((size_t)NB*8*SEG*4);
    float* pcm   = (float*)alloc((size_t)NB*CHUNKS*SEG*8*4);
    float* psum  = (float*)alloc((size_t)NB*CHUNKS*SEG*8*4);
    unsigned short* WflatT3 = (unsigned short*)alloc((size_t)3*FF*2);
    unsigned short* WkT3    = (unsigned short*)alloc((size_t)NB*512*SEG*2);
    unsigned short* wtAll   = (unsigned short*)alloc((size_t)32*FF*2);
    unsigned short* wtAllLo = (unsigned short*)alloc((size_t)32*FF*2);
    unsigned short* adjTgc  = (unsigned short*)alloc((size_t)NB*NC*NG*2);
    unsigned short* g_bf0   = (unsigned short*)alloc((size_t)NB*NG*NFEAT*2);
    unsigned short* gLo0    = (unsigned short*)alloc((size_t)NB*NG*NFEAT*2);
    unsigned short* g_bf1   = (unsigned short*)alloc((size_t)NB*NG*NFEAT*2);
    unsigned short* gLo1    = (unsigned short*)alloc((size_t)NB*NG*NFEAT*2);
    unsigned short* gT      = (unsigned short*)alloc((size_t)NB*NFEAT*NG*2);
    unsigned short* gTlo    = (unsigned short*)alloc((size_t)NB*NFEAT*NG*2);
    unsigned short* gA_bf   = (unsigned short*)alloc((size_t)NB*NG*NFEAT*2);
    unsigned short* gALo    = (unsigned short*)alloc((size_t)NB*NG*NFEAT*2);
    unsigned short* c_bf0   = (unsigned short*)alloc((size_t)NB*NC*NFEAT*2);
    unsigned short* cLo0    = (unsigned short*)alloc((size_t)NB*NC*NFEAT*2);
    unsigned short* c_bf1   = (unsigned short*)alloc((size_t)NB*NC*NFEAT*2);
    unsigned short* cLo1    = (unsigned short*)alloc((size_t)NB*NC*NFEAT*2);
    unsigned short* q_bf0   = (unsigned short*)alloc((size_t)NB*NQ*NFEAT*2);
    unsigned short* q_bf1   = (unsigned short*)alloc((size_t)NB*NQ*NFEAT*2);
    unsigned short* agg_bf  = (unsigned short*)alloc((size_t)NB*NG*NFEAT*2);
    unsigned short* aggLo   = (unsigned short*)alloc((size_t)NB*NG*NFEAT*2);
    unsigned short* agg0    = (unsigned short*)alloc((size_t)NB*NG*NFEAT*2);
    unsigned short* agg1    = (unsigned short*)alloc((size_t)NB*NQ*NFEAT*2);
    unsigned short* agg2    = (unsigned short*)alloc((size_t)NB*NG*NFEAT*2);
    int* adjTgq = (int*)alloc((size_t)NB*NQ*NG*4);
    unsigned* bm_gc = (unsigned*)alloc((size_t)NB*NG*(NC/32)*4);
    unsigned* bm_cg = (unsigned*)alloc((size_t)NB*NC*(NG/32)*4);
    unsigned* bm_gq = (unsigned*)alloc((size_t)NB*NG*(NQ/32)*4);
    unsigned* bm_qg = (unsigned*)alloc((size_t)NB*NQ*(NG/32)*4);
    (void)ws_size; (void)in_sizes; (void)n_in; (void)out_size;

    const size_t HFD = (size_t)NHEADS*NFEAT*HDIM;
    const size_t HD  = (size_t)NHEADS*HDIM;

    // ---- prep ----
    wtT_k<<<2048, 256, 0, stream>>>(fusW, fusU, fusWf, fusUf, wtAll, wtAllLo);
    adjT_h_k<<<dim3(NC/64, NG/64, NB), 256, 0, stream>>>(adj_gc, adjTgc,
        (unsigned long long*)bm_gc, (unsigned long long*)bm_cg);
    adjT_int_k<<<dim3(NQ/64, NG/64, NB), 256, 0, stream>>>(adj_gq, adjTgq,
        (unsigned long long*)bm_gq, (unsigned long long*)bm_qg);
    cvt_hl_k<<<(NB*NC*NFEAT)/2048, 256, 0, stream>>>(in_clip,  c_bf0, cLo0);
    cvt_h_k<<<(NB*NQ*NFEAT)/2048, 256, 0, stream>>>(in_q,     q_bf0);
    actT_hl_k<<<dim3(8, NG/64, NB), 256, 0, stream>>>(in_gloss, gT, gTlo, g_bf0, gLo0, NG);

    for (int l = 0; l < 2; ++l){
        const unsigned short* g_cur = (l == 0) ? g_bf0 : g_bf1;
        const unsigned short* gLoC  = (l == 0) ? gLo0  : gLo1;
        const unsigned short* c_cur = (l == 0) ? c_bf0 : c_bf1;
        const unsigned short* cLoC  = (l == 0) ? cLo0  : cLo1;
        const unsigned short* q_cur = (l == 0) ? q_bf0 : q_bf1;
        unsigned short* g_nxt = (l == 0) ? g_bf1 : g_bf0;
        unsigned short* gLoN  = (l == 0) ? gLo1  : nullptr;
        unsigned short* c_nxt = (l == 0) ? c_bf1 : c_bf0;
        unsigned short* cLoN  = (l == 0) ? cLo1  : nullptr;
        unsigned short* q_nxt = (l == 0) ? q_bf1 : q_bf0;
        float* gF = (l == 1) ? out_gloss : nullptr;
        float* cF = (l == 1) ? out_clip  : nullptr;
        float* qF = (l == 1) ? out_q     : nullptr;

        // ---- batched attention prep (depends only on layer inputs) ----
        prep_attnW3_k<<<240, 256, 0, stream>>>(
            c2gW + l*HFD, c2ga1 + l*HD, c2ga2 + l*HD,
            g2qW + l*HFD, g2qa1 + l*HD, g2qa2 + l*HD,
            q2gW + l*HFD, q2ga1 + l*HD, q2ga2 + l*HD,
            WflatT3, wa13, wa23);
        scores3_k<<<(NB*4608)/4, 256, 0, stream>>>(g_cur, c_cur, q_cur, wa13, wa23, qs3, ks3);
        wkt3_mfma_k<<<dim3(8, 36, NB), 256, 0, stream>>>(c_cur, g_cur, q_cur, WflatT3, WkT3);
        colstat3_k<<<dim3(576, 1, NB), 256, 0, stream>>>(bm_cg, bm_gq, bm_qg, qs3, ks3, pcm, psum);
        colfin3_k<<<(NB*SEG*8)/256, 256, 0, stream>>>(pcm, psum, ks3, ksh3, cmh3, ish3);

        // gloss_same = adj_gc^T @ gloss (hi/lo B, hi/lo out)
        gemmT_mfma_k<<<dim3(8, NC/64, NB), 256, 0, stream>>>(adjTgc, (size_t)NC*NG, gT, gTlo,
                                                             (size_t)512*NG, NG, NC,
                                                             agg_bf, aggLo, nullptr);
        // all 3 attentions in one launch -> agg0 (clip_agg), agg1 (gloss_agg), agg2 (question_agg)
        attn_all_k<<<(NG/64)*32 + (NQ/64)*32 + (NG/64)*32, 256, 0, stream>>>(
            bm_gc, bm_qg, bm_gq, qs3, ksh3, cmh3, ish3, WkT3, agg0, agg1, agg2);
        // gloss_1 + question_1 in one launch
        fusion1b_k<<<8*(NG/64)*NB + 8*(NQ/64)*NB, 256, 0, stream>>>(
            g_cur, gLoC, agg0, wtAll + (size_t)((l*4 + 1)*4)*FF, gA_bf, gALo,
            q_cur, agg1, wtAll + (size_t)((l*4 + 2)*4)*FF, q_nxt, qF);
        // clip_1 + gloss_2 in one launch (128-row tiles)
        fusion3b_k<<<8*(NC/128)*NB + 8*(NG/128)*NB, 256, 0, stream>>>(
            c_cur, cLoC, agg_bf, aggLo,
            wtAll + (size_t)((l*4 + 0)*4)*FF, wtAllLo + (size_t)((l*4 + 0)*4)*FF,
            c_nxt, cLoN, cF,
            gA_bf, gALo, agg2,
            wtAll + (size_t)((l*4 + 3)*4)*FF, wtAllLo + (size_t)((l*4 + 3)*4)*FF,
            g_nxt, gLoN, (l == 0) ? gT : nullptr, (l == 0) ? gTlo : nullptr, gF);
    }
}

// Round 10
// 613.268 us; speedup vs baseline: 1.4773x; 1.0191x over previous
//
#include <hip/hip_runtime.h>
#include <math.h>

#define NFEAT 512
#define NHEADS 8
#define HDIM 64
#define NB 4
#define NG 1024
#define NC 1024
#define NQ 256
#define NEGV -9e15f
#define CHUNKS 16
#define FF ((size_t)NFEAT*NFEAT)
#define LSTR 36   // LDS row stride (ushorts) for reg-written P tiles only
#define SEG 2304  // segmented attn rows per batch

typedef _Float16 v8h __attribute__((ext_vector_type(8)));
typedef float v4f __attribute__((ext_vector_type(4)));
#define MFMA16(a,b,c) __builtin_amdgcn_mfma_f32_16x16x32_f16((a),(b),(c),0,0,0)

// async global->LDS, 16B/lane, lane-linear LDS dest (wave-uniform base + lane*16)
#define GLDS(g, l) __builtin_amdgcn_global_load_lds( \
    (__attribute__((address_space(1))) void*)(g), \
    (__attribute__((address_space(3))) void*)(l), 16, 0, 0)

// XOR swizzle for 64B-row linear LDS tiles: physical 16B slot = quad ^ ((row>>1)&3).
__device__ __forceinline__ int ldsw(int row, int quad){
    return row*32 + (((quad) ^ ((row>>1)&3)) << 3);
}

__device__ __forceinline__ float lrelu(float x){ return fmaxf(x, 0.2f*x); }
__device__ __forceinline__ unsigned short f2h(float x){ union{_Float16 h; unsigned short u;} v; v.h = (_Float16)x; return v.u; }
__device__ __forceinline__ float h2f(unsigned short u){ union{_Float16 h; unsigned short u;} v; v.u = u; return (float)v.h; }

// ============ prep: clip fp32 -> hi/lo (blocks 0..1023) + question fp32 -> fp16 (1024..1279) ============
__global__ __launch_bounds__(256) void cvt2_k(const float* __restrict__ clip,
    unsigned short* __restrict__ cHi, unsigned short* __restrict__ cLo,
    const float* __restrict__ ques, unsigned short* __restrict__ qDst){
    int bx = blockIdx.x;
    if (bx < 1024){
        int idx = bx*256 + threadIdx.x;
        const float4* s = (const float4*)(clip + (size_t)idx*8);
        float4 a = s[0], b = s[1];
        float x[8] = {a.x,a.y,a.z,a.w,b.x,b.y,b.z,b.w};
        unsigned short hi[8], lo[8];
        #pragma unroll
        for (int j = 0; j < 8; ++j){ hi[j] = f2h(x[j]); lo[j] = f2h(x[j] - h2f(hi[j])); }
        *(ushort4*)(cHi + (size_t)idx*8)     = ushort4{hi[0],hi[1],hi[2],hi[3]};
        *(ushort4*)(cHi + (size_t)idx*8 + 4) = ushort4{hi[4],hi[5],hi[6],hi[7]};
        *(ushort4*)(cLo + (size_t)idx*8)     = ushort4{lo[0],lo[1],lo[2],lo[3]};
        *(ushort4*)(cLo + (size_t)idx*8 + 4) = ushort4{lo[4],lo[5],lo[6],lo[7]};
    } else {
        int idx = (bx - 1024)*256 + threadIdx.x;
        const float4* s = (const float4*)(ques + (size_t)idx*8);
        float4 a = s[0], b = s[1];
        ushort4 p0{f2h(a.x),f2h(a.y),f2h(a.z),f2h(a.w)};
        ushort4 p1{f2h(b.x),f2h(b.y),f2h(b.z),f2h(b.w)};
        *(ushort4*)(qDst + (size_t)idx*8) = p0;
        *(ushort4*)(qDst + (size_t)idx*8 + 4) = p1;
    }
}

// ============ prep: fusion weights -> PACKED transposed fp16 hi/lo ============
// packed layout per group li: [c0i(8)][ktI(16)][mat(4)][row64][k32]
__global__ __launch_bounds__(256) void wtT_k(const float* __restrict__ w0, const float* __restrict__ w1,
    const float* __restrict__ w2, const float* __restrict__ w3,
    unsigned short* __restrict__ dstHi, unsigned short* __restrict__ dstLo){
    int bx = blockIdx.x;
    int mat = bx >> 6, t = bx & 63;
    int a = mat & 3, li = mat >> 2;
    const float* src = (a==0?w0:a==1?w1:a==2?w2:w3) + (size_t)li*FF;
    int fo0 = (t>>3)*64, fi0 = (t&7)*64;
    __shared__ float sT[64][65];
    int tid = threadIdx.x;
    #pragma unroll
    for (int it = 0; it < 4; ++it){
        int idx = it*256 + tid;
        int r = idx >> 4, c4 = idx & 15;
        float4 v = *(const float4*)(src + (size_t)(fi0+r)*512 + fo0 + c4*4);
        sT[r][c4*4+0]=v.x; sT[r][c4*4+1]=v.y; sT[r][c4*4+2]=v.z; sT[r][c4*4+3]=v.w;
    }
    __syncthreads();
    #pragma unroll
    for (int it = 0; it < 2; ++it){
        int idx = it*256 + tid;
        int dd = idx >> 3, c8 = idx & 7;
        unsigned short hi[8], lo[8];
        #pragma unroll
        for (int j = 0; j < 8; ++j){
            float x = sT[c8*8+j][dd];
            hi[j] = f2h(x);
            lo[j] = f2h(x - h2f(hi[j]));
        }
        int ktI = (fi0 >> 5) + (c8 >> 2);
        int k31 = (c8 & 3)*8;
        size_t oo = (size_t)li*4*FF + ((((size_t)(fo0>>6)*16 + ktI)*4 + a)*64 + dd)*32 + k31;
        *(ushort4*)(dstHi+oo)   = ushort4{hi[0],hi[1],hi[2],hi[3]};
        *(ushort4*)(dstHi+oo+4) = ushort4{hi[4],hi[5],hi[6],hi[7]};
        *(ushort4*)(dstLo+oo)   = ushort4{lo[0],lo[1],lo[2],lo[3]};
        *(ushort4*)(dstLo+oo+4) = ushort4{lo[4],lo[5],lo[6],lo[7]};
    }
}

// ============ prep: 3 attn W repacks (blocks 0..191) + wa vectors (blocks 192..239) ============
__global__ __launch_bounds__(256) void prep_attnW3_k(
    const float* __restrict__ W0, const float* __restrict__ a10, const float* __restrict__ a20,
    const float* __restrict__ W1, const float* __restrict__ a11, const float* __restrict__ a21,
    const float* __restrict__ W2, const float* __restrict__ a12, const float* __restrict__ a22,
    unsigned short* __restrict__ WT3, float* __restrict__ wa13, float* __restrict__ wa23){
    int bx = blockIdx.x;
    int tid = threadIdx.x;
    if (bx >= 192){
        int r = bx - 192;
        int a = r >> 4;
        const float* W  = (a==0?W0:a==1?W1:W2);
        const float* a1 = (a==0?a10:a==1?a11:a12);
        const float* a2 = (a==0?a20:a==1?a21:a22);
        int idx = (r & 15)*256 + tid;
        int h = idx >> 9;
        const float* Wp = W + (size_t)idx*64;
        float s1 = 0.f, s2 = 0.f;
        #pragma unroll
        for (int d = 0; d < 64; ++d){ float w = Wp[d]; s1 += w*a1[(h<<6)+d]; s2 += w*a2[(h<<6)+d]; }
        wa13[a*4096 + idx] = s1; wa23[a*4096 + idx] = s2;
        return;
    }
    int a = bx >> 6, bxl = bx & 63;
    const float* W = (a==0?W0:a==1?W1:W2);
    unsigned short* WT = WT3 + (size_t)a*FF;
    int h = bxl >> 3, f0 = (bxl & 7)*64;
    __shared__ float sT[64][65];
    #pragma unroll
    for (int it = 0; it < 4; ++it){
        int idx = it*256 + tid;
        int r = idx >> 4, c4 = idx & 15;
        float4 v = *(const float4*)(W + ((size_t)h*512 + f0 + r)*64 + c4*4);
        sT[r][c4*4+0]=v.x; sT[r][c4*4+1]=v.y; sT[r][c4*4+2]=v.z; sT[r][c4*4+3]=v.w;
    }
    __syncthreads();
    #pragma unroll
    for (int it = 0; it < 2; ++it){
        int idx = it*256 + tid;
        int dd = idx >> 3, c8 = idx & 7;
        ushort4 p0{f2h(sT[c8*8+0][dd]),f2h(sT[c8*8+1][dd]),f2h(sT[c8*8+2][dd]),f2h(sT[c8*8+3][dd])};
        ushort4 p1{f2h(sT[c8*8+4][dd]),f2h(sT[c8*8+5][dd]),f2h(sT[c8*8+6][dd]),f2h(sT[c8*8+7][dd])};
        unsigned short* o = WT + ((size_t)h*64 + dd)*512 + f0 + c8*8;
        *(ushort4*)o = p0; *(ushort4*)(o+4) = p1;
    }
}

// ============ prep: adj_gc int -> adjT fp16 [b][c][g] + bitmasks both orientations ============
__global__ __launch_bounds__(256) void adjT_h_k(const int* __restrict__ adj, unsigned short* __restrict__ dst,
    unsigned long long* __restrict__ bm_gc, unsigned long long* __restrict__ bm_cg){
    int b = blockIdx.z;
    int c0 = blockIdx.x*64, g0 = blockIdx.y*64;
    __shared__ int sI[64][65];
    int tid = threadIdx.x;
    #pragma unroll
    for (int it = 0; it < 4; ++it){
        int idx = it*256 + tid;
        int r = idx >> 4, c4 = idx & 15;
        int4 v = *(const int4*)(adj + ((size_t)b*NG + g0 + r)*NC + c0 + c4*4);
        sI[r][c4*4+0]=v.x; sI[r][c4*4+1]=v.y; sI[r][c4*4+2]=v.z; sI[r][c4*4+3]=v.w;
    }
    __syncthreads();
    int wv = tid >> 6, lane = tid & 63;
    #pragma unroll
    for (int it = 0; it < 2; ++it){
        int idx = it*256 + tid;
        int dd = idx >> 3, c8 = idx & 7;
        ushort4 p0, p1;
        #pragma unroll
        for (int j = 0; j < 4; ++j) (&p0.x)[j] = sI[c8*8+j][dd] > 0 ? (unsigned short)0x3C00 : (unsigned short)0;
        #pragma unroll
        for (int j = 0; j < 4; ++j) (&p1.x)[j] = sI[c8*8+4+j][dd] > 0 ? (unsigned short)0x3C00 : (unsigned short)0;
        unsigned short* o = dst + ((size_t)b*NC + c0 + dd)*NG + g0 + c8*8;
        *(ushort4*)o = p0; *(ushort4*)(o+4) = p1;
    }
    #pragma unroll
    for (int rr = wv; rr < 64; rr += 4){
        unsigned long long m = __ballot(sI[rr][lane] > 0);
        if (lane == 0) bm_gc[((size_t)b*NG + g0 + rr)*(NC/64) + (c0>>6)] = m;
    }
    #pragma unroll
    for (int cc = wv; cc < 64; cc += 4){
        unsigned long long m = __ballot(sI[lane][cc] > 0);
        if (lane == 0) bm_cg[((size_t)b*NC + c0 + cc)*(NG/64) + (g0>>6)] = m;
    }
}

// ============ prep: adj_gq int -> adjT int [b][q][g] + bitmasks both orientations ============
__global__ __launch_bounds__(256) void adjT_int_k(const int* __restrict__ adj, int* __restrict__ dst,
    unsigned long long* __restrict__ bm_gq, unsigned long long* __restrict__ bm_qg){
    int b = blockIdx.z;
    int q0 = blockIdx.x*64, g0 = blockIdx.y*64;
    __shared__ int sI[64][65];
    int tid = threadIdx.x;
    #pragma unroll
    for (int it = 0; it < 4; ++it){
        int idx = it*256 + tid;
        int r = idx >> 4, c4 = idx & 15;
        int4 v = *(const int4*)(adj + ((size_t)b*NG + g0 + r)*NQ + q0 + c4*4);
        sI[r][c4*4+0]=v.x; sI[r][c4*4+1]=v.y; sI[r][c4*4+2]=v.z; sI[r][c4*4+3]=v.w;
    }
    __syncthreads();
    int wv = tid >> 6, lane = tid & 63;
    #pragma unroll
    for (int it = 0; it < 4; ++it){
        int idx = it*256 + tid;
        int dd = idx >> 4, c4 = idx & 15;
        int4 v{sI[c4*4+0][dd], sI[c4*4+1][dd], sI[c4*4+2][dd], sI[c4*4+3][dd]};
        *(int4*)(dst + ((size_t)b*NQ + q0 + dd)*NG + g0 + c4*4) = v;
    }
    #pragma unroll
    for (int rr = wv; rr < 64; rr += 4){
        unsigned long long m = __ballot(sI[rr][lane] > 0);
        if (lane == 0) bm_gq[((size_t)b*NG + g0 + rr)*(NQ/64) + (q0>>6)] = m;
    }
    #pragma unroll
    for (int cc = wv; cc < 64; cc += 4){
        unsigned long long m = __ballot(sI[lane][cc] > 0);
        if (lane == 0) bm_qg[((size_t)b*NQ + q0 + cc)*(NG/64) + (g0>>6)] = m;
    }
}

// ============ prep: gloss fp32 -> transposed hi/lo [b][512][N] AND row-major hi/lo ============
__global__ __launch_bounds__(256) void actT_hl_k(const float* __restrict__ src,
    unsigned short* __restrict__ dstHi, unsigned short* __restrict__ dstLo,
    unsigned short* __restrict__ rmHi, unsigned short* __restrict__ rmLo, int Nrows){
    int b = blockIdx.z;
    int f0 = blockIdx.x*64, g0 = blockIdx.y*64;
    __shared__ float sF[64][65];
    int tid = threadIdx.x;
    #pragma unroll
    for (int it = 0; it < 4; ++it){
        int idx = it*256 + tid;
        int r = idx >> 4, c4 = idx & 15;
        float4 v = *(const float4*)(src + ((size_t)b*Nrows + g0 + r)*512 + f0 + c4*4);
        sF[r][c4*4+0]=v.x; sF[r][c4*4+1]=v.y; sF[r][c4*4+2]=v.z; sF[r][c4*4+3]=v.w;
    }
    __syncthreads();
    #pragma unroll
    for (int it = 0; it < 2; ++it){
        int idx = it*256 + tid;
        int dd = idx >> 3, c8 = idx & 7;
        unsigned short hi[8], lo[8];
        #pragma unroll
        for (int j = 0; j < 8; ++j){
            float x = sF[c8*8+j][dd];
            hi[j] = f2h(x);
            lo[j] = f2h(x - h2f(hi[j]));
        }
        size_t oo = ((size_t)b*512 + f0 + dd)*Nrows + g0 + c8*8;
        *(ushort4*)(dstHi+oo)   = ushort4{hi[0],hi[1],hi[2],hi[3]};
        *(ushort4*)(dstHi+oo+4) = ushort4{hi[4],hi[5],hi[6],hi[7]};
        *(ushort4*)(dstLo+oo)   = ushort4{lo[0],lo[1],lo[2],lo[3]};
        *(ushort4*)(dstLo+oo+4) = ushort4{lo[4],lo[5],lo[6],lo[7]};
    }
    #pragma unroll
    for (int it = 0; it < 2; ++it){
        int idx = it*256 + tid;
        int r = idx >> 3, c8 = idx & 7;
        unsigned short hi[8], lo[8];
        #pragma unroll
        for (int j = 0; j < 8; ++j){
            float x = sF[r][c8*8+j];
            hi[j] = f2h(x);
            lo[j] = f2h(x - h2f(hi[j]));
        }
        size_t oo = ((size_t)b*Nrows + g0 + r)*512 + f0 + c8*8;
        *(ushort4*)(rmHi+oo)   = ushort4{hi[0],hi[1],hi[2],hi[3]};
        *(ushort4*)(rmHi+oo+4) = ushort4{hi[4],hi[5],hi[6],hi[7]};
        *(ushort4*)(rmLo+oo)   = ushort4{lo[0],lo[1],lo[2],lo[3]};
        *(ushort4*)(rmLo+oo+4) = ushort4{lo[4],lo[5],lo[6],lo[7]};
    }
}

// ============ scores body ============
__device__ __forceinline__ void scores3_body(int F,
    const unsigned short* g, const unsigned short* c, const unsigned short* q,
    const float* wa13, const float* wa23,
    float* qs3, float* ks3){
    int lane = threadIdx.x & 63;
    int grow = F*4 + (threadIdx.x >> 6);
    int b = grow / 4608; int r = grow - b*4608;
    const unsigned short* X; const float* wa; float* out; int n, oOff, rowsX;
    if (r < SEG){
        out = qs3;
        if (r < 1024)      { X=g; wa=wa13;        n=r;        oOff=0;    rowsX=NG; }
        else if (r < 1280) { X=q; wa=wa13+4096;   n=r-1024;   oOff=1024; rowsX=NQ; }
        else               { X=g; wa=wa13+8192;   n=r-1280;   oOff=1280; rowsX=NG; }
    } else {
        out = ks3; r -= SEG;
        if (r < 1024)      { X=c; wa=wa23;        n=r;        oOff=0;    rowsX=NC; }
        else if (r < 2048) { X=g; wa=wa23+4096;   n=r-1024;   oOff=1024; rowsX=NG; }
        else               { X=q; wa=wa23+8192;   n=r-2048;   oOff=2048; rowsX=NQ; }
    }
    const unsigned short* Xr = X + ((size_t)b*rowsX + n)*NFEAT;
    float p[NHEADS];
    #pragma unroll
    for (int h = 0; h < NHEADS; ++h) p[h] = 0.f;
    #pragma unroll
    for (int cc = 0; cc < 8; ++cc){
        float x = h2f(Xr[(cc<<6) + lane]);
        #pragma unroll
        for (int h = 0; h < NHEADS; ++h) p[h] += x * wa[(h<<9) + (cc<<6) + lane];
    }
    #pragma unroll
    for (int h = 0; h < NHEADS; ++h){
        float v = p[h];
        #pragma unroll
        for (int off = 32; off > 0; off >>= 1) v += __shfl_xor(v, off);
        if (lane == 0) out[((size_t)b*SEG + oOff + n)*8 + h] = v;
    }
}

// ============ generic 64x64 GEMM step body on shared dbuf LDS ============
__device__ __forceinline__ void gemm64_body(
    unsigned short (*aS)[2048], unsigned short (*bS)[2048],
    const unsigned short* aG, size_t aRow, int aStep,
    const unsigned short* bG0, const unsigned short* bG1, size_t bRow, int bStep,
    int spp, int nsteps, v4f* acc){
    int tid = threadIdx.x;
    int w = tid >> 6;
    int lane = tid & 63;
    int lrow = lane & 15, quad = lane >> 4;
    GLDS(aG + aRow, &aS[0][w << 9]);
    GLDS(bG0 + bRow, &bS[0][w << 9]);
    __syncthreads();
    int buf = 0;
    for (int s = 0; s < nsteps; ++s){
        int sn = s + 1;
        if (sn < nsteps){
            int kin = (sn >= spp) ? (sn - spp) : sn;
            const unsigned short* bgn = (sn >= spp) ? bG1 : bG0;
            GLDS(aG + aRow + (size_t)((sn >= spp) ? (sn - spp) : sn)*aStep, &aS[buf^1][w << 9]);
            GLDS(bgn + bRow + (size_t)kin*bStep, &bS[buf^1][w << 9]);
        }
        v8h af = *(const v8h*)&aS[buf][ldsw(w*16 + lrow, quad)];
        #pragma unroll
        for (int cf = 0; cf < 4; ++cf){
            v8h bf = *(const v8h*)&bS[buf][ldsw(cf*16 + lrow, quad)];
            acc[cf] = MFMA16(af, bf, acc[cf]);
        }
        __syncthreads();
        buf ^= 1;
    }
}

// ============ merged layer-B: scores (0..4607) | wkt3 (..5759) | gemmT gloss_same (..6271) ============
__global__ __launch_bounds__(256) void layerB_k(
    const unsigned short* __restrict__ g, const unsigned short* __restrict__ c,
    const unsigned short* __restrict__ q,
    const float* __restrict__ wa13, const float* __restrict__ wa23,
    float* __restrict__ qs3, float* __restrict__ ks3,
    const unsigned short* __restrict__ WT3, unsigned short* __restrict__ WkT3,
    const unsigned short* __restrict__ adjTgc,
    const unsigned short* __restrict__ gT, const unsigned short* __restrict__ gTlo,
    unsigned short* __restrict__ agg_bf, unsigned short* __restrict__ aggLo){
    __shared__ alignas(16) unsigned short aS[2][2048], bS[2][2048];
    int F = blockIdx.x;
    if (F < 4608){
        scores3_body(F, g, c, q, wa13, wa23, qs3, ks3);
        return;
    }
    int tid = threadIdx.x;
    int w = tid >> 6, lane = tid & 63;
    int lrow = lane & 15, quad = lane >> 4;
    int sr = tid >> 2;
    int sq = (tid & 3) ^ ((sr >> 1) & 3);
    v4f acc[4];
    #pragma unroll
    for (int cf = 0; cf < 4; ++cf) acc[cf] = (v4f)0.f;
    if (F < 5760){
        // wkt3: i = F-4608; b = i/288; y = (i%288)/8; x = i%8
        int i = F - 4608;
        int b = i / 288, rem = i - b*288;
        int y = rem >> 3, x = rem & 7;
        const unsigned short* kv; int rowsX, mOff, a;
        if (y < 16)      { a=0; kv=c; rowsX=NC; mOff=0; }
        else if (y < 32) { a=1; y-=16; kv=g; rowsX=NG; mOff=1024; }
        else             { a=2; y-=32; kv=q; rowsX=NQ; mOff=2048; }
        int r0 = y*64, c0 = x*64;
        const unsigned short* aG = kv + (size_t)b*rowsX*512;
        const unsigned short* bG = WT3 + (size_t)a*FF;
        size_t aRow = (size_t)(r0 + sr)*512 + sq*8;
        size_t bRow = (size_t)(c0 + sr)*512 + sq*8;
        gemm64_body(aS, bS, aG, aRow, 32, bG, nullptr, bRow, 32, 16, 16, acc);
        #pragma unroll
        for (int cf = 0; cf < 4; ++cf){
            int colg = c0 + cf*16 + lrow;
            int rbase = r0 + w*16 + quad*4;
            ushort4 pk{f2h(acc[cf][0]), f2h(acc[cf][1]), f2h(acc[cf][2]), f2h(acc[cf][3])};
            *(ushort4*)&WkT3[((size_t)b*512 + colg)*SEG + mOff + rbase] = pk;
        }
    } else {
        // gemmT gloss_same: i = F-5760; b = i/128; y = (i%128)/8; x = i%8
        int i = F - 5760;
        int b = i >> 7, rem = i & 127;
        int y = rem >> 3, x = rem & 7;
        int r0 = y*64, c0 = x*64;
        const unsigned short* aG = adjTgc + (size_t)b*NC*NG;
        const unsigned short* bG0 = gT + (size_t)b*512*NG;
        const unsigned short* bG1 = gTlo + (size_t)b*512*NG;
        size_t aRow = (size_t)(r0 + sr)*NG + sq*8;
        size_t bRow = (size_t)(c0 + sr)*NG + sq*8;
        gemm64_body(aS, bS, aG, aRow, 32, bG0, bG1, bRow, 32, 32, 64, acc);
        #pragma unroll
        for (int cf = 0; cf < 4; ++cf){
            int colg = c0 + cf*16 + lrow;
            int rbase = r0 + w*16 + quad*4;
            #pragma unroll
            for (int reg = 0; reg < 4; ++reg){
                float v = acc[cf][reg];
                unsigned short hv = f2h(v);
                size_t oo = ((size_t)b*NC + rbase + reg)*512 + colg;
                agg_bf[oo] = hv;
                aggLo[oo] = f2h(v - h2f(hv));
            }
        }
    }
}

// ============ batched colstat: all 3 attns, per-chunk (cm, sum) via bitmasks ============
__global__ __launch_bounds__(256) void colstat3_k(
    const unsigned* __restrict__ bm_cg, const unsigned* __restrict__ bm_gq,
    const unsigned* __restrict__ bm_qg,
    const float* __restrict__ qs3, const float* __restrict__ ks3,
    float* __restrict__ pcm, float* __restrict__ psum){
    int x = blockIdx.x, b = blockIdx.z;
    const unsigned* bm; int Mrows, N, N32, mOff, qOff;
    if (x < 256)      { bm=bm_cg; Mrows=NC; N=NG; N32=NG/32; mOff=0;    qOff=0; }
    else if (x < 512) { x-=256; bm=bm_gq; Mrows=NG; N=NQ; N32=NQ/32; mOff=1024; qOff=1024; }
    else              { x-=512; bm=bm_qg; Mrows=NQ; N=NG; N32=NG/32; mOff=2048; qOff=1280; }
    int mt = x >> 4, ch = x & 15;
    int chunk = N / CHUNKS, subl = chunk >> 2;
    int ml = threadIdx.x & 63; int m = mt*64 + ml;
    int g = threadIdx.x >> 6;
    int n0 = ch*chunk + g*subl;
    __shared__ float sQ[64][8];
    for (int t2 = threadIdx.x; t2 < chunk*8; t2 += 256)
        sQ[t2>>3][t2&7] = qs3[((size_t)b*SEG + qOff + ch*chunk)*8 + t2];
    float ksv[8];
    size_t mo = ((size_t)b*SEG + mOff + m)*8;
    #pragma unroll
    for (int h = 0; h < 8; ++h) ksv[h] = ks3[mo+h];
    unsigned word = bm[((size_t)b*Mrows + m)*N32 + (n0>>5)];
    unsigned bits = (word >> (n0 & 31)) & ((1u << subl) - 1u);
    __syncthreads();
    int nb = g*subl;
    float mx[8];
    #pragma unroll
    for (int h = 0; h < 8; ++h) mx[h] = -INFINITY;
    for (int i = 0; i < subl; ++i){
        if ((bits >> i) & 1){
            #pragma unroll
            for (int h = 0; h < 8; ++h) mx[h] = fmaxf(mx[h], sQ[nb+i][h]);
        }
    }
    float cm[8], s[8];
    #pragma unroll
    for (int h = 0; h < 8; ++h){
        cm[h] = bits ? lrelu(mx[h] + ksv[h]) : NEGV;
        s[h] = 0.f;
    }
    for (int i = 0; i < subl; ++i){
        bool on = (bits >> i) & 1;
        #pragma unroll
        for (int h = 0; h < 8; ++h){
            float e = on ? lrelu(sQ[nb+i][h] + ksv[h]) : NEGV;
            s[h] += __expf(e - cm[h]);
        }
    }
    __shared__ float scm[4][64][8], ssm[4][64][8];
    #pragma unroll
    for (int h = 0; h < 8; ++h){ scm[g][ml][h] = cm[h]; ssm[g][ml][h] = s[h]; }
    __syncthreads();
    if (g == 0){
        #pragma unroll
        for (int h = 0; h < 8; ++h){
            float c0 = scm[0][ml][h], c1 = scm[1][ml][h], c2 = scm[2][ml][h], c3 = scm[3][ml][h];
            float CM = fmaxf(fmaxf(c0, c1), fmaxf(c2, c3));
            float S = ssm[0][ml][h]*__expf(c0-CM) + ssm[1][ml][h]*__expf(c1-CM)
                    + ssm[2][ml][h]*__expf(c2-CM) + ssm[3][ml][h]*__expf(c3-CM);
            size_t o = (((size_t)b*CHUNKS + ch)*SEG + mOff + m)*8 + h;
            pcm[o] = CM; psum[o] = S;
        }
    }
}

// ============ batched finalize: chunk-combine + repack -> ksh/cmh/ish [b][8][SEG] ============
__global__ __launch_bounds__(256) void colfin3_k(const float* __restrict__ pcm, const float* __restrict__ psum,
    const float* __restrict__ ks3, float* __restrict__ ksh, float* __restrict__ cmh,
    float* __restrict__ ish){
    int idx = blockIdx.x*256 + threadIdx.x;    // NB*SEG*8
    const int m8 = SEG*8;
    int b = idx / m8, rem = idx - b*m8;
    int m = rem >> 3, h = rem & 7;
    size_t base = (size_t)b*CHUNKS*m8 + rem;
    float c[CHUNKS], s[CHUNKS];
    #pragma unroll
    for (int ch = 0; ch < CHUNKS; ++ch){
        c[ch] = pcm[base + (size_t)ch*m8];
        s[ch] = psum[base + (size_t)ch*m8];
    }
    float CM = c[0];
    #pragma unroll
    for (int ch = 1; ch < CHUNKS; ++ch) CM = fmaxf(CM, c[ch]);
    float S = 0.f;
    #pragma unroll
    for (int ch = 0; ch < CHUNKS; ++ch) S += s[ch]*__expf(c[ch] - CM);
    size_t o = ((size_t)b*8 + h)*SEG + m;
    ksh[o] = ks3[idx]; cmh[o] = CM; ish[o] = 1.f/S;
}

// ============ 3-pass fusion body: 128-row tile, shared weight staging ============
__device__ __forceinline__ void fusion3_body(int F,
    unsigned short* aHs, unsigned short* bHs, unsigned short* aLs, unsigned short* bLs,
    unsigned short* wHs, unsigned short* wLs,
    const unsigned short* aHi, const unsigned short* aLo,
    const unsigned short* bHi, const unsigned short* bLo,
    const unsigned short* Whi, const unsigned short* Wlo,
    unsigned short* dst, unsigned short* dstLo,
    unsigned short* dstT, unsigned short* dstTLo,
    float* dstF, int rows){
    int nY = rows >> 7;                  // 128-row tiles
    int ppg = (nY * NB) >> 3;
    int xcd = F & 7, t = F >> 3;
    int c0i = t / ppg;
    int p = xcd + ((t - c0i*ppg) << 3);
    int r0 = (p % nY) << 7, c0 = c0i << 6;
    int b = p / nY;
    int tid = threadIdx.x;
    size_t actOff = (size_t)b*rows*512;
    const unsigned short* aHG = aHi + actOff;
    const unsigned short* bHG = bHi + actOff;
    const unsigned short* aLG = aLo ? aLo + actOff : nullptr;
    const unsigned short* bLG = bLo ? bLo + actOff : nullptr;
    bool hasALo = (aLG != nullptr);
    bool hasBLo = (bLG != nullptr);
    int w = tid >> 6, lane = tid & 63;
    int wr = w >> 1, wc = w & 1;
    int lrow = lane & 15, quad = lane >> 4;
    int sr = tid >> 2;
    int sq = (tid & 3) ^ ((sr >> 1) & 3);
    size_t aRow0 = (size_t)(r0 + sr)*512 + sq*8;
    size_t aRow1 = (size_t)(r0 + 64 + sr)*512 + sq*8;
    size_t wPk = (size_t)c0i*16*8192 + (size_t)sr*32 + sq*8;
    int d0 = w << 9, d1 = 2048 + (w << 9);
    v4f accN[2][2][2], accF[2][2][2];     // [rt][r][cf]
    #pragma unroll
    for (int rt = 0; rt < 2; ++rt)
        #pragma unroll
        for (int r = 0; r < 2; ++r)
            #pragma unroll
            for (int cf = 0; cf < 2; ++cf){ accN[rt][r][cf] = (v4f)0.f; accF[rt][r][cf] = (v4f)0.f; }
    for (int kt = 0; kt < 512; kt += 32){
        __syncthreads();
        GLDS(aHG + aRow0 + kt, &aHs[d0]);
        GLDS(aHG + aRow1 + kt, &aHs[d1]);
        GLDS(bHG + aRow0 + kt, &bHs[d0]);
        GLDS(bHG + aRow1 + kt, &bHs[d1]);
        if (hasALo){ GLDS(aLG + aRow0 + kt, &aLs[d0]); GLDS(aLG + aRow1 + kt, &aLs[d1]); }
        if (hasBLo){ GLDS(bLG + aRow0 + kt, &bLs[d0]); GLDS(bLG + aRow1 + kt, &bLs[d1]); }
        size_t wk = wPk + (size_t)(kt >> 5)*8192;
        #pragma unroll
        for (int m = 0; m < 4; ++m){
            GLDS(Whi + wk + (m<<11), &wHs[(m<<11) + d0]);
            GLDS(Wlo + wk + (m<<11), &wLs[(m<<11) + d0]);
        }
        __syncthreads();
        #pragma unroll
        for (int rt = 0; rt < 2; ++rt){
            v8h ah[2], bh[2], al[2], bl[2];
            #pragma unroll
            for (int r = 0; r < 2; ++r){
                int ao = ldsw(rt*64 + wr*32 + r*16 + lrow, quad);
                ah[r] = *(const v8h*)&aHs[ao];
                bh[r] = *(const v8h*)&bHs[ao];
                if (hasALo) al[r] = *(const v8h*)&aLs[ao];
                if (hasBLo) bl[r] = *(const v8h*)&bLs[ao];
            }
            #pragma unroll
            for (int cf = 0; cf < 2; ++cf){
                int wo = ldsw(wc*32 + cf*16 + lrow, quad);
                v8h w0 = *(const v8h*)&wHs[wo];
                v8h w1 = *(const v8h*)&wHs[2048 + wo];
                v8h w2 = *(const v8h*)&wHs[4096 + wo];
                v8h w3 = *(const v8h*)&wHs[6144 + wo];
                v8h l0 = *(const v8h*)&wLs[wo];
                v8h l1 = *(const v8h*)&wLs[2048 + wo];
                v8h l2 = *(const v8h*)&wLs[4096 + wo];
                v8h l3 = *(const v8h*)&wLs[6144 + wo];
                #pragma unroll
                for (int r = 0; r < 2; ++r){
                    accN[rt][r][cf] = MFMA16(ah[r], w0, accN[rt][r][cf]);
                    accN[rt][r][cf] = MFMA16(bh[r], w1, accN[rt][r][cf]);
                    accF[rt][r][cf] = MFMA16(ah[r], w2, accF[rt][r][cf]);
                    accF[rt][r][cf] = MFMA16(bh[r], w3, accF[rt][r][cf]);
                    if (hasALo){ accN[rt][r][cf] = MFMA16(al[r], w0, accN[rt][r][cf]); accF[rt][r][cf] = MFMA16(al[r], w2, accF[rt][r][cf]); }
                    if (hasBLo){ accN[rt][r][cf] = MFMA16(bl[r], w1, accN[rt][r][cf]); accF[rt][r][cf] = MFMA16(bl[r], w3, accF[rt][r][cf]); }
                    accN[rt][r][cf] = MFMA16(ah[r], l0, accN[rt][r][cf]);
                    accN[rt][r][cf] = MFMA16(bh[r], l1, accN[rt][r][cf]);
                    accF[rt][r][cf] = MFMA16(ah[r], l2, accF[rt][r][cf]);
                    accF[rt][r][cf] = MFMA16(bh[r], l3, accF[rt][r][cf]);
                }
            }
        }
    }
    #pragma unroll
    for (int rt = 0; rt < 2; ++rt)
        #pragma unroll
        for (int r = 0; r < 2; ++r)
            #pragma unroll
            for (int cf = 0; cf < 2; ++cf){
                int colg = c0 + wc*32 + cf*16 + lrow;
                int rbase = r0 + rt*64 + wr*32 + r*16 + quad*4;
                float o4[4];
                #pragma unroll
                for (int reg = 0; reg < 4; ++reg){
                    float f = 1.f/(1.f + __expf(-accF[rt][r][cf][reg]));
                    size_t ai = (size_t)(rbase+reg)*512 + colg;
                    float ao = h2f(aHG[ai]);
                    if (aLG) ao += h2f(aLG[ai]);
                    o4[reg] = f*accN[rt][r][cf][reg] + (1.f - f)*ao;
                    size_t oo = ((size_t)b*rows + rbase + reg)*512 + colg;
                    unsigned short hv = f2h(o4[reg]);
                    dst[oo] = hv;
                    if (dstLo) dstLo[oo] = f2h(o4[reg] - h2f(hv));
                    if (dstF) dstF[oo] = o4[reg];
                }
                if (dstT){
                    unsigned short h0 = f2h(o4[0]), h1 = f2h(o4[1]), h2 = f2h(o4[2]), h3 = f2h(o4[3]);
                    size_t to = ((size_t)b*512 + colg)*rows + rbase;
                    *(ushort4*)&dstT[to] = ushort4{h0,h1,h2,h3};
                    if (dstTLo)
                        *(ushort4*)&dstTLo[to] = ushort4{f2h(o4[0]-h2f(h0)), f2h(o4[1]-h2f(h1)),
                                                         f2h(o4[2]-h2f(h2)), f2h(o4[3]-h2f(h3))};
                }
            }
}

// ============ batched 3-pass fusion (128-row tiles): seg0 clip_1 (NC), seg1 gloss_2 (NG) ============
__global__ __launch_bounds__(256) void fusion3b_k(
    const unsigned short* __restrict__ a0, const unsigned short* __restrict__ a0Lo,
    const unsigned short* __restrict__ b0, const unsigned short* __restrict__ b0Lo,
    const unsigned short* __restrict__ W0hi, const unsigned short* __restrict__ W0lo,
    unsigned short* __restrict__ d0, unsigned short* __restrict__ d0Lo, float* __restrict__ d0F,
    const unsigned short* __restrict__ a1, const unsigned short* __restrict__ a1Lo,
    const unsigned short* __restrict__ b1,
    const unsigned short* __restrict__ W1hi, const unsigned short* __restrict__ W1lo,
    unsigned short* __restrict__ d1, unsigned short* __restrict__ d1Lo,
    unsigned short* __restrict__ d1T, unsigned short* __restrict__ d1TLo, float* __restrict__ d1F){
    __shared__ alignas(16) unsigned short aHs[4096], bHs[4096], aLs[4096], bLs[4096];
    __shared__ alignas(16) unsigned short wHs[8192], wLs[8192];
    int F = blockIdx.x;
    const int S0 = 8*(NC/128)*NB;
    if (F < S0)
        fusion3_body(F, aHs, bHs, aLs, bLs, wHs, wLs,
                     a0, a0Lo, b0, b0Lo, W0hi, W0lo,
                     d0, d0Lo, nullptr, nullptr, d0F, NC);
    else
        fusion3_body(F - S0, aHs, bHs, aLs, bLs, wHs, wLs,
                     a1, a1Lo, b1, nullptr, W1hi, W1lo,
                     d1, d1Lo, d1T, d1TLo, d1F, NG);
}

// ============ 1-pass fusion body (double-buffered; shared LDS passed in) ============
__device__ __forceinline__ void fusion1_body(int F,
    unsigned short (*aHs)[2048], unsigned short (*bHs)[2048], unsigned short (*wHs)[8192],
    const unsigned short* aHi, const unsigned short* aLo,
    const unsigned short* bHi, const unsigned short* Whi,
    unsigned short* dst, unsigned short* dstLo, float* dstF, int rows){
    int nY = rows >> 6;
    int ppg = (nY * NB) >> 3;
    int xcd = F & 7, t = F >> 3;
    int c0i = t / ppg;
    int p = xcd + ((t - c0i*ppg) << 3);
    int r0 = (p % nY) << 6, c0 = c0i << 6;
    int b = p / nY;
    int tid = threadIdx.x;
    size_t actOff = (size_t)b*rows*512;
    const unsigned short* aHG = aHi + actOff;
    const unsigned short* bHG = bHi + actOff;
    const unsigned short* aLG = aLo ? aLo + actOff : nullptr;
    int w = tid >> 6, lane = tid & 63;
    int wr = w >> 1, wc = w & 1;
    int lrow = lane & 15, quad = lane >> 4;
    int sr = tid >> 2;
    int sq = (tid & 3) ^ ((sr >> 1) & 3);
    size_t aRow = (size_t)(r0 + sr)*512 + sq*8;
    size_t wPk = (size_t)c0i*16*8192 + (size_t)sr*32 + sq*8;
    v4f accN[2][2], accF[2][2];
    #pragma unroll
    for (int r = 0; r < 2; ++r)
        #pragma unroll
        for (int cf = 0; cf < 2; ++cf){ accN[r][cf] = (v4f)0.f; accF[r][cf] = (v4f)0.f; }

    #define F1STAGE(bb, kk) do{ \
        GLDS(aHG + aRow + (kk), &aHs[bb][w << 9]); \
        GLDS(bHG + aRow + (kk), &bHs[bb][w << 9]); \
        size_t wk_ = wPk + (size_t)((kk) >> 5)*8192; \
        GLDS(Whi + wk_,          &wHs[bb][(0<<11) + (w<<9)]); \
        GLDS(Whi + wk_ + (1<<11), &wHs[bb][(1<<11) + (w<<9)]); \
        GLDS(Whi + wk_ + (2<<11), &wHs[bb][(2<<11) + (w<<9)]); \
        GLDS(Whi + wk_ + (3<<11), &wHs[bb][(3<<11) + (w<<9)]); \
    } while(0)

    F1STAGE(0, 0);
    __syncthreads();
    int buf = 0;
    for (int kt = 0; kt < 512; kt += 32){
        if (kt + 32 < 512) F1STAGE(buf^1, kt + 32);
        v8h ah[2], bh[2];
        #pragma unroll
        for (int r = 0; r < 2; ++r){
            int ao = ldsw(wr*32 + r*16 + lrow, quad);
            ah[r] = *(const v8h*)&aHs[buf][ao];
            bh[r] = *(const v8h*)&bHs[buf][ao];
        }
        #pragma unroll
        for (int cf = 0; cf < 2; ++cf){
            int wo = ldsw(wc*32 + cf*16 + lrow, quad);
            v8h w0 = *(const v8h*)&wHs[buf][wo];
            v8h w1 = *(const v8h*)&wHs[buf][2048 + wo];
            v8h w2 = *(const v8h*)&wHs[buf][4096 + wo];
            v8h w3 = *(const v8h*)&wHs[buf][6144 + wo];
            #pragma unroll
            for (int r = 0; r < 2; ++r){
                accN[r][cf] = MFMA16(ah[r], w0, accN[r][cf]);
                accN[r][cf] = MFMA16(bh[r], w1, accN[r][cf]);
                accF[r][cf] = MFMA16(ah[r], w2, accF[r][cf]);
                accF[r][cf] = MFMA16(bh[r], w3, accF[r][cf]);
            }
        }
        __syncthreads();
        buf ^= 1;
    }
    #undef F1STAGE
    #pragma unroll
    for (int r = 0; r < 2; ++r)
        #pragma unroll
        for (int cf = 0; cf < 2; ++cf){
            int colg = c0 + wc*32 + cf*16 + lrow;
            int rbase = r0 + wr*32 + r*16 + quad*4;
            #pragma unroll
            for (int reg = 0; reg < 4; ++reg){
                float f = 1.f/(1.f + __expf(-accF[r][cf][reg]));
                size_t ai = (size_t)(rbase+reg)*512 + colg;
                float ao = h2f(aHG[ai]);
                if (aLG) ao += h2f(aLG[ai]);
                float o = f*accN[r][cf][reg] + (1.f - f)*ao;
                size_t oo = ((size_t)b*rows + rbase + reg)*512 + colg;
                unsigned short hv = f2h(o);
                dst[oo] = hv;
                if (dstLo) dstLo[oo] = f2h(o - h2f(hv));
                if (dstF) dstF[oo] = o;
            }
        }
}

// ============ batched 1-pass fusion: seg0 gloss_1 (NG), seg1 question_1 (NQ) ============
__global__ __launch_bounds__(256) void fusion1b_k(
    const unsigned short* __restrict__ a0, const unsigned short* __restrict__ a0Lo,
    const unsigned short* __restrict__ b0, const unsigned short* __restrict__ W0,
    unsigned short* __restrict__ d0, unsigned short* __restrict__ d0Lo,
    const unsigned short* __restrict__ a1, const unsigned short* __restrict__ b1,
    const unsigned short* __restrict__ W1,
    unsigned short* __restrict__ d1, float* __restrict__ d1F){
    __shared__ alignas(16) unsigned short aHs[2][2048], bHs[2][2048];
    __shared__ alignas(16) unsigned short wHs[2][8192];
    int F = blockIdx.x;
    const int S0 = 8*(NG/64)*NB;
    if (F < S0)
        fusion1_body(F, aHs, bHs, wHs, a0, a0Lo, b0, W0, d0, d0Lo, nullptr, NG);
    else
        fusion1_body(F - S0, aHs, bHs, wHs, a1, nullptr, b1, W1, d1, nullptr, d1F, NQ);
}

// ============ attention output body (shared LDS passed in) ============
__device__ __forceinline__ void attn_body(int F,
    unsigned short* pS, unsigned short* wS, float* qsS, float* sKs, float* sCm, float* sIs,
    const unsigned* bmN, int M32,
    const float* qs3, int qOff,
    const float* ksh, const float* cmh, const float* ish,
    int mOff, const unsigned short* WkT3,
    unsigned short* outp, int N, int M){
    int nN0 = N >> 6;
    int xcd = F & 7, t = F >> 3;
    int bh = xcd*4 + t/nN0;
    int n0 = (t % nN0) << 6;
    int b = bh >> 3, h = bh & 7;
    int tid = threadIdx.x;
    const float* ksb = ksh + ((size_t)b*8 + h)*SEG + mOff;
    const float* cmb = cmh + ((size_t)b*8 + h)*SEG + mOff;
    const float* isb = ish + ((size_t)b*8 + h)*SEG + mOff;
    const unsigned short* wkb = WkT3 + ((size_t)b*512 + h*64)*SEG + mOff;
    int w = tid >> 6, lane = tid & 63;
    int lrow = lane & 15, quad = lane >> 4;
    int pn = tid >> 2, pm = (tid & 3)*8;
    int sr = tid >> 2;
    int sq = (tid & 3) ^ ((sr >> 1) & 3);
    for (int o = w*256; o < M; o += 1024){
        GLDS(ksb + o + lane*4, &sKs[o]);
        GLDS(cmb + o + lane*4, &sCm[o]);
        GLDS(isb + o + lane*4, &sIs[o]);
    }
    if (tid < 64) qsS[tid] = qs3[((size_t)b*SEG + qOff + n0 + tid)*8 + h];
    const unsigned* bmrow = bmN + ((size_t)b*N + n0 + pn)*M32;
    v4f acc[4];
    #pragma unroll
    for (int cf = 0; cf < 4; ++cf) acc[cf] = (v4f)0.f;
    uint2 CW = *(const uint2*)(bmrow);
    uint2 NW;
    __syncthreads();
    float qv = qsS[pn];
    for (int mt = 0; mt < M; mt += 64){
        int mtB = mt + 32;
        int mtN = (mt + 64 < M) ? (mt + 64) : 0;
        GLDS(wkb + (size_t)sr*SEG + mt + sq*8, &wS[w << 9]);
        {
            unsigned bb = (CW.x >> pm) & 0xffu;
            float4 k0 = *(const float4*)&sKs[mt+pm], k1 = *(const float4*)&sKs[mt+pm+4];
            float4 c0 = *(const float4*)&sCm[mt+pm], c1 = *(const float4*)&sCm[mt+pm+4];
            float4 i0 = *(const float4*)&sIs[mt+pm], i1 = *(const float4*)&sIs[mt+pm+4];
            float p[8];
            const float* kk0 = &k0.x; const float* kk1 = &k1.x;
            const float* cc0 = &c0.x; const float* cc1 = &c1.x;
            const float* ii0 = &i0.x; const float* ii1 = &i1.x;
            #pragma unroll
            for (int j = 0; j < 4; ++j){
                float e = ((bb >> j) & 1) ? lrelu(qv + kk0[j]) : NEGV;
                p[j] = __expf(e - cc0[j]) * ii0[j];
            }
            #pragma unroll
            for (int j = 0; j < 4; ++j){
                float e = ((bb >> (4+j)) & 1) ? lrelu(qv + kk1[j]) : NEGV;
                p[4+j] = __expf(e - cc1[j]) * ii1[j];
            }
            *(ushort4*)&pS[pn*LSTR + pm]     = ushort4{f2h(p[0]), f2h(p[1]), f2h(p[2]), f2h(p[3])};
            *(ushort4*)&pS[pn*LSTR + pm + 4] = ushort4{f2h(p[4]), f2h(p[5]), f2h(p[6]), f2h(p[7])};
        }
        __syncthreads();
        {
            v8h af = *(const v8h*)&pS[(w*16 + lrow)*LSTR + quad*8];
            #pragma unroll
            for (int cf = 0; cf < 4; ++cf){
                v8h bf = *(const v8h*)&wS[ldsw(cf*16 + lrow, quad)];
                acc[cf] = MFMA16(af, bf, acc[cf]);
            }
        }
        GLDS(wkb + (size_t)sr*SEG + mtB + sq*8, &wS[2048 + (w << 9)]);
        NW = *(const uint2*)(bmrow + (mtN >> 5));
        {
            unsigned bb = (CW.y >> pm) & 0xffu;
            float4 k0 = *(const float4*)&sKs[mtB+pm], k1 = *(const float4*)&sKs[mtB+pm+4];
            float4 c0 = *(const float4*)&sCm[mtB+pm], c1 = *(const float4*)&sCm[mtB+pm+4];
            float4 i0 = *(const float4*)&sIs[mtB+pm], i1 = *(const float4*)&sIs[mtB+pm+4];
            float p[8];
            const float* kk0 = &k0.x; const float* kk1 = &k1.x;
            const float* cc0 = &c0.x; const float* cc1 = &c1.x;
            const float* ii0 = &i0.x; const float* ii1 = &i1.x;
            #pragma unroll
            for (int j = 0; j < 4; ++j){
                float e = ((bb >> j) & 1) ? lrelu(qv + kk0[j]) : NEGV;
                p[j] = __expf(e - cc0[j]) * ii0[j];
            }
            #pragma unroll
            for (int j = 0; j < 4; ++j){
                float e = ((bb >> (4+j)) & 1) ? lrelu(qv + kk1[j]) : NEGV;
                p[4+j] = __expf(e - cc1[j]) * ii1[j];
            }
            *(ushort4*)&pS[2304 + pn*LSTR + pm]     = ushort4{f2h(p[0]), f2h(p[1]), f2h(p[2]), f2h(p[3])};
            *(ushort4*)&pS[2304 + pn*LSTR + pm + 4] = ushort4{f2h(p[4]), f2h(p[5]), f2h(p[6]), f2h(p[7])};
        }
        __syncthreads();
        {
            v8h af = *(const v8h*)&pS[2304 + (w*16 + lrow)*LSTR + quad*8];
            #pragma unroll
            for (int cf = 0; cf < 4; ++cf){
                v8h bf = *(const v8h*)&wS[2048 + ldsw(cf*16 + lrow, quad)];
                acc[cf] = MFMA16(af, bf, acc[cf]);
            }
        }
        CW = NW;
    }
    #pragma unroll
    for (int cf = 0; cf < 4; ++cf){
        int colg = h*64 + cf*16 + lrow;
        int rbase = n0 + w*16 + quad*4;
        #pragma unroll
        for (int reg = 0; reg < 4; ++reg){
            float v = acc[cf][reg];
            v = (v > 0.f) ? v : (__expf(v) - 1.f);
            outp[((size_t)b*N + rbase + reg)*512 + colg] = f2h(v);
        }
    }
}

// ============ batched attention: attn0 (512 blk) + attn1 (128) + attn2 (512) ============
__global__ __launch_bounds__(256) void attn_all_k(
    const unsigned* __restrict__ bm_gc, const unsigned* __restrict__ bm_qg,
    const unsigned* __restrict__ bm_gq,
    const float* __restrict__ qs3,
    const float* __restrict__ ksh, const float* __restrict__ cmh, const float* __restrict__ ish,
    const unsigned short* __restrict__ WkT3,
    unsigned short* __restrict__ agg0, unsigned short* __restrict__ agg1,
    unsigned short* __restrict__ agg2){
    __shared__ unsigned short pS[2*64*LSTR];
    __shared__ alignas(16) unsigned short wS[2*2048];
    __shared__ float qsS[64];
    __shared__ alignas(16) float sKs[1024], sCm[1024], sIs[1024];
    int F = blockIdx.x;
    const int S0 = (NG/64)*32;            // 512
    const int S1 = S0 + (NQ/64)*32;       // 640
    if (F < S0)
        attn_body(F, pS, wS, qsS, sKs, sCm, sIs, bm_gc, NC/32, qs3, 0,
                  ksh, cmh, ish, 0, WkT3, agg0, NG, NC);
    else if (F < S1)
        attn_body(F - S0, pS, wS, qsS, sKs, sCm, sIs, bm_qg, NG/32, qs3, 1024,
                  ksh, cmh, ish, 1024, WkT3, agg1, NQ, NG);
    else
        attn_body(F - S1, pS, wS, qsS, sKs, sCm, sIs, bm_gq, NQ/32, qs3, 1280,
                  ksh, cmh, ish, 2048, WkT3, agg2, NG, NQ);
}

extern "C" void kernel_launch(void* const* d_in, const int* in_sizes, int n_in,
                              void* d_out, int out_size, void* d_ws, size_t ws_size,
                              hipStream_t stream){
    const float* in_gloss = (const float*)d_in[0];
    const float* in_clip  = (const float*)d_in[1];
    const float* in_q     = (const float*)d_in[2];
    const int*   adj_gc   = (const int*)d_in[3];
    const int*   adj_gq   = (const int*)d_in[4];
    const float* c2gW  = (const float*)d_in[5];
    const float* c2ga1 = (const float*)d_in[6];
    const float* c2ga2 = (const float*)d_in[7];
    const float* g2qW  = (const float*)d_in[8];
    const float* g2qa1 = (const float*)d_in[9];
    const float* g2qa2 = (const float*)d_in[10];
    const float* q2gW  = (const float*)d_in[11];
    const float* q2ga1 = (const float*)d_in[12];
    const float* q2ga2 = (const float*)d_in[13];
    const float* fusW  = (const float*)d_in[14];
    const float* fusU  = (const float*)d_in[15];
    const float* fusWf = (const float*)d_in[16];
    const float* fusUf = (const float*)d_in[17];
    float* out = (float*)d_out;
    float* out_gloss = out;
    float* out_clip  = out + (size_t)NB*NG*NFEAT;
    float* out_q     = out + (size_t)NB*NG*NFEAT*2;

    char* wsB = (char*)d_ws;
    size_t off = 0;
    auto alloc = [&](size_t bytes){ void* p = wsB + off; off += (bytes + 255) & ~(size_t)255; return p; };
    float* wa13  = (float*)alloc(3*4096*4);
    float* wa23  = (float*)alloc(3*4096*4);
    float* qs3   = (float*)alloc((size_t)NB*SEG*8*4);
    float* ks3   = (float*)alloc((size_t)NB*SEG*8*4);
    float* ksh3  = (float*)alloc((size_t)NB*8*SEG*4);
    float* cmh3  = (float*)alloc((size_t)NB*8*SEG*4);
    float* ish3  = (float*)alloc((size_t)NB*8*SEG*4);
    float* pcm   = (float*)alloc((size_t)NB*CHUNKS*SEG*8*4);
    float* psum  = (float*)alloc((size_t)NB*CHUNKS*SEG*8*4);
    unsigned short* WflatT3 = (unsigned short*)alloc((size_t)3*FF*2);
    unsigned short* WkT3    = (unsigned short*)alloc((size_t)NB*512*SEG*2);
    unsigned short* wtAll   = (unsigned short*)alloc((size_t)32*FF*2);
    unsigned short* wtAllLo = (unsigned short*)alloc((size_t)32*FF*2);
    unsigned short* adjTgc  = (unsigned short*)alloc((size_t)NB*NC*NG*2);
    unsigned short* g_bf0   = (unsigned short*)alloc((size_t)NB*NG*NFEAT*2);
    unsigned short* gLo0    = (unsigned short*)alloc((size_t)NB*NG*NFEAT*2);
    unsigned short* g_bf1   = (unsigned short*)alloc((size_t)NB*NG*NFEAT*2);
    unsigned short* gLo1    = (unsigned short*)alloc((size_t)NB*NG*NFEAT*2);
    unsigned short* gT      = (unsigned short*)alloc((size_t)NB*NFEAT*NG*2);
    unsigned short* gTlo    = (unsigned short*)alloc((size_t)NB*NFEAT*NG*2);
    unsigned short* gA_bf   = (unsigned short*)alloc((size_t)NB*NG*NFEAT*2);
    unsigned short* gALo    = (unsigned short*)alloc((size_t)NB*NG*NFEAT*2);
    unsigned short* c_bf0   = (unsigned short*)alloc((size_t)NB*NC*NFEAT*2);
    unsigned short* cLo0    = (unsigned short*)alloc((size_t)NB*NC*NFEAT*2);
    unsigned short* c_bf1   = (unsigned short*)alloc((size_t)NB*NC*NFEAT*2);
    unsigned short* cLo1    = (unsigned short*)alloc((size_t)NB*NC*NFEAT*2);
    unsigned short* q_bf0   = (unsigned short*)alloc((size_t)NB*NQ*NFEAT*2);
    unsigned short* q_bf1   = (unsigned short*)alloc((size_t)NB*NQ*NFEAT*2);
    unsigned short* agg_bf  = (unsigned short*)alloc((size_t)NB*NG*NFEAT*2);
    unsigned short* aggLo   = (unsigned short*)alloc((size_t)NB*NG*NFEAT*2);
    unsigned short* agg0    = (unsigned short*)alloc((size_t)NB*NG*NFEAT*2);
    unsigned short* agg1    = (unsigned short*)alloc((size_t)NB*NQ*NFEAT*2);
    unsigned short* agg2    = (unsigned short*)alloc((size_t)NB*NG*NFEAT*2);
    int* adjTgq = (int*)alloc((size_t)NB*NQ*NG*4);
    unsigned* bm_gc = (unsigned*)alloc((size_t)NB*NG*(NC/32)*4);
    unsigned* bm_cg = (unsigned*)alloc((size_t)NB*NC*(NG/32)*4);
    unsigned* bm_gq = (unsigned*)alloc((size_t)NB*NG*(NQ/32)*4);
    unsigned* bm_qg = (unsigned*)alloc((size_t)NB*NQ*(NG/32)*4);
    (void)ws_size; (void)in_sizes; (void)n_in; (void)out_size;

    const size_t HFD = (size_t)NHEADS*NFEAT*HDIM;
    const size_t HD  = (size_t)NHEADS*HDIM;

    // ---- prep ----
    wtT_k<<<2048, 256, 0, stream>>>(fusW, fusU, fusWf, fusUf, wtAll, wtAllLo);
    adjT_h_k<<<dim3(NC/64, NG/64, NB), 256, 0, stream>>>(adj_gc, adjTgc,
        (unsigned long long*)bm_gc, (unsigned long long*)bm_cg);
    adjT_int_k<<<dim3(NQ/64, NG/64, NB), 256, 0, stream>>>(adj_gq, adjTgq,
        (unsigned long long*)bm_gq, (unsigned long long*)bm_qg);
    cvt2_k<<<1024 + 256, 256, 0, stream>>>(in_clip, c_bf0, cLo0, in_q, q_bf0);
    actT_hl_k<<<dim3(8, NG/64, NB), 256, 0, stream>>>(in_gloss, gT, gTlo, g_bf0, gLo0, NG);

    for (int l = 0; l < 2; ++l){
        const unsigned short* g_cur = (l == 0) ? g_bf0 : g_bf1;
        const unsigned short* gLoC  = (l == 0) ? gLo0  : gLo1;
        const unsigned short* c_cur = (l == 0) ? c_bf0 : c_bf1;
        const unsigned short* cLoC  = (l == 0) ? cLo0  : cLo1;
        const unsigned short* q_cur = (l == 0) ? q_bf0 : q_bf1;
        unsigned short* g_nxt = (l == 0) ? g_bf1 : g_bf0;
        unsigned short* gLoN  = (l == 0) ? gLo1  : nullptr;
        unsigned short* c_nxt = (l == 0) ? c_bf1 : c_bf0;
        unsigned short* cLoN  = (l == 0) ? cLo1  : nullptr;
        unsigned short* q_nxt = (l == 0) ? q_bf1 : q_bf0;
        float* gF = (l == 1) ? out_gloss : nullptr;
        float* cF = (l == 1) ? out_clip  : nullptr;
        float* qF = (l == 1) ? out_q     : nullptr;

        // ---- batched attention prep (depends only on layer inputs) ----
        prep_attnW3_k<<<240, 256, 0, stream>>>(
            c2gW + l*HFD, c2ga1 + l*HD, c2ga2 + l*HD,
            g2qW + l*HFD, g2qa1 + l*HD, g2qa2 + l*HD,
            q2gW + l*HFD, q2ga1 + l*HD, q2ga2 + l*HD,
            WflatT3, wa13, wa23);
        // scores | wkt3 | gemmT(gloss_same) in one launch
        layerB_k<<<4608 + 1152 + 512, 256, 0, stream>>>(
            g_cur, c_cur, q_cur, wa13, wa23, qs3, ks3,
            WflatT3, WkT3, adjTgc, gT, gTlo, agg_bf, aggLo);
        colstat3_k<<<dim3(576, 1, NB), 256, 0, stream>>>(bm_cg, bm_gq, bm_qg, qs3, ks3, pcm, psum);
        colfin3_k<<<(NB*SEG*8)/256, 256, 0, stream>>>(pcm, psum, ks3, ksh3, cmh3, ish3);

        // all 3 attentions in one launch -> agg0 (clip_agg), agg1 (gloss_agg), agg2 (question_agg)
        attn_all_k<<<(NG/64)*32 + (NQ/64)*32 + (NG/64)*32, 256, 0, stream>>>(
            bm_gc, bm_qg, bm_gq, qs3, ksh3, cmh3, ish3, WkT3, agg0, agg1, agg2);
        // gloss_1 + question_1 in one launch
        fusion1b_k<<<8*(NG/64)*NB + 8*(NQ/64)*NB, 256, 0, stream>>>(
            g_cur, gLoC, agg0, wtAll + (size_t)((l*4 + 1)*4)*FF, gA_bf, gALo,
            q_cur, agg1, wtAll + (size_t)((l*4 + 2)*4)*FF, q_nxt, qF);
        // clip_1 + gloss_2 in one launch (128-row tiles)
        fusion3b_k<<<8*(NC/128)*NB + 8*(NG/128)*NB, 256, 0, stream>>>(
            c_cur, cLoC, agg_bf, aggLo,
            wtAll + (size_t)((l*4 + 0)*4)*FF, wtAllLo + (size_t)((l*4 + 0)*4)*FF,
            c_nxt, cLoN, cF,
            gA_bf, gALo, agg2,
            wtAll + (size_t)((l*4 + 3)*4)*FF, wtAllLo + (size_t)((l*4 + 3)*4)*FF,
            g_nxt, gLoN, (l == 0) ? gT : nullptr, (l == 0) ? gTlo : nullptr, gF);
    }
}